// Round 3
// baseline (713.603 us; speedup 1.0000x reference)
//
#include <hip/hip_runtime.h>
#include <hip/hip_fp16.h>
#include <cmath>

typedef unsigned short ushort_t;
typedef unsigned int uint_t;

#define N_TOT 30000
#define N0_   18000
#define R_    5
#define E_    600000
#define RN    (R_ * N_TOT)
#define NC_   (N_TOT * 8)        // logits elements
#define NX_   (N_TOT * 128)      // x elements
#define NL_   (N_TOT * 64)      // node*lane pairs

__device__ __forceinline__ ushort_t f2bf(float f) {
    uint_t u = __float_as_uint(f);
    uint_t r = (u + 0x7fffu + ((u >> 16) & 1u)) >> 16;   // RTNE
    return (ushort_t)r;
}
__device__ __forceinline__ float bflo(uint_t v) { return __uint_as_float(v << 16); }
__device__ __forceinline__ float bfhi(uint_t v) { return __uint_as_float(v & 0xffff0000u); }

// ---------------------------------------------------------------------------
// init: u = 1/R, act[0] = 1
// ---------------------------------------------------------------------------
__global__ void init_kernel(float* ug, int* act) {
    if (threadIdx.x < 5) ug[threadIdx.x] = 0.2f;
    if (threadIdx.x == 0) act[0] = 1;
}

// ---------------------------------------------------------------------------
// Fused MLP, 8 nodes per 128-thread block + bf16 shadow write (unchanged)
// ---------------------------------------------------------------------------
__global__ __launch_bounds__(128) void mlp_kernel(
    const float* __restrict__ feat0, const float* __restrict__ feat1,
    const float* __restrict__ W0, const float* __restrict__ b0,
    const float* __restrict__ W1, const float* __restrict__ b1,
    const float* __restrict__ Wm1, const float* __restrict__ bm1,
    const float* __restrict__ Wm2, const float* __restrict__ bm2,
    float* __restrict__ xout, ushort_t* __restrict__ xh)
{
    const int j = threadIdx.x;
    const int lane = j & 63, wv_id = j >> 6;
    const int row0 = blockIdx.x * 8;

    __shared__ float sh[8][128];
    __shared__ float red[2][8];

    const bool is0 = (row0 < N0_);
    const float* __restrict__ fbase =
        is0 ? feat0 + (size_t)row0 * 256 : feat1 + (size_t)(row0 - N0_) * 128;
    const float* __restrict__ W = is0 ? W0 : W1;
    const int K = is0 ? 256 : 128;
    const float bias = is0 ? b0[j] : b1[j];

    float acc[8];
    #pragma unroll
    for (int p = 0; p < 8; ++p) acc[p] = bias;

    for (int k = 0; k < K; k += 4) {
        float w0 = W[(k + 0) * 128 + j];
        float w1 = W[(k + 1) * 128 + j];
        float w2 = W[(k + 2) * 128 + j];
        float w3 = W[(k + 3) * 128 + j];
        #pragma unroll
        for (int p = 0; p < 8; ++p) {
            const float4 f4 = *(const float4*)(fbase + (size_t)p * K + k);
            acc[p] = fmaf(f4.x, w0, acc[p]);
            acc[p] = fmaf(f4.y, w1, acc[p]);
            acc[p] = fmaf(f4.z, w2, acc[p]);
            acc[p] = fmaf(f4.w, w3, acc[p]);
        }
    }
    #pragma unroll
    for (int p = 0; p < 8; ++p) sh[p][j] = acc[p];
    __syncthreads();

    float t1[8];
    #pragma unroll
    for (int p = 0; p < 8; ++p) t1[p] = bm1[j];
    for (int k = 0; k < 128; k += 4) {
        float w0 = Wm1[(k + 0) * 128 + j];
        float w1 = Wm1[(k + 1) * 128 + j];
        float w2 = Wm1[(k + 2) * 128 + j];
        float w3 = Wm1[(k + 3) * 128 + j];
        #pragma unroll
        for (int p = 0; p < 8; ++p) {
            const float4 f4 = *(const float4*)(&sh[p][k]);
            t1[p] = fmaf(f4.x, w0, t1[p]);
            t1[p] = fmaf(f4.y, w1, t1[p]);
            t1[p] = fmaf(f4.z, w2, t1[p]);
            t1[p] = fmaf(f4.w, w3, t1[p]);
        }
    }

    float mean[8];
    {
        #pragma unroll
        for (int p = 0; p < 8; ++p) {
            float s = t1[p];
            for (int o = 32; o > 0; o >>= 1) s += __shfl_down(s, o, 64);
            if (lane == 0) red[wv_id][p] = s;
        }
        __syncthreads();
        #pragma unroll
        for (int p = 0; p < 8; ++p) mean[p] = (red[0][p] + red[1][p]) * (1.0f / 128.0f);
        __syncthreads();
        #pragma unroll
        for (int p = 0; p < 8; ++p) {
            float d = t1[p] - mean[p];
            float s = d * d;
            for (int o = 32; o > 0; o >>= 1) s += __shfl_down(s, o, 64);
            if (lane == 0) red[wv_id][p] = s;
        }
        __syncthreads();
    }
    #pragma unroll
    for (int p = 0; p < 8; ++p) {
        float var = (red[0][p] + red[1][p]) * (1.0f / 128.0f);
        float z = fmaxf((t1[p] - mean[p]) / sqrtf(var + 1e-5f), 0.0f);
        t1[p] = z;
    }
    __syncthreads();
    #pragma unroll
    for (int p = 0; p < 8; ++p) sh[p][j] = t1[p];
    __syncthreads();

    float t2[8];
    #pragma unroll
    for (int p = 0; p < 8; ++p) t2[p] = bm2[j];
    for (int k = 0; k < 128; k += 4) {
        float w0 = Wm2[(k + 0) * 128 + j];
        float w1 = Wm2[(k + 1) * 128 + j];
        float w2 = Wm2[(k + 2) * 128 + j];
        float w3 = Wm2[(k + 3) * 128 + j];
        #pragma unroll
        for (int p = 0; p < 8; ++p) {
            const float4 f4 = *(const float4*)(&sh[p][k]);
            t2[p] = fmaf(f4.x, w0, t2[p]);
            t2[p] = fmaf(f4.y, w1, t2[p]);
            t2[p] = fmaf(f4.z, w2, t2[p]);
            t2[p] = fmaf(f4.w, w3, t2[p]);
        }
    }

    float mu[8];
    {
        #pragma unroll
        for (int p = 0; p < 8; ++p) {
            float s = t2[p];
            for (int o = 32; o > 0; o >>= 1) s += __shfl_down(s, o, 64);
            if (lane == 0) red[wv_id][p] = s;
        }
        __syncthreads();
        #pragma unroll
        for (int p = 0; p < 8; ++p) mu[p] = (red[0][p] + red[1][p]) * (1.0f / 128.0f);
        __syncthreads();
        #pragma unroll
        for (int p = 0; p < 8; ++p) {
            float d = t2[p] - mu[p];
            float s = d * d;
            for (int o = 32; o > 0; o >>= 1) s += __shfl_down(s, o, 64);
            if (lane == 0) red[wv_id][p] = s;
        }
        __syncthreads();
    }
    #pragma unroll
    for (int p = 0; p < 8; ++p) {
        float sd = sqrtf((red[0][p] + red[1][p]) * (1.0f / 127.0f));
        float r = (t2[p] - mu[p]) / sd;
        if (!(fabsf(r) <= 3.402823466e38f)) {
            r = (r != r) ? 0.0f : ((r > 0.0f) ? 3.402823466e38f : -3.402823466e38f);
        }
        xout[(size_t)(row0 + p) * 128 + j] = r;
        xh[(size_t)(row0 + p) * 128 + j] = f2bf(r);
    }
}

// ---------------------------------------------------------------------------
// preprocessing (unchanged)
// ---------------------------------------------------------------------------
__global__ void deg_kernel(const int* __restrict__ src, const int* __restrict__ rel,
                           int* __restrict__ deg_i)
{
    int e = blockIdx.x * 256 + threadIdx.x;
    if (e >= E_) return;
    atomicAdd(&deg_i[rel[e] * N_TOT + src[e]], 1);
}

__global__ void dinv_kernel(const int* __restrict__ deg_i, float* __restrict__ dinv)
{
    int i = blockIdx.x * 256 + threadIdx.x;
    if (i >= RN) return;
    int dg = deg_i[i];
    dinv[i] = (dg > 0) ? 1.0f / sqrtf((float)dg) : 0.0f;
}

__global__ __launch_bounds__(1024) void scan_kernel(const int* __restrict__ cnt,
                                                    int* __restrict__ rp)
{
    __shared__ int wsum[16];
    __shared__ int s_carry;
    const int t = threadIdx.x, lane = t & 63, w = t >> 6;
    if (t == 0) s_carry = 0;
    __syncthreads();
    const int CH = 8192;
    for (int base = 0; base < RN; base += CH) {
        int v[8]; int s = 0;
        const int i0 = base + t * 8;
        #pragma unroll
        for (int i = 0; i < 8; ++i) { int ii = i0 + i; v[i] = (ii < RN) ? cnt[ii] : 0; s += v[i]; }
        int sc = s;
        #pragma unroll
        for (int o = 1; o < 64; o <<= 1) { int tmp = __shfl_up(sc, o, 64); if (lane >= o) sc += tmp; }
        if (lane == 63) wsum[w] = sc;
        __syncthreads();
        int woff = 0;
        for (int i = 0; i < w; ++i) woff += wsum[i];
        int run = s_carry + woff + (sc - s);
        #pragma unroll
        for (int i = 0; i < 8; ++i) { int ii = i0 + i; if (ii < RN) rp[ii] = run; run += v[i]; }
        int chunk_total = woff + sc;   // valid for t==1023
        __syncthreads();
        if (t == 1023) s_carry += chunk_total;
        __syncthreads();
    }
    if (threadIdx.x == 0) rp[RN] = s_carry;
}

__global__ void scatter_kernel(const int* __restrict__ src, const int* __restrict__ dst,
                               const int* __restrict__ rel, const int* __restrict__ rp,
                               int* __restrict__ fill, const int* __restrict__ deg_i,
                               const float* __restrict__ dinv,
                               int* __restrict__ csr_dst, float* __restrict__ csr_w,
                               float* __restrict__ csr_edinv)
{
    int e = blockIdx.x * 256 + threadIdx.x;
    if (e >= E_) return;
    int s = src[e], r = rel[e], d = dst[e];
    int key = r * N_TOT + s;
    int pos = rp[key] + atomicAdd(&fill[key], 1);
    csr_dst[pos] = d;
    csr_w[pos] = 1.0f / (float)deg_i[key];
    csr_edinv[pos] = dinv[key] * dinv[r * N_TOT + d];
}

// ---------------------------------------------------------------------------
// gather: ONE edge pass computing BOTH tv partials (node+edge terms) AND the
// per-relation messages m_r[n] = sum_e w_e * x[dst], written to mbuf as
// packed fp16 pairs ((x,y) per lane).  u-independent, so the apply kernel
// can consume m after the scalar step without a second gather.
// ---------------------------------------------------------------------------
__global__ __launch_bounds__(256) void gather_kernel(
    const ushort_t* __restrict__ xh, const int* __restrict__ rp,
    const int* __restrict__ csr_dst, const float* __restrict__ csr_edinv,
    const float* __restrict__ csr_w,
    const int* __restrict__ act, int k, float* __restrict__ accbuf,
    uint_t* __restrict__ mbuf)
{
    if (act[k] == 0) return;
    const int lane = threadIdx.x & 63;
    const int wv = threadIdx.x >> 6;
    const int wid = blockIdx.x * 4 + wv;
    const int nw = gridDim.x * 4;
    float na[5] = {0, 0, 0, 0, 0};
    float ea[5] = {0, 0, 0, 0, 0};
    for (int n = wid; n < N_TOT; n += nw) {
        const uint_t vs = ((const uint_t*)(xh + (size_t)n * 128))[lane];
        const float sx = bflo(vs), sy = bfhi(vs);
        const float pp = fmaf(sx, sx, sy * sy);
        #pragma unroll
        for (int r = 0; r < 5; ++r) {
            const int e0 = rp[r * N_TOT + n];
            const int e1 = rp[r * N_TOT + n + 1];
            if (e1 > e0) na[r] += pp;
            float d0 = 0.0f, d1 = 0.0f;
            float mxa = 0.0f, mya = 0.0f, mxb = 0.0f, myb = 0.0f;
            int e = e0;
            for (; e + 2 <= e1; e += 2) {
                const int dn0 = csr_dst[e];
                const int dn1 = csr_dst[e + 1];
                const float ed0 = csr_edinv[e];
                const float ed1 = csr_edinv[e + 1];
                const float cw0 = csr_w[e];
                const float cw1 = csr_w[e + 1];
                const uint_t v0 = ((const uint_t*)(xh + (size_t)dn0 * 128))[lane];
                const uint_t v1 = ((const uint_t*)(xh + (size_t)dn1 * 128))[lane];
                const float x0 = bflo(v0), y0 = bfhi(v0);
                const float x1 = bflo(v1), y1 = bfhi(v1);
                d0 = fmaf(ed0, fmaf(sx, x0, sy * y0), d0);
                d1 = fmaf(ed1, fmaf(sx, x1, sy * y1), d1);
                mxa = fmaf(cw0, x0, mxa); mya = fmaf(cw0, y0, mya);
                mxb = fmaf(cw1, x1, mxb); myb = fmaf(cw1, y1, myb);
            }
            if (e < e1) {
                const int dn0 = csr_dst[e];
                const float ed0 = csr_edinv[e];
                const float cw0 = csr_w[e];
                const uint_t v0 = ((const uint_t*)(xh + (size_t)dn0 * 128))[lane];
                const float x0 = bflo(v0), y0 = bfhi(v0);
                d0 = fmaf(ed0, fmaf(sx, x0, sy * y0), d0);
                mxa = fmaf(cw0, x0, mxa); mya = fmaf(cw0, y0, mya);
            }
            ea[r] += d0 + d1;
            __half2 hm = __floats2half2_rn(mxa + mxb, mya + myb);
            mbuf[((size_t)(r * N_TOT + n)) * 64 + lane] =
                *reinterpret_cast<const uint_t*>(&hm);
        }
    }
    __shared__ float sacc[4][10];
    #pragma unroll
    for (int r = 0; r < 5; ++r) {
        float a = na[r], b2 = ea[r];
        for (int o = 32; o > 0; o >>= 1) {
            a += __shfl_down(a, o, 64);
            b2 += __shfl_down(b2, o, 64);
        }
        if (lane == 0) { sacc[wv][r] = a; sacc[wv][5 + r] = b2; }
    }
    __syncthreads();
    if (threadIdx.x < 10) {
        float t = sacc[0][threadIdx.x] + sacc[1][threadIdx.x] +
                  sacc[2][threadIdx.x] + sacc[3][threadIdx.x];
        atomicAdd(&accbuf[k * 16 + threadIdx.x], t);
    }
}

// ---------------------------------------------------------------------------
// scalar: fp32 lane-parallel mirror descent (lanes 0..7 of one wave)
// ---------------------------------------------------------------------------
__global__ void scalar_kernel(const float* __restrict__ accbuf, float* __restrict__ ug,
                              float* __restrict__ c_l1, int* __restrict__ act, int k)
{
    if (blockIdx.x != 0 || threadIdx.x >= 8) return;
    const int r = threadIdx.x;
    const int a = act[k];
    float w = (r < 5) ? (accbuf[k * 16 + r] - accbuf[k * 16 + 5 + r]) * (1.0f / 30000.0f)
                      : 0.0f;
    float l1 = fabsf(w);
    for (int o = 4; o > 0; o >>= 1) l1 += __shfl_xor(l1, o, 8);
    if (k == 0 && r == 0) c_l1[0] = l1;
    if (!a) { if (r == 0) act[k + 1] = 0; return; }
    float u = (r < 5) ? ug[r] : 0.0f;
    const float fi = l1 + 3.0f;
    bool mact = true;
    for (int t = 1; t <= 20; ++t) {
        float T = sqrtf(3.2188758248682006f / ((float)t * fi * fi));
        float ta = u * expf(-T * (3.0f * u + w));
        float ssum = ta;
        for (int o = 4; o > 0; o >>= 1) ssum += __shfl_xor(ssum, o, 8);
        float un = ta / ssum;
        float d0 = u - un;
        float dq = d0 * d0;
        for (int o = 4; o > 0; o >>= 1) dq += __shfl_xor(dq, o, 8);
        if (mact) u = un;
        mact = mact && (sqrtf(dq) >= 1e-3f);
    }
    if (r < 5) ug[r] = u;
    if (r == 0) act[k + 1] = (l1 / c_l1[0] >= 0.3f) ? 1 : 0;
}

// ---------------------------------------------------------------------------
// apply: x = x/(1+L1) + L1/(1+L1) * sum_r u_r m_r  — pure streaming, no
// gathers.  One thread per (node, lane-pair).
// ---------------------------------------------------------------------------
__global__ __launch_bounds__(256) void apply_kernel(
    float* __restrict__ x, ushort_t* __restrict__ xh_out,
    const uint_t* __restrict__ mbuf, const float* __restrict__ ug,
    const int* __restrict__ act, int k)
{
    if (act[k + 1] == 0) return;
    const int tid = blockIdx.x * 256 + threadIdx.x;
    if (tid >= NL_) return;
    const float u0 = ug[0], u1 = ug[1], u2 = ug[2], u3 = ug[3], u4 = ug[4];

    uint_t w0 = mbuf[(size_t)0 * NL_ + tid];
    uint_t w1 = mbuf[(size_t)1 * NL_ + tid];
    uint_t w2 = mbuf[(size_t)2 * NL_ + tid];
    uint_t w3 = mbuf[(size_t)3 * NL_ + tid];
    uint_t w4 = mbuf[(size_t)4 * NL_ + tid];
    const float2 m0 = __half22float2(*reinterpret_cast<const __half2*>(&w0));
    const float2 m1 = __half22float2(*reinterpret_cast<const __half2*>(&w1));
    const float2 m2 = __half22float2(*reinterpret_cast<const __half2*>(&w2));
    const float2 m3 = __half22float2(*reinterpret_cast<const __half2*>(&w3));
    const float2 m4 = __half22float2(*reinterpret_cast<const __half2*>(&w4));

    const float sm_x = u0 * m0.x + u1 * m1.x + u2 * m2.x + u3 * m3.x + u4 * m4.x;
    const float sm_y = u0 * m0.y + u1 * m1.y + u2 * m2.y + u3 * m3.y + u4 * m4.y;

    const float ci = 1.0f / 21.0f, cb = 20.0f / 21.0f;
    float2* xp = (float2*)x;
    const float2 xs = xp[tid];
    const float nx_ = fmaf(cb, sm_x, xs.x * ci);
    const float ny_ = fmaf(cb, sm_y, xs.y * ci);
    xp[tid] = make_float2(nx_, ny_);
    ((uint_t*)xh_out)[tid] = ((uint_t)f2bf(ny_) << 16) | (uint_t)f2bf(nx_);
}

// ---------------------------------------------------------------------------
// epilogue: logits = x@Wout + bout ; write logits, x, u (unchanged)
// ---------------------------------------------------------------------------
__global__ __launch_bounds__(256) void final_kernel(const float* __restrict__ x,
                                                    const float* __restrict__ Wout,
                                                    const float* __restrict__ bout,
                                                    const float* __restrict__ ug,
                                                    float* __restrict__ out)
{
    const int nl = threadIdx.x >> 7;
    const int n = blockIdx.x * 2 + nl;
    const int j = threadIdx.x & 127;
    const int lane = threadIdx.x & 63;
    const int wv = threadIdx.x >> 6;
    float xv = x[(size_t)n * 128 + j];
    out[(size_t)NC_ + (size_t)n * 128 + j] = xv;
    float p[8];
    #pragma unroll
    for (int c = 0; c < 8; ++c) p[c] = xv * Wout[j * 8 + c];
    #pragma unroll
    for (int c = 0; c < 8; ++c)
        for (int o = 32; o > 0; o >>= 1) p[c] += __shfl_down(p[c], o, 64);
    __shared__ float sp[4][8];
    if (lane == 0) {
        #pragma unroll
        for (int c = 0; c < 8; ++c) sp[wv][c] = p[c];
    }
    __syncthreads();
    if (j < 8) {
        int c = j;
        out[(size_t)n * 8 + c] = bout[c] + sp[2 * nl][c] + sp[2 * nl + 1][c];
    }
    if (blockIdx.x == 0 && threadIdx.x < 5)
        out[(size_t)NC_ + (size_t)NX_ + threadIdx.x] = ug[threadIdx.x];
}

// ---------------------------------------------------------------------------
extern "C" void kernel_launch(void* const* d_in, const int* in_sizes, int n_in,
                              void* d_out, int out_size, void* d_ws, size_t ws_size,
                              hipStream_t stream)
{
    const float* feat0 = (const float*)d_in[0];
    const float* feat1 = (const float*)d_in[1];
    const float* W0   = (const float*)d_in[2];
    const float* b0   = (const float*)d_in[3];
    const float* W1   = (const float*)d_in[4];
    const float* b1   = (const float*)d_in[5];
    const float* Wm1  = (const float*)d_in[6];
    const float* bm1  = (const float*)d_in[7];
    const float* Wm2  = (const float*)d_in[8];
    const float* bm2  = (const float*)d_in[9];
    const float* Wout = (const float*)d_in[10];
    const float* bout = (const float*)d_in[11];
    const int* src = (const int*)d_in[12];
    const int* dst = (const int*)d_in[13];
    const int* rel = (const int*)d_in[14];
    float* out = (float*)d_out;

    char* p = (char*)d_ws;
    auto alloc = [&](size_t bytes) { char* q = p; p += (bytes + 255) & ~(size_t)255; return q; };
    float*    xbuf      = (float*)   alloc((size_t)NX_ * 4);
    ushort_t* xh0       = (ushort_t*)alloc((size_t)NX_ * 2);
    ushort_t* xh1       = (ushort_t*)alloc((size_t)NX_ * 2);
    uint_t*   mbuf      = (uint_t*)  alloc((size_t)R_ * NL_ * 4);   // 38.4 MB fp16 msgs
    int*      deg_i     = (int*)     alloc((size_t)RN * 4);
    float*    dinv      = (float*)   alloc((size_t)RN * 4);
    int*      rp        = (int*)     alloc(((size_t)RN + 1) * 4);
    int*      fill      = (int*)     alloc((size_t)RN * 4);
    int*      csr_dst   = (int*)     alloc((size_t)E_ * 4);
    float*    csr_w     = (float*)   alloc((size_t)E_ * 4);
    float*    csr_edinv = (float*)   alloc((size_t)E_ * 4);
    float*    accbuf    = (float*)   alloc(128 * 4);
    float*    ug        = (float*)   alloc(64);
    float*    c_l1      = (float*)   alloc(64);
    int*      act       = (int*)     alloc(64);

    hipMemsetAsync(deg_i, 0, (size_t)RN * 4, stream);
    hipMemsetAsync(fill, 0, (size_t)RN * 4, stream);
    hipMemsetAsync(accbuf, 0, 128 * 4, stream);
    init_kernel<<<1, 64, 0, stream>>>(ug, act);

    mlp_kernel<<<N_TOT / 8, 128, 0, stream>>>(feat0, feat1, W0, b0, W1, b1,
                                              Wm1, bm1, Wm2, bm2, xbuf, xh0);

    deg_kernel<<<(E_ + 255) / 256, 256, 0, stream>>>(src, rel, deg_i);
    dinv_kernel<<<(RN + 255) / 256, 256, 0, stream>>>(deg_i, dinv);
    scan_kernel<<<1, 1024, 0, stream>>>(deg_i, rp);
    scatter_kernel<<<(E_ + 255) / 256, 256, 0, stream>>>(src, dst, rel, rp, fill,
                                                         deg_i, dinv,
                                                         csr_dst, csr_w, csr_edinv);

    ushort_t* ha = xh0;
    ushort_t* hb = xh1;
    for (int k = 0; k < 8; ++k) {
        gather_kernel<<<2048, 256, 0, stream>>>(ha, rp, csr_dst, csr_edinv, csr_w,
                                                act, k, accbuf, mbuf);
        scalar_kernel<<<1, 64, 0, stream>>>(accbuf, ug, c_l1, act, k);
        apply_kernel<<<(NL_ + 255) / 256, 256, 0, stream>>>(xbuf, hb, mbuf, ug, act, k);
        ushort_t* t = ha; ha = hb; hb = t;
    }

    final_kernel<<<N_TOT / 2, 256, 0, stream>>>(xbuf, Wout, bout, ug, out);
}

// Round 4
// 604.170 us; speedup vs baseline: 1.1811x; 1.1811x over previous
//
#include <hip/hip_runtime.h>
#include <cmath>

typedef unsigned short ushort_t;
typedef unsigned int uint_t;

#define N_TOT 30000
#define N0_   18000
#define R_    5
#define E_    600000
#define RN    (R_ * N_TOT)
#define NC_   (N_TOT * 8)        // logits elements
#define NX_   (N_TOT * 128)      // x elements

typedef __attribute__((ext_vector_type(8))) short bf16x8;
typedef __attribute__((ext_vector_type(4))) float f32x4;

__device__ __forceinline__ ushort_t f2bf(float f) {
    uint_t u = __float_as_uint(f);
    uint_t r = (u + 0x7fffu + ((u >> 16) & 1u)) >> 16;   // RTNE
    return (ushort_t)r;
}
__device__ __forceinline__ float bflo(uint_t v) { return __uint_as_float(v << 16); }
__device__ __forceinline__ float bfhi(uint_t v) { return __uint_as_float(v & 0xffff0000u); }

// ---------------------------------------------------------------------------
// init: u = 1/R, act[0] = 1
// ---------------------------------------------------------------------------
__global__ void init_kernel(float* ug, int* act) {
    if (threadIdx.x < 5) ug[threadIdx.x] = 0.2f;
    if (threadIdx.x == 0) act[0] = 1;
}

// ---------------------------------------------------------------------------
// bf16 pre-conversion: feats row-major, weights transposed [col][k]
// ---------------------------------------------------------------------------
__global__ __launch_bounds__(256) void cvtfeat_kernel(const float* __restrict__ in,
                                                      ushort_t* __restrict__ out,
                                                      int nelem)
{
    int i = (blockIdx.x * 256 + threadIdx.x) * 4;
    if (i >= nelem) return;
    const float4 v = *(const float4*)(in + i);
    ushort_t o0 = f2bf(v.x), o1 = f2bf(v.y), o2 = f2bf(v.z), o3 = f2bf(v.w);
    uint_t p0 = (uint_t)o0 | ((uint_t)o1 << 16);
    uint_t p1 = (uint_t)o2 | ((uint_t)o3 << 16);
    uint2* op = (uint2*)(out + i);
    *op = make_uint2(p0, p1);
}

__global__ __launch_bounds__(256) void cvtw_kernel(const float* __restrict__ W,
                                                   ushort_t* __restrict__ wt, int K)
{
    int idx = blockIdx.x * 256 + threadIdx.x;   // idx = j*K + k
    if (idx >= 128 * K) return;
    int j = idx / K, k = idx - j * K;
    wt[idx] = f2bf(W[k * 128 + j]);
}

// ---------------------------------------------------------------------------
// MFMA MLP: 32 nodes per 256-thread block (4 waves).  Each wave owns a
// 32-col slice (2 N-tiles of 16); M = 2 tiles of 16.  mfma_f32_16x16x32_bf16.
// A frag: row=lane&15, k=(lane>>4)*8+i (contiguous).  B frag: col=lane&15,
// same k (weights pre-transposed to [col][k]).  D: col=lane&15,
// row=(lane>>4)*4+reg (m89-verified).
// ---------------------------------------------------------------------------
__global__ __launch_bounds__(256) void mlp_mfma_kernel(
    const ushort_t* __restrict__ fb0, const ushort_t* __restrict__ fb1,
    const ushort_t* __restrict__ wt0, const ushort_t* __restrict__ wt1,
    const ushort_t* __restrict__ wtm1, const ushort_t* __restrict__ wtm2,
    const float* __restrict__ b0, const float* __restrict__ b1,
    const float* __restrict__ bm1, const float* __restrict__ bm2,
    float* __restrict__ xout, ushort_t* __restrict__ xh)
{
    const int t = threadIdx.x;
    const int lane = t & 63;
    const int wv = t >> 6;            // 0..3 -> col block wv*32
    const int lr = lane & 15;         // A-row / B-col within tile
    const int lg = lane >> 4;         // k-group, D row-group
    const int row0 = blockIdx.x * 32;

    __shared__ ushort_t hls[32][136];   // bf16 h   (pad: 272B row stride)
    __shared__ float    tls[32][132];   // fp32 t1/t2 (pad: 528B row stride)
    __shared__ ushort_t zls[32][136];   // bf16 z

    // ---------------- GEMM1: h = feat @ W + b -------------------------------
    #pragma unroll
    for (int mt = 0; mt < 2; ++mt) {
        const int rb = row0 + mt * 16;
        const bool is0 = (rb < N0_);
        const int r = min(rb + lr, N_TOT - 1);
        const ushort_t* __restrict__ fa =
            is0 ? fb0 + (size_t)r * 256 : fb1 + (size_t)(r - N0_) * 128;
        const ushort_t* __restrict__ wt = is0 ? wt0 : wt1;
        const int K = is0 ? 256 : 128;
        const int c0 = wv * 32 + lr;

        f32x4 a0 = {0.f, 0.f, 0.f, 0.f};
        f32x4 a1 = {0.f, 0.f, 0.f, 0.f};
        for (int ks = 0; ks < K; ks += 32) {
            const bf16x8 af = *(const bf16x8*)(fa + ks + lg * 8);
            const bf16x8 wb0 = *(const bf16x8*)(wt + (size_t)c0 * K + ks + lg * 8);
            const bf16x8 wb1 = *(const bf16x8*)(wt + (size_t)(c0 + 16) * K + ks + lg * 8);
            a0 = __builtin_amdgcn_mfma_f32_16x16x32_bf16(af, wb0, a0, 0, 0, 0);
            a1 = __builtin_amdgcn_mfma_f32_16x16x32_bf16(af, wb1, a1, 0, 0, 0);
        }
        const float bb0 = is0 ? b0[c0] : b1[c0];
        const float bb1 = is0 ? b0[c0 + 16] : b1[c0 + 16];
        #pragma unroll
        for (int j = 0; j < 4; ++j) {
            hls[mt * 16 + lg * 4 + j][c0]      = f2bf(a0[j] + bb0);
            hls[mt * 16 + lg * 4 + j][c0 + 16] = f2bf(a1[j] + bb1);
        }
    }
    __syncthreads();

    // ---------------- GEMM2: t1 = h @ Wm1 + bm1 -----------------------------
    {
        const int c0 = wv * 32 + lr;
        f32x4 g00 = {0.f,0.f,0.f,0.f}, g01 = {0.f,0.f,0.f,0.f};
        f32x4 g10 = {0.f,0.f,0.f,0.f}, g11 = {0.f,0.f,0.f,0.f};
        for (int ks = 0; ks < 128; ks += 32) {
            const bf16x8 wb0 = *(const bf16x8*)(wtm1 + (size_t)c0 * 128 + ks + lg * 8);
            const bf16x8 wb1 = *(const bf16x8*)(wtm1 + (size_t)(c0 + 16) * 128 + ks + lg * 8);
            const bf16x8 af0 = *(const bf16x8*)(&hls[lr][ks + lg * 8]);
            const bf16x8 af1 = *(const bf16x8*)(&hls[16 + lr][ks + lg * 8]);
            g00 = __builtin_amdgcn_mfma_f32_16x16x32_bf16(af0, wb0, g00, 0, 0, 0);
            g01 = __builtin_amdgcn_mfma_f32_16x16x32_bf16(af0, wb1, g01, 0, 0, 0);
            g10 = __builtin_amdgcn_mfma_f32_16x16x32_bf16(af1, wb0, g10, 0, 0, 0);
            g11 = __builtin_amdgcn_mfma_f32_16x16x32_bf16(af1, wb1, g11, 0, 0, 0);
        }
        const float bb0 = bm1[c0], bb1 = bm1[c0 + 16];
        #pragma unroll
        for (int j = 0; j < 4; ++j) {
            tls[lg * 4 + j][c0]           = g00[j] + bb0;
            tls[lg * 4 + j][c0 + 16]      = g01[j] + bb1;
            tls[16 + lg * 4 + j][c0]      = g10[j] + bb0;
            tls[16 + lg * 4 + j][c0 + 16] = g11[j] + bb1;
        }
    }
    __syncthreads();

    // ---------------- LN + relu -> z (bf16) ---------------------------------
    {
        const int row = t >> 3, seg = t & 7;
        f32x4 v[4];
        float s = 0.f;
        #pragma unroll
        for (int i = 0; i < 4; ++i) {
            v[i] = *(const f32x4*)(&tls[row][seg * 16 + i * 4]);
            s += v[i][0] + v[i][1] + v[i][2] + v[i][3];
        }
        #pragma unroll
        for (int o = 1; o < 8; o <<= 1) s += __shfl_xor(s, o, 64);
        const float mean = s * (1.0f / 128.0f);
        float q = 0.f;
        #pragma unroll
        for (int i = 0; i < 4; ++i) {
            #pragma unroll
            for (int e = 0; e < 4; ++e) { float d = v[i][e] - mean; q = fmaf(d, d, q); }
        }
        #pragma unroll
        for (int o = 1; o < 8; o <<= 1) q += __shfl_xor(q, o, 64);
        const float inv = 1.0f / sqrtf(q * (1.0f / 128.0f) + 1e-5f);
        uint_t* zp = (uint_t*)&zls[row][0];
        #pragma unroll
        for (int i = 0; i < 4; ++i) {
            ushort_t z0 = f2bf(fmaxf((v[i][0] - mean) * inv, 0.0f));
            ushort_t z1 = f2bf(fmaxf((v[i][1] - mean) * inv, 0.0f));
            ushort_t z2 = f2bf(fmaxf((v[i][2] - mean) * inv, 0.0f));
            ushort_t z3 = f2bf(fmaxf((v[i][3] - mean) * inv, 0.0f));
            zp[(seg * 16 + i * 4) / 2]     = (uint_t)z0 | ((uint_t)z1 << 16);
            zp[(seg * 16 + i * 4) / 2 + 1] = (uint_t)z2 | ((uint_t)z3 << 16);
        }
    }
    __syncthreads();

    // ---------------- GEMM3: t2 = z @ Wm2 + bm2 -----------------------------
    {
        const int c0 = wv * 32 + lr;
        f32x4 g00 = {0.f,0.f,0.f,0.f}, g01 = {0.f,0.f,0.f,0.f};
        f32x4 g10 = {0.f,0.f,0.f,0.f}, g11 = {0.f,0.f,0.f,0.f};
        for (int ks = 0; ks < 128; ks += 32) {
            const bf16x8 wb0 = *(const bf16x8*)(wtm2 + (size_t)c0 * 128 + ks + lg * 8);
            const bf16x8 wb1 = *(const bf16x8*)(wtm2 + (size_t)(c0 + 16) * 128 + ks + lg * 8);
            const bf16x8 af0 = *(const bf16x8*)(&zls[lr][ks + lg * 8]);
            const bf16x8 af1 = *(const bf16x8*)(&zls[16 + lr][ks + lg * 8]);
            g00 = __builtin_amdgcn_mfma_f32_16x16x32_bf16(af0, wb0, g00, 0, 0, 0);
            g01 = __builtin_amdgcn_mfma_f32_16x16x32_bf16(af0, wb1, g01, 0, 0, 0);
            g10 = __builtin_amdgcn_mfma_f32_16x16x32_bf16(af1, wb0, g10, 0, 0, 0);
            g11 = __builtin_amdgcn_mfma_f32_16x16x32_bf16(af1, wb1, g11, 0, 0, 0);
        }
        __syncthreads();   // all zls reads done before tls is overwritten below
        const float bb0 = bm2[c0], bb1 = bm2[c0 + 16];
        #pragma unroll
        for (int j = 0; j < 4; ++j) {
            tls[lg * 4 + j][c0]           = g00[j] + bb0;
            tls[lg * 4 + j][c0 + 16]      = g01[j] + bb1;
            tls[16 + lg * 4 + j][c0]      = g10[j] + bb0;
            tls[16 + lg * 4 + j][c0 + 16] = g11[j] + bb1;
        }
    }
    __syncthreads();

    // ---------------- per-row standardization + store -----------------------
    {
        const int row = t >> 3, seg = t & 7;
        const int n = row0 + row;
        f32x4 v[4];
        float s = 0.f;
        #pragma unroll
        for (int i = 0; i < 4; ++i) {
            v[i] = *(const f32x4*)(&tls[row][seg * 16 + i * 4]);
            s += v[i][0] + v[i][1] + v[i][2] + v[i][3];
        }
        #pragma unroll
        for (int o = 1; o < 8; o <<= 1) s += __shfl_xor(s, o, 64);
        const float mu = s * (1.0f / 128.0f);
        float q = 0.f;
        #pragma unroll
        for (int i = 0; i < 4; ++i) {
            #pragma unroll
            for (int e = 0; e < 4; ++e) { float d = v[i][e] - mu; q = fmaf(d, d, q); }
        }
        #pragma unroll
        for (int o = 1; o < 8; o <<= 1) q += __shfl_xor(q, o, 64);
        const float sd = sqrtf(q * (1.0f / 127.0f));
        const float inv = 1.0f / sd;
        if (n < N_TOT) {
            uint_t* xhp = (uint_t*)xh + (size_t)n * 64 + seg * 8;
            float* xop = xout + (size_t)n * 128 + seg * 16;
            #pragma unroll
            for (int i = 0; i < 4; ++i) {
                float rr[4];
                #pragma unroll
                for (int e = 0; e < 4; ++e) {
                    float r = (v[i][e] - mu) * inv;
                    if (!(fabsf(r) <= 3.402823466e38f)) {
                        r = (r != r) ? 0.0f : ((r > 0.0f) ? 3.402823466e38f : -3.402823466e38f);
                    }
                    rr[e] = r;
                }
                *(float4*)(xop + i * 4) = make_float4(rr[0], rr[1], rr[2], rr[3]);
                xhp[i * 2]     = (uint_t)f2bf(rr[0]) | ((uint_t)f2bf(rr[1]) << 16);
                xhp[i * 2 + 1] = (uint_t)f2bf(rr[2]) | ((uint_t)f2bf(rr[3]) << 16);
            }
        }
    }
}

// ---------------------------------------------------------------------------
// preprocessing (unchanged)
// ---------------------------------------------------------------------------
__global__ void deg_kernel(const int* __restrict__ src, const int* __restrict__ rel,
                           int* __restrict__ deg_i)
{
    int e = blockIdx.x * 256 + threadIdx.x;
    if (e >= E_) return;
    atomicAdd(&deg_i[rel[e] * N_TOT + src[e]], 1);
}

__global__ void dinv_kernel(const int* __restrict__ deg_i, float* __restrict__ dinv)
{
    int i = blockIdx.x * 256 + threadIdx.x;
    if (i >= RN) return;
    int dg = deg_i[i];
    dinv[i] = (dg > 0) ? 1.0f / sqrtf((float)dg) : 0.0f;
}

__global__ __launch_bounds__(1024) void scan_kernel(const int* __restrict__ cnt,
                                                    int* __restrict__ rp)
{
    __shared__ int wsum[16];
    __shared__ int s_carry;
    const int t = threadIdx.x, lane = t & 63, w = t >> 6;
    if (t == 0) s_carry = 0;
    __syncthreads();
    const int CH = 8192;
    for (int base = 0; base < RN; base += CH) {
        int v[8]; int s = 0;
        const int i0 = base + t * 8;
        #pragma unroll
        for (int i = 0; i < 8; ++i) { int ii = i0 + i; v[i] = (ii < RN) ? cnt[ii] : 0; s += v[i]; }
        int sc = s;
        #pragma unroll
        for (int o = 1; o < 64; o <<= 1) { int tmp = __shfl_up(sc, o, 64); if (lane >= o) sc += tmp; }
        if (lane == 63) wsum[w] = sc;
        __syncthreads();
        int woff = 0;
        for (int i = 0; i < w; ++i) woff += wsum[i];
        int run = s_carry + woff + (sc - s);
        #pragma unroll
        for (int i = 0; i < 8; ++i) { int ii = i0 + i; if (ii < RN) rp[ii] = run; run += v[i]; }
        int chunk_total = woff + sc;   // valid for t==1023
        __syncthreads();
        if (t == 1023) s_carry += chunk_total;
        __syncthreads();
    }
    if (threadIdx.x == 0) rp[RN] = s_carry;
}

__global__ void scatter_kernel(const int* __restrict__ src, const int* __restrict__ dst,
                               const int* __restrict__ rel, const int* __restrict__ rp,
                               int* __restrict__ fill, const int* __restrict__ deg_i,
                               const float* __restrict__ dinv,
                               int* __restrict__ csr_dst, float* __restrict__ csr_w,
                               float* __restrict__ csr_edinv)
{
    int e = blockIdx.x * 256 + threadIdx.x;
    if (e >= E_) return;
    int s = src[e], r = rel[e], d = dst[e];
    int key = r * N_TOT + s;
    int pos = rp[key] + atomicAdd(&fill[key], 1);
    csr_dst[pos] = d;
    csr_w[pos] = 1.0f / (float)deg_i[key];
    csr_edinv[pos] = dinv[key] * dinv[r * N_TOT + d];
}

// ---------------------------------------------------------------------------
// tv: bf16 gathers (4 B/lane), edge loop unrolled x2
// ---------------------------------------------------------------------------
__global__ __launch_bounds__(256) void tv_kernel(
    const ushort_t* __restrict__ xh, const int* __restrict__ rp,
    const int* __restrict__ csr_dst, const float* __restrict__ csr_edinv,
    const int* __restrict__ act, int k, float* __restrict__ accbuf)
{
    if (act[k] == 0) return;
    const int lane = threadIdx.x & 63;
    const int wv = threadIdx.x >> 6;
    const int wid = blockIdx.x * 4 + wv;
    const int nw = gridDim.x * 4;
    float na[5] = {0, 0, 0, 0, 0};
    float ea[5] = {0, 0, 0, 0, 0};
    for (int n = wid; n < N_TOT; n += nw) {
        const uint_t vs = ((const uint_t*)(xh + (size_t)n * 128))[lane];
        const float sx = bflo(vs), sy = bfhi(vs);
        const float pp = fmaf(sx, sx, sy * sy);
        #pragma unroll
        for (int r = 0; r < 5; ++r) {
            const int e0 = rp[r * N_TOT + n];
            const int e1 = rp[r * N_TOT + n + 1];
            if (e1 > e0) na[r] += pp;
            float acc0 = 0.0f, acc1 = 0.0f;
            int e = e0;
            for (; e + 2 <= e1; e += 2) {
                const int dn0 = csr_dst[e];
                const int dn1 = csr_dst[e + 1];
                const float w0 = csr_edinv[e];
                const float w1 = csr_edinv[e + 1];
                const uint_t v0 = ((const uint_t*)(xh + (size_t)dn0 * 128))[lane];
                const uint_t v1 = ((const uint_t*)(xh + (size_t)dn1 * 128))[lane];
                acc0 = fmaf(w0, fmaf(sx, bflo(v0), sy * bfhi(v0)), acc0);
                acc1 = fmaf(w1, fmaf(sx, bflo(v1), sy * bfhi(v1)), acc1);
            }
            if (e < e1) {
                const int dn0 = csr_dst[e];
                const float w0 = csr_edinv[e];
                const uint_t v0 = ((const uint_t*)(xh + (size_t)dn0 * 128))[lane];
                acc0 = fmaf(w0, fmaf(sx, bflo(v0), sy * bfhi(v0)), acc0);
            }
            ea[r] += acc0 + acc1;
        }
    }
    __shared__ float sacc[4][10];
    #pragma unroll
    for (int r = 0; r < 5; ++r) {
        float a = na[r], b2 = ea[r];
        for (int o = 32; o > 0; o >>= 1) {
            a += __shfl_down(a, o, 64);
            b2 += __shfl_down(b2, o, 64);
        }
        if (lane == 0) { sacc[wv][r] = a; sacc[wv][5 + r] = b2; }
    }
    __syncthreads();
    if (threadIdx.x < 10) {
        float t = sacc[0][threadIdx.x] + sacc[1][threadIdx.x] +
                  sacc[2][threadIdx.x] + sacc[3][threadIdx.x];
        atomicAdd(&accbuf[k * 16 + threadIdx.x], t);
    }
}

// ---------------------------------------------------------------------------
// scalar: fp32 lane-parallel mirror descent (lanes 0..7 of one wave)
// ---------------------------------------------------------------------------
__global__ void scalar_kernel(const float* __restrict__ accbuf, float* __restrict__ ug,
                              float* __restrict__ c_l1, int* __restrict__ act, int k)
{
    if (blockIdx.x != 0 || threadIdx.x >= 8) return;
    const int r = threadIdx.x;
    const int a = act[k];
    float w = (r < 5) ? (accbuf[k * 16 + r] - accbuf[k * 16 + 5 + r]) * (1.0f / 30000.0f)
                      : 0.0f;
    float l1 = fabsf(w);
    for (int o = 4; o > 0; o >>= 1) l1 += __shfl_xor(l1, o, 8);
    if (k == 0 && r == 0) c_l1[0] = l1;
    if (!a) { if (r == 0) act[k + 1] = 0; return; }
    float u = (r < 5) ? ug[r] : 0.0f;
    const float fi = l1 + 3.0f;
    bool mact = true;
    for (int t = 1; t <= 20; ++t) {
        float T = sqrtf(3.2188758248682006f / ((float)t * fi * fi));
        float ta = u * expf(-T * (3.0f * u + w));
        float ssum = ta;
        for (int o = 4; o > 0; o >>= 1) ssum += __shfl_xor(ssum, o, 8);
        float un = ta / ssum;
        float d0 = u - un;
        float dq = d0 * d0;
        for (int o = 4; o > 0; o >>= 1) dq += __shfl_xor(dq, o, 8);
        if (mact) u = un;
        mact = mact && (sqrtf(dq) >= 1e-3f);
    }
    if (r < 5) ug[r] = u;
    if (r == 0) act[k + 1] = (l1 / c_l1[0] >= 0.3f) ? 1 : 0;
}

// ---------------------------------------------------------------------------
// msg + update: bf16 gathers, fp32 x updated IN PLACE, bf16 shadow ping-pong.
// ---------------------------------------------------------------------------
__global__ __launch_bounds__(256) void msg_upd_kernel(
    float* __restrict__ x, const ushort_t* __restrict__ xh_in,
    ushort_t* __restrict__ xh_out,
    const int* __restrict__ rp, const int* __restrict__ csr_dst,
    const float* __restrict__ csr_w, const float* __restrict__ ug,
    const int* __restrict__ act, int k)
{
    if (act[k + 1] == 0) return;
    const int lane = threadIdx.x & 63;
    const int wid = blockIdx.x * 4 + (threadIdx.x >> 6);
    const int nw = gridDim.x * 4;
    const float u0 = ug[0], u1 = ug[1], u2 = ug[2], u3 = ug[3], u4 = ug[4];
    for (int n = wid; n < N_TOT; n += nw) {
        float ax0 = 0.0f, ay0 = 0.0f, ax1 = 0.0f, ay1 = 0.0f;
        #pragma unroll
        for (int r = 0; r < 5; ++r) {
            const float ur = (r == 0) ? u0 : (r == 1) ? u1 : (r == 2) ? u2 : (r == 3) ? u3 : u4;
            const int e0 = rp[r * N_TOT + n];
            const int e1 = rp[r * N_TOT + n + 1];
            int e = e0;
            for (; e + 2 <= e1; e += 2) {
                const float w0 = ur * csr_w[e];
                const float w1 = ur * csr_w[e + 1];
                const int dn0 = csr_dst[e];
                const int dn1 = csr_dst[e + 1];
                const uint_t v0 = ((const uint_t*)(xh_in + (size_t)dn0 * 128))[lane];
                const uint_t v1 = ((const uint_t*)(xh_in + (size_t)dn1 * 128))[lane];
                ax0 = fmaf(w0, bflo(v0), ax0);
                ay0 = fmaf(w0, bfhi(v0), ay0);
                ax1 = fmaf(w1, bflo(v1), ax1);
                ay1 = fmaf(w1, bfhi(v1), ay1);
            }
            if (e < e1) {
                const float w0 = ur * csr_w[e];
                const int dn0 = csr_dst[e];
                const uint_t v0 = ((const uint_t*)(xh_in + (size_t)dn0 * 128))[lane];
                ax0 = fmaf(w0, bflo(v0), ax0);
                ay0 = fmaf(w0, bfhi(v0), ay0);
            }
        }
        const float ci = 1.0f / 21.0f, cb = 20.0f / 21.0f;
        float2* xp = (float2*)(x + (size_t)n * 128);
        const float2 xs = xp[lane];
        const float nx_ = fmaf(cb, ax0 + ax1, xs.x * ci);
        const float ny_ = fmaf(cb, ay0 + ay1, xs.y * ci);
        xp[lane] = make_float2(nx_, ny_);
        ((uint_t*)(xh_out + (size_t)n * 128))[lane] =
            ((uint_t)f2bf(ny_) << 16) | (uint_t)f2bf(nx_);
    }
}

// ---------------------------------------------------------------------------
// epilogue: logits = x@Wout + bout ; write logits, x, u (unchanged)
// ---------------------------------------------------------------------------
__global__ __launch_bounds__(256) void final_kernel(const float* __restrict__ x,
                                                    const float* __restrict__ Wout,
                                                    const float* __restrict__ bout,
                                                    const float* __restrict__ ug,
                                                    float* __restrict__ out)
{
    const int nl = threadIdx.x >> 7;
    const int n = blockIdx.x * 2 + nl;
    const int j = threadIdx.x & 127;
    const int lane = threadIdx.x & 63;
    const int wv = threadIdx.x >> 6;
    float xv = x[(size_t)n * 128 + j];
    out[(size_t)NC_ + (size_t)n * 128 + j] = xv;
    float p[8];
    #pragma unroll
    for (int c = 0; c < 8; ++c) p[c] = xv * Wout[j * 8 + c];
    #pragma unroll
    for (int c = 0; c < 8; ++c)
        for (int o = 32; o > 0; o >>= 1) p[c] += __shfl_down(p[c], o, 64);
    __shared__ float sp[4][8];
    if (lane == 0) {
        #pragma unroll
        for (int c = 0; c < 8; ++c) sp[wv][c] = p[c];
    }
    __syncthreads();
    if (j < 8) {
        int c = j;
        out[(size_t)n * 8 + c] = bout[c] + sp[2 * nl][c] + sp[2 * nl + 1][c];
    }
    if (blockIdx.x == 0 && threadIdx.x < 5)
        out[(size_t)NC_ + (size_t)NX_ + threadIdx.x] = ug[threadIdx.x];
}

// ---------------------------------------------------------------------------
extern "C" void kernel_launch(void* const* d_in, const int* in_sizes, int n_in,
                              void* d_out, int out_size, void* d_ws, size_t ws_size,
                              hipStream_t stream)
{
    const float* feat0 = (const float*)d_in[0];
    const float* feat1 = (const float*)d_in[1];
    const float* W0   = (const float*)d_in[2];
    const float* b0   = (const float*)d_in[3];
    const float* W1   = (const float*)d_in[4];
    const float* b1   = (const float*)d_in[5];
    const float* Wm1  = (const float*)d_in[6];
    const float* bm1  = (const float*)d_in[7];
    const float* Wm2  = (const float*)d_in[8];
    const float* bm2  = (const float*)d_in[9];
    const float* Wout = (const float*)d_in[10];
    const float* bout = (const float*)d_in[11];
    const int* src = (const int*)d_in[12];
    const int* dst = (const int*)d_in[13];
    const int* rel = (const int*)d_in[14];
    float* out = (float*)d_out;

    char* p = (char*)d_ws;
    auto alloc = [&](size_t bytes) { char* q = p; p += (bytes + 255) & ~(size_t)255; return q; };
    float*    xbuf      = (float*)   alloc((size_t)NX_ * 4);
    ushort_t* xh0       = (ushort_t*)alloc((size_t)NX_ * 2);
    ushort_t* xh1       = (ushort_t*)alloc((size_t)NX_ * 2);
    ushort_t* fb0       = (ushort_t*)alloc((size_t)N0_ * 256 * 2);
    ushort_t* fb1       = (ushort_t*)alloc((size_t)(N_TOT - N0_) * 128 * 2);
    ushort_t* wt0       = (ushort_t*)alloc((size_t)128 * 256 * 2);
    ushort_t* wt1       = (ushort_t*)alloc((size_t)128 * 128 * 2);
    ushort_t* wtm1      = (ushort_t*)alloc((size_t)128 * 128 * 2);
    ushort_t* wtm2      = (ushort_t*)alloc((size_t)128 * 128 * 2);
    int*      deg_i     = (int*)     alloc((size_t)RN * 4);
    float*    dinv      = (float*)   alloc((size_t)RN * 4);
    int*      rp        = (int*)     alloc(((size_t)RN + 1) * 4);
    int*      fill      = (int*)     alloc((size_t)RN * 4);
    int*      csr_dst   = (int*)     alloc((size_t)E_ * 4);
    float*    csr_w     = (float*)   alloc((size_t)E_ * 4);
    float*    csr_edinv = (float*)   alloc((size_t)E_ * 4);
    float*    accbuf    = (float*)   alloc(128 * 4);
    float*    ug        = (float*)   alloc(64);
    float*    c_l1      = (float*)   alloc(64);
    int*      act       = (int*)     alloc(64);

    hipMemsetAsync(deg_i, 0, (size_t)RN * 4, stream);
    hipMemsetAsync(fill, 0, (size_t)RN * 4, stream);
    hipMemsetAsync(accbuf, 0, 128 * 4, stream);
    init_kernel<<<1, 64, 0, stream>>>(ug, act);

    // bf16 pre-conversion
    cvtfeat_kernel<<<(N0_ * 256 / 4 + 255) / 256, 256, 0, stream>>>(feat0, fb0, N0_ * 256);
    cvtfeat_kernel<<<((N_TOT - N0_) * 128 / 4 + 255) / 256, 256, 0, stream>>>(
        feat1, fb1, (N_TOT - N0_) * 128);
    cvtw_kernel<<<(128 * 256 + 255) / 256, 256, 0, stream>>>(W0, wt0, 256);
    cvtw_kernel<<<(128 * 128 + 255) / 256, 256, 0, stream>>>(W1, wt1, 128);
    cvtw_kernel<<<(128 * 128 + 255) / 256, 256, 0, stream>>>(Wm1, wtm1, 128);
    cvtw_kernel<<<(128 * 128 + 255) / 256, 256, 0, stream>>>(Wm2, wtm2, 128);

    mlp_mfma_kernel<<<(N_TOT + 31) / 32, 256, 0, stream>>>(
        fb0, fb1, wt0, wt1, wtm1, wtm2, b0, b1, bm1, bm2, xbuf, xh0);

    deg_kernel<<<(E_ + 255) / 256, 256, 0, stream>>>(src, rel, deg_i);
    dinv_kernel<<<(RN + 255) / 256, 256, 0, stream>>>(deg_i, dinv);
    scan_kernel<<<1, 1024, 0, stream>>>(deg_i, rp);
    scatter_kernel<<<(E_ + 255) / 256, 256, 0, stream>>>(src, dst, rel, rp, fill,
                                                         deg_i, dinv,
                                                         csr_dst, csr_w, csr_edinv);

    ushort_t* ha = xh0;
    ushort_t* hb = xh1;
    for (int k = 0; k < 8; ++k) {
        tv_kernel<<<2048, 256, 0, stream>>>(ha, rp, csr_dst, csr_edinv, act, k, accbuf);
        scalar_kernel<<<1, 64, 0, stream>>>(accbuf, ug, c_l1, act, k);
        msg_upd_kernel<<<2048, 256, 0, stream>>>(xbuf, ha, hb, rp, csr_dst, csr_w,
                                                 ug, act, k);
        ushort_t* t = ha; ha = hb; hb = t;
    }

    final_kernel<<<N_TOT / 2, 256, 0, stream>>>(xbuf, Wout, bout, ug, out);
}

// Round 5
// 470.924 us; speedup vs baseline: 1.5153x; 1.2829x over previous
//
#include <hip/hip_runtime.h>
#include <cmath>

typedef unsigned short ushort_t;
typedef unsigned int uint_t;

#define N_TOT 30000
#define N0_   18000
#define R_    5
#define E_    600000
#define RN    (R_ * N_TOT)
#define NC_   (N_TOT * 8)        // logits elements
#define NX_   (N_TOT * 128)      // x elements
#define SCAN_NB ((RN + 1023) / 1024)   // 147 blocks of 1024 elements

typedef __attribute__((ext_vector_type(8))) short bf16x8;
typedef __attribute__((ext_vector_type(4))) float f32x4;

__device__ __forceinline__ ushort_t f2bf(float f) {
    uint_t u = __float_as_uint(f);
    uint_t r = (u + 0x7fffu + ((u >> 16) & 1u)) >> 16;   // RTNE
    return (ushort_t)r;
}
__device__ __forceinline__ float bflo(uint_t v) { return __uint_as_float(v << 16); }
__device__ __forceinline__ float bfhi(uint_t v) { return __uint_as_float(v & 0xffff0000u); }

// ---------------------------------------------------------------------------
// init: u = 1/R, act[0] = 1
// ---------------------------------------------------------------------------
__global__ void init_kernel(float* ug, int* act) {
    if (threadIdx.x < 5) ug[threadIdx.x] = 0.2f;
    if (threadIdx.x == 0) act[0] = 1;
}

// ---------------------------------------------------------------------------
// bf16 pre-conversion: feats row-major, weights transposed [col][k]
// ---------------------------------------------------------------------------
__global__ __launch_bounds__(256) void cvtfeat_kernel(const float* __restrict__ in,
                                                      ushort_t* __restrict__ out,
                                                      int nelem)
{
    int i = (blockIdx.x * 256 + threadIdx.x) * 4;
    if (i >= nelem) return;
    const float4 v = *(const float4*)(in + i);
    ushort_t o0 = f2bf(v.x), o1 = f2bf(v.y), o2 = f2bf(v.z), o3 = f2bf(v.w);
    uint_t p0 = (uint_t)o0 | ((uint_t)o1 << 16);
    uint_t p1 = (uint_t)o2 | ((uint_t)o3 << 16);
    uint2* op = (uint2*)(out + i);
    *op = make_uint2(p0, p1);
}

__global__ __launch_bounds__(256) void cvtw_kernel(const float* __restrict__ W,
                                                   ushort_t* __restrict__ wt, int K)
{
    int idx = blockIdx.x * 256 + threadIdx.x;   // idx = j*K + k
    if (idx >= 128 * K) return;
    int j = idx / K, k = idx - j * K;
    wt[idx] = f2bf(W[k * 128 + j]);
}

// ---------------------------------------------------------------------------
// MFMA MLP: 32 nodes per 256-thread block (4 waves) — unchanged from R4.
// ---------------------------------------------------------------------------
__global__ __launch_bounds__(256) void mlp_mfma_kernel(
    const ushort_t* __restrict__ fb0, const ushort_t* __restrict__ fb1,
    const ushort_t* __restrict__ wt0, const ushort_t* __restrict__ wt1,
    const ushort_t* __restrict__ wtm1, const ushort_t* __restrict__ wtm2,
    const float* __restrict__ b0, const float* __restrict__ b1,
    const float* __restrict__ bm1, const float* __restrict__ bm2,
    float* __restrict__ xout, ushort_t* __restrict__ xh)
{
    const int t = threadIdx.x;
    const int lane = t & 63;
    const int wv = t >> 6;            // 0..3 -> col block wv*32
    const int lr = lane & 15;         // A-row / B-col within tile
    const int lg = lane >> 4;         // k-group, D row-group
    const int row0 = blockIdx.x * 32;

    __shared__ ushort_t hls[32][136];   // bf16 h   (pad: 272B row stride)
    __shared__ float    tls[32][132];   // fp32 t1/t2 (pad: 528B row stride)
    __shared__ ushort_t zls[32][136];   // bf16 z

    // ---------------- GEMM1: h = feat @ W + b -------------------------------
    #pragma unroll
    for (int mt = 0; mt < 2; ++mt) {
        const int rb = row0 + mt * 16;
        const bool is0 = (rb < N0_);
        const int r = min(rb + lr, N_TOT - 1);
        const ushort_t* __restrict__ fa =
            is0 ? fb0 + (size_t)r * 256 : fb1 + (size_t)(r - N0_) * 128;
        const ushort_t* __restrict__ wt = is0 ? wt0 : wt1;
        const int K = is0 ? 256 : 128;
        const int c0 = wv * 32 + lr;

        f32x4 a0 = {0.f, 0.f, 0.f, 0.f};
        f32x4 a1 = {0.f, 0.f, 0.f, 0.f};
        for (int ks = 0; ks < K; ks += 32) {
            const bf16x8 af = *(const bf16x8*)(fa + ks + lg * 8);
            const bf16x8 wb0 = *(const bf16x8*)(wt + (size_t)c0 * K + ks + lg * 8);
            const bf16x8 wb1 = *(const bf16x8*)(wt + (size_t)(c0 + 16) * K + ks + lg * 8);
            a0 = __builtin_amdgcn_mfma_f32_16x16x32_bf16(af, wb0, a0, 0, 0, 0);
            a1 = __builtin_amdgcn_mfma_f32_16x16x32_bf16(af, wb1, a1, 0, 0, 0);
        }
        const float bb0 = is0 ? b0[c0] : b1[c0];
        const float bb1 = is0 ? b0[c0 + 16] : b1[c0 + 16];
        #pragma unroll
        for (int j = 0; j < 4; ++j) {
            hls[mt * 16 + lg * 4 + j][c0]      = f2bf(a0[j] + bb0);
            hls[mt * 16 + lg * 4 + j][c0 + 16] = f2bf(a1[j] + bb1);
        }
    }
    __syncthreads();

    // ---------------- GEMM2: t1 = h @ Wm1 + bm1 -----------------------------
    {
        const int c0 = wv * 32 + lr;
        f32x4 g00 = {0.f,0.f,0.f,0.f}, g01 = {0.f,0.f,0.f,0.f};
        f32x4 g10 = {0.f,0.f,0.f,0.f}, g11 = {0.f,0.f,0.f,0.f};
        for (int ks = 0; ks < 128; ks += 32) {
            const bf16x8 wb0 = *(const bf16x8*)(wtm1 + (size_t)c0 * 128 + ks + lg * 8);
            const bf16x8 wb1 = *(const bf16x8*)(wtm1 + (size_t)(c0 + 16) * 128 + ks + lg * 8);
            const bf16x8 af0 = *(const bf16x8*)(&hls[lr][ks + lg * 8]);
            const bf16x8 af1 = *(const bf16x8*)(&hls[16 + lr][ks + lg * 8]);
            g00 = __builtin_amdgcn_mfma_f32_16x16x32_bf16(af0, wb0, g00, 0, 0, 0);
            g01 = __builtin_amdgcn_mfma_f32_16x16x32_bf16(af0, wb1, g01, 0, 0, 0);
            g10 = __builtin_amdgcn_mfma_f32_16x16x32_bf16(af1, wb0, g10, 0, 0, 0);
            g11 = __builtin_amdgcn_mfma_f32_16x16x32_bf16(af1, wb1, g11, 0, 0, 0);
        }
        const float bb0 = bm1[c0], bb1 = bm1[c0 + 16];
        #pragma unroll
        for (int j = 0; j < 4; ++j) {
            tls[lg * 4 + j][c0]           = g00[j] + bb0;
            tls[lg * 4 + j][c0 + 16]      = g01[j] + bb1;
            tls[16 + lg * 4 + j][c0]      = g10[j] + bb0;
            tls[16 + lg * 4 + j][c0 + 16] = g11[j] + bb1;
        }
    }
    __syncthreads();

    // ---------------- LN + relu -> z (bf16) ---------------------------------
    {
        const int row = t >> 3, seg = t & 7;
        f32x4 v[4];
        float s = 0.f;
        #pragma unroll
        for (int i = 0; i < 4; ++i) {
            v[i] = *(const f32x4*)(&tls[row][seg * 16 + i * 4]);
            s += v[i][0] + v[i][1] + v[i][2] + v[i][3];
        }
        #pragma unroll
        for (int o = 1; o < 8; o <<= 1) s += __shfl_xor(s, o, 64);
        const float mean = s * (1.0f / 128.0f);
        float q = 0.f;
        #pragma unroll
        for (int i = 0; i < 4; ++i) {
            #pragma unroll
            for (int e = 0; e < 4; ++e) { float d = v[i][e] - mean; q = fmaf(d, d, q); }
        }
        #pragma unroll
        for (int o = 1; o < 8; o <<= 1) q += __shfl_xor(q, o, 64);
        const float inv = 1.0f / sqrtf(q * (1.0f / 128.0f) + 1e-5f);
        uint_t* zp = (uint_t*)&zls[row][0];
        #pragma unroll
        for (int i = 0; i < 4; ++i) {
            ushort_t z0 = f2bf(fmaxf((v[i][0] - mean) * inv, 0.0f));
            ushort_t z1 = f2bf(fmaxf((v[i][1] - mean) * inv, 0.0f));
            ushort_t z2 = f2bf(fmaxf((v[i][2] - mean) * inv, 0.0f));
            ushort_t z3 = f2bf(fmaxf((v[i][3] - mean) * inv, 0.0f));
            zp[(seg * 16 + i * 4) / 2]     = (uint_t)z0 | ((uint_t)z1 << 16);
            zp[(seg * 16 + i * 4) / 2 + 1] = (uint_t)z2 | ((uint_t)z3 << 16);
        }
    }
    __syncthreads();

    // ---------------- GEMM3: t2 = z @ Wm2 + bm2 -----------------------------
    {
        const int c0 = wv * 32 + lr;
        f32x4 g00 = {0.f,0.f,0.f,0.f}, g01 = {0.f,0.f,0.f,0.f};
        f32x4 g10 = {0.f,0.f,0.f,0.f}, g11 = {0.f,0.f,0.f,0.f};
        for (int ks = 0; ks < 128; ks += 32) {
            const bf16x8 wb0 = *(const bf16x8*)(wtm2 + (size_t)c0 * 128 + ks + lg * 8);
            const bf16x8 wb1 = *(const bf16x8*)(wtm2 + (size_t)(c0 + 16) * 128 + ks + lg * 8);
            const bf16x8 af0 = *(const bf16x8*)(&zls[lr][ks + lg * 8]);
            const bf16x8 af1 = *(const bf16x8*)(&zls[16 + lr][ks + lg * 8]);
            g00 = __builtin_amdgcn_mfma_f32_16x16x32_bf16(af0, wb0, g00, 0, 0, 0);
            g01 = __builtin_amdgcn_mfma_f32_16x16x32_bf16(af0, wb1, g01, 0, 0, 0);
            g10 = __builtin_amdgcn_mfma_f32_16x16x32_bf16(af1, wb0, g10, 0, 0, 0);
            g11 = __builtin_amdgcn_mfma_f32_16x16x32_bf16(af1, wb1, g11, 0, 0, 0);
        }
        __syncthreads();   // all zls reads done before tls is overwritten below
        const float bb0 = bm2[c0], bb1 = bm2[c0 + 16];
        #pragma unroll
        for (int j = 0; j < 4; ++j) {
            tls[lg * 4 + j][c0]           = g00[j] + bb0;
            tls[lg * 4 + j][c0 + 16]      = g01[j] + bb1;
            tls[16 + lg * 4 + j][c0]      = g10[j] + bb0;
            tls[16 + lg * 4 + j][c0 + 16] = g11[j] + bb1;
        }
    }
    __syncthreads();

    // ---------------- per-row standardization + store -----------------------
    {
        const int row = t >> 3, seg = t & 7;
        const int n = row0 + row;
        f32x4 v[4];
        float s = 0.f;
        #pragma unroll
        for (int i = 0; i < 4; ++i) {
            v[i] = *(const f32x4*)(&tls[row][seg * 16 + i * 4]);
            s += v[i][0] + v[i][1] + v[i][2] + v[i][3];
        }
        #pragma unroll
        for (int o = 1; o < 8; o <<= 1) s += __shfl_xor(s, o, 64);
        const float mu = s * (1.0f / 128.0f);
        float q = 0.f;
        #pragma unroll
        for (int i = 0; i < 4; ++i) {
            #pragma unroll
            for (int e = 0; e < 4; ++e) { float d = v[i][e] - mu; q = fmaf(d, d, q); }
        }
        #pragma unroll
        for (int o = 1; o < 8; o <<= 1) q += __shfl_xor(q, o, 64);
        const float sd = sqrtf(q * (1.0f / 127.0f));
        const float inv = 1.0f / sd;
        if (n < N_TOT) {
            uint_t* xhp = (uint_t*)xh + (size_t)n * 64 + seg * 8;
            float* xop = xout + (size_t)n * 128 + seg * 16;
            #pragma unroll
            for (int i = 0; i < 4; ++i) {
                float rr[4];
                #pragma unroll
                for (int e = 0; e < 4; ++e) {
                    float r = (v[i][e] - mu) * inv;
                    if (!(fabsf(r) <= 3.402823466e38f)) {
                        r = (r != r) ? 0.0f : ((r > 0.0f) ? 3.402823466e38f : -3.402823466e38f);
                    }
                    rr[e] = r;
                }
                *(float4*)(xop + i * 4) = make_float4(rr[0], rr[1], rr[2], rr[3]);
                xhp[i * 2]     = (uint_t)f2bf(rr[0]) | ((uint_t)f2bf(rr[1]) << 16);
                xhp[i * 2 + 1] = (uint_t)f2bf(rr[2]) | ((uint_t)f2bf(rr[3]) << 16);
            }
        }
    }
}

// ---------------------------------------------------------------------------
// preprocessing
// ---------------------------------------------------------------------------
__global__ void deg_kernel(const int* __restrict__ src, const int* __restrict__ rel,
                           int* __restrict__ deg_i)
{
    int e = blockIdx.x * 256 + threadIdx.x;
    if (e >= E_) return;
    atomicAdd(&deg_i[rel[e] * N_TOT + src[e]], 1);
}

__global__ void dinv_kernel(const int* __restrict__ deg_i, float* __restrict__ dinv)
{
    int i = blockIdx.x * 256 + threadIdx.x;
    if (i >= RN) return;
    int dg = deg_i[i];
    dinv[i] = (dg > 0) ? 1.0f / sqrtf((float)dg) : 0.0f;
}

// ---------------------------------------------------------------------------
// 3-pass parallel exclusive scan over RN elements (replaces 1-block scan).
// scan1: per-block (1024 elems) exclusive prefix + block totals
// scan2: exclusive scan of the 147 block totals (1 block)
// scan3: add block offsets
// ---------------------------------------------------------------------------
__global__ __launch_bounds__(256) void scan1_kernel(const int* __restrict__ cnt,
                                                    int* __restrict__ rp,
                                                    int* __restrict__ bsum)
{
    __shared__ int wsum[4];
    const int t = threadIdx.x, lane = t & 63, w = t >> 6;
    const int i0 = blockIdx.x * 1024 + t * 4;
    const int v0 = (i0 + 0 < RN) ? cnt[i0 + 0] : 0;
    const int v1 = (i0 + 1 < RN) ? cnt[i0 + 1] : 0;
    const int v2 = (i0 + 2 < RN) ? cnt[i0 + 2] : 0;
    const int v3 = (i0 + 3 < RN) ? cnt[i0 + 3] : 0;
    const int s = v0 + v1 + v2 + v3;
    int sc = s;
    #pragma unroll
    for (int o = 1; o < 64; o <<= 1) { int tmp = __shfl_up(sc, o, 64); if (lane >= o) sc += tmp; }
    if (lane == 63) wsum[w] = sc;
    __syncthreads();
    int woff = 0;
    #pragma unroll
    for (int i = 0; i < 3; ++i) if (i < w) woff += wsum[i];
    int run = woff + sc - s;                 // exclusive within block
    if (i0 + 0 < RN) rp[i0 + 0] = run; run += v0;
    if (i0 + 1 < RN) rp[i0 + 1] = run; run += v1;
    if (i0 + 2 < RN) rp[i0 + 2] = run; run += v2;
    if (i0 + 3 < RN) rp[i0 + 3] = run;
    if (t == 255) bsum[blockIdx.x] = woff + sc;   // block total
}

__global__ __launch_bounds__(256) void scan2_kernel(const int* __restrict__ bsum,
                                                    int* __restrict__ boff,
                                                    int* __restrict__ rp)
{
    __shared__ int wsum[4];
    const int t = threadIdx.x, lane = t & 63, w = t >> 6;
    const int v = (t < SCAN_NB) ? bsum[t] : 0;
    int sc = v;
    #pragma unroll
    for (int o = 1; o < 64; o <<= 1) { int tmp = __shfl_up(sc, o, 64); if (lane >= o) sc += tmp; }
    if (lane == 63) wsum[w] = sc;
    __syncthreads();
    int woff = 0;
    #pragma unroll
    for (int i = 0; i < 3; ++i) if (i < w) woff += wsum[i];
    boff[t] = woff + sc - v;                 // exclusive block offset
    if (t == 0) rp[RN] = E_;                 // total degree == E
}

__global__ __launch_bounds__(256) void scan3_kernel(int* __restrict__ rp,
                                                    const int* __restrict__ boff)
{
    const int off = boff[blockIdx.x];
    if (off == 0) return;
    const int i0 = blockIdx.x * 1024 + threadIdx.x * 4;
    if (i0 + 3 < RN) {
        int4* p = (int4*)(rp + i0);
        int4 q = *p;
        q.x += off; q.y += off; q.z += off; q.w += off;
        *p = q;
    } else {
        for (int i = 0; i < 4; ++i)
            if (i0 + i < RN) rp[i0 + i] += off;
    }
}

__global__ void scatter_kernel(const int* __restrict__ src, const int* __restrict__ dst,
                               const int* __restrict__ rel, const int* __restrict__ rp,
                               int* __restrict__ fill, const int* __restrict__ deg_i,
                               const float* __restrict__ dinv,
                               int* __restrict__ csr_dst, float* __restrict__ csr_w,
                               float* __restrict__ csr_edinv)
{
    int e = blockIdx.x * 256 + threadIdx.x;
    if (e >= E_) return;
    int s = src[e], r = rel[e], d = dst[e];
    int key = r * N_TOT + s;
    int pos = rp[key] + atomicAdd(&fill[key], 1);
    csr_dst[pos] = d;
    csr_w[pos] = 1.0f / (float)deg_i[key];
    csr_edinv[pos] = dinv[key] * dinv[r * N_TOT + d];
}

// ---------------------------------------------------------------------------
// tv: bf16 gathers (4 B/lane), edge loop unrolled x2
// ---------------------------------------------------------------------------
__global__ __launch_bounds__(256) void tv_kernel(
    const ushort_t* __restrict__ xh, const int* __restrict__ rp,
    const int* __restrict__ csr_dst, const float* __restrict__ csr_edinv,
    const int* __restrict__ act, int k, float* __restrict__ accbuf)
{
    if (act[k] == 0) return;
    const int lane = threadIdx.x & 63;
    const int wv = threadIdx.x >> 6;
    const int wid = blockIdx.x * 4 + wv;
    const int nw = gridDim.x * 4;
    float na[5] = {0, 0, 0, 0, 0};
    float ea[5] = {0, 0, 0, 0, 0};
    for (int n = wid; n < N_TOT; n += nw) {
        const uint_t vs = ((const uint_t*)(xh + (size_t)n * 128))[lane];
        const float sx = bflo(vs), sy = bfhi(vs);
        const float pp = fmaf(sx, sx, sy * sy);
        #pragma unroll
        for (int r = 0; r < 5; ++r) {
            const int e0 = rp[r * N_TOT + n];
            const int e1 = rp[r * N_TOT + n + 1];
            if (e1 > e0) na[r] += pp;
            float acc0 = 0.0f, acc1 = 0.0f;
            int e = e0;
            for (; e + 2 <= e1; e += 2) {
                const int dn0 = csr_dst[e];
                const int dn1 = csr_dst[e + 1];
                const float w0 = csr_edinv[e];
                const float w1 = csr_edinv[e + 1];
                const uint_t v0 = ((const uint_t*)(xh + (size_t)dn0 * 128))[lane];
                const uint_t v1 = ((const uint_t*)(xh + (size_t)dn1 * 128))[lane];
                acc0 = fmaf(w0, fmaf(sx, bflo(v0), sy * bfhi(v0)), acc0);
                acc1 = fmaf(w1, fmaf(sx, bflo(v1), sy * bfhi(v1)), acc1);
            }
            if (e < e1) {
                const int dn0 = csr_dst[e];
                const float w0 = csr_edinv[e];
                const uint_t v0 = ((const uint_t*)(xh + (size_t)dn0 * 128))[lane];
                acc0 = fmaf(w0, fmaf(sx, bflo(v0), sy * bfhi(v0)), acc0);
            }
            ea[r] += acc0 + acc1;
        }
    }
    __shared__ float sacc[4][10];
    #pragma unroll
    for (int r = 0; r < 5; ++r) {
        float a = na[r], b2 = ea[r];
        for (int o = 32; o > 0; o >>= 1) {
            a += __shfl_down(a, o, 64);
            b2 += __shfl_down(b2, o, 64);
        }
        if (lane == 0) { sacc[wv][r] = a; sacc[wv][5 + r] = b2; }
    }
    __syncthreads();
    if (threadIdx.x < 10) {
        float t = sacc[0][threadIdx.x] + sacc[1][threadIdx.x] +
                  sacc[2][threadIdx.x] + sacc[3][threadIdx.x];
        atomicAdd(&accbuf[k * 16 + threadIdx.x], t);
    }
}

// ---------------------------------------------------------------------------
// scalar: fp32 lane-parallel mirror descent (lanes 0..7 of one wave)
// ---------------------------------------------------------------------------
__global__ void scalar_kernel(const float* __restrict__ accbuf, float* __restrict__ ug,
                              float* __restrict__ c_l1, int* __restrict__ act, int k)
{
    if (blockIdx.x != 0 || threadIdx.x >= 8) return;
    const int r = threadIdx.x;
    const int a = act[k];
    float w = (r < 5) ? (accbuf[k * 16 + r] - accbuf[k * 16 + 5 + r]) * (1.0f / 30000.0f)
                      : 0.0f;
    float l1 = fabsf(w);
    for (int o = 4; o > 0; o >>= 1) l1 += __shfl_xor(l1, o, 8);
    if (k == 0 && r == 0) c_l1[0] = l1;
    if (!a) { if (r == 0) act[k + 1] = 0; return; }
    float u = (r < 5) ? ug[r] : 0.0f;
    const float fi = l1 + 3.0f;
    bool mact = true;
    for (int t = 1; t <= 20; ++t) {
        float T = sqrtf(3.2188758248682006f / ((float)t * fi * fi));
        float ta = u * expf(-T * (3.0f * u + w));
        float ssum = ta;
        for (int o = 4; o > 0; o >>= 1) ssum += __shfl_xor(ssum, o, 8);
        float un = ta / ssum;
        float d0 = u - un;
        float dq = d0 * d0;
        for (int o = 4; o > 0; o >>= 1) dq += __shfl_xor(dq, o, 8);
        if (mact) u = un;
        mact = mact && (sqrtf(dq) >= 1e-3f);
    }
    if (r < 5) ug[r] = u;
    if (r == 0) act[k + 1] = (l1 / c_l1[0] >= 0.3f) ? 1 : 0;
}

// ---------------------------------------------------------------------------
// msg + update: bf16 gathers, fp32 x updated IN PLACE, bf16 shadow ping-pong.
// ---------------------------------------------------------------------------
__global__ __launch_bounds__(256) void msg_upd_kernel(
    float* __restrict__ x, const ushort_t* __restrict__ xh_in,
    ushort_t* __restrict__ xh_out,
    const int* __restrict__ rp, const int* __restrict__ csr_dst,
    const float* __restrict__ csr_w, const float* __restrict__ ug,
    const int* __restrict__ act, int k)
{
    if (act[k + 1] == 0) return;
    const int lane = threadIdx.x & 63;
    const int wid = blockIdx.x * 4 + (threadIdx.x >> 6);
    const int nw = gridDim.x * 4;
    const float u0 = ug[0], u1 = ug[1], u2 = ug[2], u3 = ug[3], u4 = ug[4];
    for (int n = wid; n < N_TOT; n += nw) {
        float ax0 = 0.0f, ay0 = 0.0f, ax1 = 0.0f, ay1 = 0.0f;
        #pragma unroll
        for (int r = 0; r < 5; ++r) {
            const float ur = (r == 0) ? u0 : (r == 1) ? u1 : (r == 2) ? u2 : (r == 3) ? u3 : u4;
            const int e0 = rp[r * N_TOT + n];
            const int e1 = rp[r * N_TOT + n + 1];
            int e = e0;
            for (; e + 2 <= e1; e += 2) {
                const float w0 = ur * csr_w[e];
                const float w1 = ur * csr_w[e + 1];
                const int dn0 = csr_dst[e];
                const int dn1 = csr_dst[e + 1];
                const uint_t v0 = ((const uint_t*)(xh_in + (size_t)dn0 * 128))[lane];
                const uint_t v1 = ((const uint_t*)(xh_in + (size_t)dn1 * 128))[lane];
                ax0 = fmaf(w0, bflo(v0), ax0);
                ay0 = fmaf(w0, bfhi(v0), ay0);
                ax1 = fmaf(w1, bflo(v1), ax1);
                ay1 = fmaf(w1, bfhi(v1), ay1);
            }
            if (e < e1) {
                const float w0 = ur * csr_w[e];
                const int dn0 = csr_dst[e];
                const uint_t v0 = ((const uint_t*)(xh_in + (size_t)dn0 * 128))[lane];
                ax0 = fmaf(w0, bflo(v0), ax0);
                ay0 = fmaf(w0, bfhi(v0), ay0);
            }
        }
        const float ci = 1.0f / 21.0f, cb = 20.0f / 21.0f;
        float2* xp = (float2*)(x + (size_t)n * 128);
        const float2 xs = xp[lane];
        const float nx_ = fmaf(cb, ax0 + ax1, xs.x * ci);
        const float ny_ = fmaf(cb, ay0 + ay1, xs.y * ci);
        xp[lane] = make_float2(nx_, ny_);
        ((uint_t*)(xh_out + (size_t)n * 128))[lane] =
            ((uint_t)f2bf(ny_) << 16) | (uint_t)f2bf(nx_);
    }
}

// ---------------------------------------------------------------------------
// epilogue: logits = x@Wout + bout ; write logits, x, u (unchanged)
// ---------------------------------------------------------------------------
__global__ __launch_bounds__(256) void final_kernel(const float* __restrict__ x,
                                                    const float* __restrict__ Wout,
                                                    const float* __restrict__ bout,
                                                    const float* __restrict__ ug,
                                                    float* __restrict__ out)
{
    const int nl = threadIdx.x >> 7;
    const int n = blockIdx.x * 2 + nl;
    const int j = threadIdx.x & 127;
    const int lane = threadIdx.x & 63;
    const int wv = threadIdx.x >> 6;
    float xv = x[(size_t)n * 128 + j];
    out[(size_t)NC_ + (size_t)n * 128 + j] = xv;
    float p[8];
    #pragma unroll
    for (int c = 0; c < 8; ++c) p[c] = xv * Wout[j * 8 + c];
    #pragma unroll
    for (int c = 0; c < 8; ++c)
        for (int o = 32; o > 0; o >>= 1) p[c] += __shfl_down(p[c], o, 64);
    __shared__ float sp[4][8];
    if (lane == 0) {
        #pragma unroll
        for (int c = 0; c < 8; ++c) sp[wv][c] = p[c];
    }
    __syncthreads();
    if (j < 8) {
        int c = j;
        out[(size_t)n * 8 + c] = bout[c] + sp[2 * nl][c] + sp[2 * nl + 1][c];
    }
    if (blockIdx.x == 0 && threadIdx.x < 5)
        out[(size_t)NC_ + (size_t)NX_ + threadIdx.x] = ug[threadIdx.x];
}

// ---------------------------------------------------------------------------
extern "C" void kernel_launch(void* const* d_in, const int* in_sizes, int n_in,
                              void* d_out, int out_size, void* d_ws, size_t ws_size,
                              hipStream_t stream)
{
    const float* feat0 = (const float*)d_in[0];
    const float* feat1 = (const float*)d_in[1];
    const float* W0   = (const float*)d_in[2];
    const float* b0   = (const float*)d_in[3];
    const float* W1   = (const float*)d_in[4];
    const float* b1   = (const float*)d_in[5];
    const float* Wm1  = (const float*)d_in[6];
    const float* bm1  = (const float*)d_in[7];
    const float* Wm2  = (const float*)d_in[8];
    const float* bm2  = (const float*)d_in[9];
    const float* Wout = (const float*)d_in[10];
    const float* bout = (const float*)d_in[11];
    const int* src = (const int*)d_in[12];
    const int* dst = (const int*)d_in[13];
    const int* rel = (const int*)d_in[14];
    float* out = (float*)d_out;

    char* p = (char*)d_ws;
    auto alloc = [&](size_t bytes) { char* q = p; p += (bytes + 255) & ~(size_t)255; return q; };
    float*    xbuf      = (float*)   alloc((size_t)NX_ * 4);
    ushort_t* xh0       = (ushort_t*)alloc((size_t)NX_ * 2);
    ushort_t* xh1       = (ushort_t*)alloc((size_t)NX_ * 2);
    ushort_t* fb0       = (ushort_t*)alloc((size_t)N0_ * 256 * 2);
    ushort_t* fb1       = (ushort_t*)alloc((size_t)(N_TOT - N0_) * 128 * 2);
    ushort_t* wt0       = (ushort_t*)alloc((size_t)128 * 256 * 2);
    ushort_t* wt1       = (ushort_t*)alloc((size_t)128 * 128 * 2);
    ushort_t* wtm1      = (ushort_t*)alloc((size_t)128 * 128 * 2);
    ushort_t* wtm2      = (ushort_t*)alloc((size_t)128 * 128 * 2);
    int*      deg_i     = (int*)     alloc((size_t)RN * 4);
    float*    dinv      = (float*)   alloc((size_t)RN * 4);
    int*      rp        = (int*)     alloc(((size_t)RN + 1) * 4);
    int*      fill      = (int*)     alloc((size_t)RN * 4);
    int*      bsum      = (int*)     alloc((size_t)SCAN_NB * 4);
    int*      boff      = (int*)     alloc(256 * 4);
    int*      csr_dst   = (int*)     alloc((size_t)E_ * 4);
    float*    csr_w     = (float*)   alloc((size_t)E_ * 4);
    float*    csr_edinv = (float*)   alloc((size_t)E_ * 4);
    float*    accbuf    = (float*)   alloc(128 * 4);
    float*    ug        = (float*)   alloc(64);
    float*    c_l1      = (float*)   alloc(64);
    int*      act       = (int*)     alloc(64);

    hipMemsetAsync(deg_i, 0, (size_t)RN * 4, stream);
    hipMemsetAsync(fill, 0, (size_t)RN * 4, stream);
    hipMemsetAsync(accbuf, 0, 128 * 4, stream);
    init_kernel<<<1, 64, 0, stream>>>(ug, act);

    // bf16 pre-conversion
    cvtfeat_kernel<<<(N0_ * 256 / 4 + 255) / 256, 256, 0, stream>>>(feat0, fb0, N0_ * 256);
    cvtfeat_kernel<<<((N_TOT - N0_) * 128 / 4 + 255) / 256, 256, 0, stream>>>(
        feat1, fb1, (N_TOT - N0_) * 128);
    cvtw_kernel<<<(128 * 256 + 255) / 256, 256, 0, stream>>>(W0, wt0, 256);
    cvtw_kernel<<<(128 * 128 + 255) / 256, 256, 0, stream>>>(W1, wt1, 128);
    cvtw_kernel<<<(128 * 128 + 255) / 256, 256, 0, stream>>>(Wm1, wtm1, 128);
    cvtw_kernel<<<(128 * 128 + 255) / 256, 256, 0, stream>>>(Wm2, wtm2, 128);

    mlp_mfma_kernel<<<(N_TOT + 31) / 32, 256, 0, stream>>>(
        fb0, fb1, wt0, wt1, wtm1, wtm2, b0, b1, bm1, bm2, xbuf, xh0);

    deg_kernel<<<(E_ + 255) / 256, 256, 0, stream>>>(src, rel, deg_i);
    dinv_kernel<<<(RN + 255) / 256, 256, 0, stream>>>(deg_i, dinv);
    scan1_kernel<<<SCAN_NB, 256, 0, stream>>>(deg_i, rp, bsum);
    scan2_kernel<<<1, 256, 0, stream>>>(bsum, boff, rp);
    scan3_kernel<<<SCAN_NB, 256, 0, stream>>>(rp, boff);
    scatter_kernel<<<(E_ + 255) / 256, 256, 0, stream>>>(src, dst, rel, rp, fill,
                                                         deg_i, dinv,
                                                         csr_dst, csr_w, csr_edinv);

    ushort_t* ha = xh0;
    ushort_t* hb = xh1;
    for (int k = 0; k < 8; ++k) {
        tv_kernel<<<2048, 256, 0, stream>>>(ha, rp, csr_dst, csr_edinv, act, k, accbuf);
        scalar_kernel<<<1, 64, 0, stream>>>(accbuf, ug, c_l1, act, k);
        msg_upd_kernel<<<2048, 256, 0, stream>>>(xbuf, ha, hb, rp, csr_dst, csr_w,
                                                 ug, act, k);
        ushort_t* t = ha; ha = hb; hb = t;
    }

    final_kernel<<<N_TOT / 2, 256, 0, stream>>>(xbuf, Wout, bout, ug, out);
}

// Round 6
// 445.153 us; speedup vs baseline: 1.6031x; 1.0579x over previous
//
#include <hip/hip_runtime.h>
#include <cmath>

typedef unsigned short ushort_t;
typedef unsigned int uint_t;

#define N_TOT 30000
#define N0_   18000
#define R_    5
#define E_    600000
#define RN    (R_ * N_TOT)
#define NC_   (N_TOT * 8)        // logits elements
#define NX_   (N_TOT * 128)      // x elements
#define SCAN_NB ((RN + 1023) / 1024)   // 147 blocks of 1024 elements

typedef __attribute__((ext_vector_type(8))) short bf16x8;
typedef __attribute__((ext_vector_type(4))) float f32x4;

__device__ __forceinline__ ushort_t f2bf(float f) {
    uint_t u = __float_as_uint(f);
    uint_t r = (u + 0x7fffu + ((u >> 16) & 1u)) >> 16;   // RTNE
    return (ushort_t)r;
}
__device__ __forceinline__ float bflo(uint_t v) { return __uint_as_float(v << 16); }
__device__ __forceinline__ float bfhi(uint_t v) { return __uint_as_float(v & 0xffff0000u); }

// ---------------------------------------------------------------------------
// init: u = 1/R, act[0] = 1
// ---------------------------------------------------------------------------
__global__ void init_kernel(float* ug, int* act) {
    if (threadIdx.x < 5) ug[threadIdx.x] = 0.2f;
    if (threadIdx.x == 0) act[0] = 1;
}

// ---------------------------------------------------------------------------
// bf16 pre-conversion: feats row-major, weights transposed [col][k]
// ---------------------------------------------------------------------------
__global__ __launch_bounds__(256) void cvtfeat_kernel(const float* __restrict__ in,
                                                      ushort_t* __restrict__ out,
                                                      int nelem)
{
    int i = (blockIdx.x * 256 + threadIdx.x) * 4;
    if (i >= nelem) return;
    const float4 v = *(const float4*)(in + i);
    ushort_t o0 = f2bf(v.x), o1 = f2bf(v.y), o2 = f2bf(v.z), o3 = f2bf(v.w);
    uint_t p0 = (uint_t)o0 | ((uint_t)o1 << 16);
    uint_t p1 = (uint_t)o2 | ((uint_t)o3 << 16);
    uint2* op = (uint2*)(out + i);
    *op = make_uint2(p0, p1);
}

__global__ __launch_bounds__(256) void cvtw_kernel(const float* __restrict__ W,
                                                   ushort_t* __restrict__ wt, int K)
{
    int idx = blockIdx.x * 256 + threadIdx.x;   // idx = j*K + k
    if (idx >= 128 * K) return;
    int j = idx / K, k = idx - j * K;
    wt[idx] = f2bf(W[k * 128 + j]);
}

// ---------------------------------------------------------------------------
// MFMA MLP: 32 nodes per 256-thread block (4 waves) — unchanged from R4.
// ---------------------------------------------------------------------------
__global__ __launch_bounds__(256) void mlp_mfma_kernel(
    const ushort_t* __restrict__ fb0, const ushort_t* __restrict__ fb1,
    const ushort_t* __restrict__ wt0, const ushort_t* __restrict__ wt1,
    const ushort_t* __restrict__ wtm1, const ushort_t* __restrict__ wtm2,
    const float* __restrict__ b0, const float* __restrict__ b1,
    const float* __restrict__ bm1, const float* __restrict__ bm2,
    float* __restrict__ xout, ushort_t* __restrict__ xh)
{
    const int t = threadIdx.x;
    const int lane = t & 63;
    const int wv = t >> 6;            // 0..3 -> col block wv*32
    const int lr = lane & 15;         // A-row / B-col within tile
    const int lg = lane >> 4;         // k-group, D row-group
    const int row0 = blockIdx.x * 32;

    __shared__ ushort_t hls[32][136];   // bf16 h   (pad: 272B row stride)
    __shared__ float    tls[32][132];   // fp32 t1/t2 (pad: 528B row stride)
    __shared__ ushort_t zls[32][136];   // bf16 z

    // ---------------- GEMM1: h = feat @ W + b -------------------------------
    #pragma unroll
    for (int mt = 0; mt < 2; ++mt) {
        const int rb = row0 + mt * 16;
        const bool is0 = (rb < N0_);
        const int r = min(rb + lr, N_TOT - 1);
        const ushort_t* __restrict__ fa =
            is0 ? fb0 + (size_t)r * 256 : fb1 + (size_t)(r - N0_) * 128;
        const ushort_t* __restrict__ wt = is0 ? wt0 : wt1;
        const int K = is0 ? 256 : 128;
        const int c0 = wv * 32 + lr;

        f32x4 a0 = {0.f, 0.f, 0.f, 0.f};
        f32x4 a1 = {0.f, 0.f, 0.f, 0.f};
        for (int ks = 0; ks < K; ks += 32) {
            const bf16x8 af = *(const bf16x8*)(fa + ks + lg * 8);
            const bf16x8 wb0 = *(const bf16x8*)(wt + (size_t)c0 * K + ks + lg * 8);
            const bf16x8 wb1 = *(const bf16x8*)(wt + (size_t)(c0 + 16) * K + ks + lg * 8);
            a0 = __builtin_amdgcn_mfma_f32_16x16x32_bf16(af, wb0, a0, 0, 0, 0);
            a1 = __builtin_amdgcn_mfma_f32_16x16x32_bf16(af, wb1, a1, 0, 0, 0);
        }
        const float bb0 = is0 ? b0[c0] : b1[c0];
        const float bb1 = is0 ? b0[c0 + 16] : b1[c0 + 16];
        #pragma unroll
        for (int j = 0; j < 4; ++j) {
            hls[mt * 16 + lg * 4 + j][c0]      = f2bf(a0[j] + bb0);
            hls[mt * 16 + lg * 4 + j][c0 + 16] = f2bf(a1[j] + bb1);
        }
    }
    __syncthreads();

    // ---------------- GEMM2: t1 = h @ Wm1 + bm1 -----------------------------
    {
        const int c0 = wv * 32 + lr;
        f32x4 g00 = {0.f,0.f,0.f,0.f}, g01 = {0.f,0.f,0.f,0.f};
        f32x4 g10 = {0.f,0.f,0.f,0.f}, g11 = {0.f,0.f,0.f,0.f};
        for (int ks = 0; ks < 128; ks += 32) {
            const bf16x8 wb0 = *(const bf16x8*)(wtm1 + (size_t)c0 * 128 + ks + lg * 8);
            const bf16x8 wb1 = *(const bf16x8*)(wtm1 + (size_t)(c0 + 16) * 128 + ks + lg * 8);
            const bf16x8 af0 = *(const bf16x8*)(&hls[lr][ks + lg * 8]);
            const bf16x8 af1 = *(const bf16x8*)(&hls[16 + lr][ks + lg * 8]);
            g00 = __builtin_amdgcn_mfma_f32_16x16x32_bf16(af0, wb0, g00, 0, 0, 0);
            g01 = __builtin_amdgcn_mfma_f32_16x16x32_bf16(af0, wb1, g01, 0, 0, 0);
            g10 = __builtin_amdgcn_mfma_f32_16x16x32_bf16(af1, wb0, g10, 0, 0, 0);
            g11 = __builtin_amdgcn_mfma_f32_16x16x32_bf16(af1, wb1, g11, 0, 0, 0);
        }
        const float bb0 = bm1[c0], bb1 = bm1[c0 + 16];
        #pragma unroll
        for (int j = 0; j < 4; ++j) {
            tls[lg * 4 + j][c0]           = g00[j] + bb0;
            tls[lg * 4 + j][c0 + 16]      = g01[j] + bb1;
            tls[16 + lg * 4 + j][c0]      = g10[j] + bb0;
            tls[16 + lg * 4 + j][c0 + 16] = g11[j] + bb1;
        }
    }
    __syncthreads();

    // ---------------- LN + relu -> z (bf16) ---------------------------------
    {
        const int row = t >> 3, seg = t & 7;
        f32x4 v[4];
        float s = 0.f;
        #pragma unroll
        for (int i = 0; i < 4; ++i) {
            v[i] = *(const f32x4*)(&tls[row][seg * 16 + i * 4]);
            s += v[i][0] + v[i][1] + v[i][2] + v[i][3];
        }
        #pragma unroll
        for (int o = 1; o < 8; o <<= 1) s += __shfl_xor(s, o, 64);
        const float mean = s * (1.0f / 128.0f);
        float q = 0.f;
        #pragma unroll
        for (int i = 0; i < 4; ++i) {
            #pragma unroll
            for (int e = 0; e < 4; ++e) { float d = v[i][e] - mean; q = fmaf(d, d, q); }
        }
        #pragma unroll
        for (int o = 1; o < 8; o <<= 1) q += __shfl_xor(q, o, 64);
        const float inv = 1.0f / sqrtf(q * (1.0f / 128.0f) + 1e-5f);
        uint_t* zp = (uint_t*)&zls[row][0];
        #pragma unroll
        for (int i = 0; i < 4; ++i) {
            ushort_t z0 = f2bf(fmaxf((v[i][0] - mean) * inv, 0.0f));
            ushort_t z1 = f2bf(fmaxf((v[i][1] - mean) * inv, 0.0f));
            ushort_t z2 = f2bf(fmaxf((v[i][2] - mean) * inv, 0.0f));
            ushort_t z3 = f2bf(fmaxf((v[i][3] - mean) * inv, 0.0f));
            zp[(seg * 16 + i * 4) / 2]     = (uint_t)z0 | ((uint_t)z1 << 16);
            zp[(seg * 16 + i * 4) / 2 + 1] = (uint_t)z2 | ((uint_t)z3 << 16);
        }
    }
    __syncthreads();

    // ---------------- GEMM3: t2 = z @ Wm2 + bm2 -----------------------------
    {
        const int c0 = wv * 32 + lr;
        f32x4 g00 = {0.f,0.f,0.f,0.f}, g01 = {0.f,0.f,0.f,0.f};
        f32x4 g10 = {0.f,0.f,0.f,0.f}, g11 = {0.f,0.f,0.f,0.f};
        for (int ks = 0; ks < 128; ks += 32) {
            const bf16x8 wb0 = *(const bf16x8*)(wtm2 + (size_t)c0 * 128 + ks + lg * 8);
            const bf16x8 wb1 = *(const bf16x8*)(wtm2 + (size_t)(c0 + 16) * 128 + ks + lg * 8);
            const bf16x8 af0 = *(const bf16x8*)(&zls[lr][ks + lg * 8]);
            const bf16x8 af1 = *(const bf16x8*)(&zls[16 + lr][ks + lg * 8]);
            g00 = __builtin_amdgcn_mfma_f32_16x16x32_bf16(af0, wb0, g00, 0, 0, 0);
            g01 = __builtin_amdgcn_mfma_f32_16x16x32_bf16(af0, wb1, g01, 0, 0, 0);
            g10 = __builtin_amdgcn_mfma_f32_16x16x32_bf16(af1, wb0, g10, 0, 0, 0);
            g11 = __builtin_amdgcn_mfma_f32_16x16x32_bf16(af1, wb1, g11, 0, 0, 0);
        }
        __syncthreads();   // all zls reads done before tls is overwritten below
        const float bb0 = bm2[c0], bb1 = bm2[c0 + 16];
        #pragma unroll
        for (int j = 0; j < 4; ++j) {
            tls[lg * 4 + j][c0]           = g00[j] + bb0;
            tls[lg * 4 + j][c0 + 16]      = g01[j] + bb1;
            tls[16 + lg * 4 + j][c0]      = g10[j] + bb0;
            tls[16 + lg * 4 + j][c0 + 16] = g11[j] + bb1;
        }
    }
    __syncthreads();

    // ---------------- per-row standardization + store -----------------------
    {
        const int row = t >> 3, seg = t & 7;
        const int n = row0 + row;
        f32x4 v[4];
        float s = 0.f;
        #pragma unroll
        for (int i = 0; i < 4; ++i) {
            v[i] = *(const f32x4*)(&tls[row][seg * 16 + i * 4]);
            s += v[i][0] + v[i][1] + v[i][2] + v[i][3];
        }
        #pragma unroll
        for (int o = 1; o < 8; o <<= 1) s += __shfl_xor(s, o, 64);
        const float mu = s * (1.0f / 128.0f);
        float q = 0.f;
        #pragma unroll
        for (int i = 0; i < 4; ++i) {
            #pragma unroll
            for (int e = 0; e < 4; ++e) { float d = v[i][e] - mu; q = fmaf(d, d, q); }
        }
        #pragma unroll
        for (int o = 1; o < 8; o <<= 1) q += __shfl_xor(q, o, 64);
        const float sd = sqrtf(q * (1.0f / 127.0f));
        const float inv = 1.0f / sd;
        if (n < N_TOT) {
            uint_t* xhp = (uint_t*)xh + (size_t)n * 64 + seg * 8;
            float* xop = xout + (size_t)n * 128 + seg * 16;
            #pragma unroll
            for (int i = 0; i < 4; ++i) {
                float rr[4];
                #pragma unroll
                for (int e = 0; e < 4; ++e) {
                    float r = (v[i][e] - mu) * inv;
                    if (!(fabsf(r) <= 3.402823466e38f)) {
                        r = (r != r) ? 0.0f : ((r > 0.0f) ? 3.402823466e38f : -3.402823466e38f);
                    }
                    rr[e] = r;
                }
                *(float4*)(xop + i * 4) = make_float4(rr[0], rr[1], rr[2], rr[3]);
                xhp[i * 2]     = (uint_t)f2bf(rr[0]) | ((uint_t)f2bf(rr[1]) << 16);
                xhp[i * 2 + 1] = (uint_t)f2bf(rr[2]) | ((uint_t)f2bf(rr[3]) << 16);
            }
        }
    }
}

// ---------------------------------------------------------------------------
// preprocessing — NODE-MAJOR keys: key = src*5 + rel, so each node's edges
// (all 5 relations) are contiguous in the CSR and its 6 range boundaries
// are 6 consecutive ints in rp.
// ---------------------------------------------------------------------------
__global__ void deg_kernel(const int* __restrict__ src, const int* __restrict__ rel,
                           int* __restrict__ deg_i)
{
    int e = blockIdx.x * 256 + threadIdx.x;
    if (e >= E_) return;
    atomicAdd(&deg_i[src[e] * R_ + rel[e]], 1);
}

__global__ void dinv_kernel(const int* __restrict__ deg_i, float* __restrict__ dinv)
{
    int i = blockIdx.x * 256 + threadIdx.x;
    if (i >= RN) return;
    int dg = deg_i[i];
    dinv[i] = (dg > 0) ? 1.0f / sqrtf((float)dg) : 0.0f;
}

// 3-pass parallel exclusive scan over RN elements (unchanged structure)
__global__ __launch_bounds__(256) void scan1_kernel(const int* __restrict__ cnt,
                                                    int* __restrict__ rp,
                                                    int* __restrict__ bsum)
{
    __shared__ int wsum[4];
    const int t = threadIdx.x, lane = t & 63, w = t >> 6;
    const int i0 = blockIdx.x * 1024 + t * 4;
    const int v0 = (i0 + 0 < RN) ? cnt[i0 + 0] : 0;
    const int v1 = (i0 + 1 < RN) ? cnt[i0 + 1] : 0;
    const int v2 = (i0 + 2 < RN) ? cnt[i0 + 2] : 0;
    const int v3 = (i0 + 3 < RN) ? cnt[i0 + 3] : 0;
    const int s = v0 + v1 + v2 + v3;
    int sc = s;
    #pragma unroll
    for (int o = 1; o < 64; o <<= 1) { int tmp = __shfl_up(sc, o, 64); if (lane >= o) sc += tmp; }
    if (lane == 63) wsum[w] = sc;
    __syncthreads();
    int woff = 0;
    #pragma unroll
    for (int i = 0; i < 3; ++i) if (i < w) woff += wsum[i];
    int run = woff + sc - s;                 // exclusive within block
    if (i0 + 0 < RN) rp[i0 + 0] = run; run += v0;
    if (i0 + 1 < RN) rp[i0 + 1] = run; run += v1;
    if (i0 + 2 < RN) rp[i0 + 2] = run; run += v2;
    if (i0 + 3 < RN) rp[i0 + 3] = run;
    if (t == 255) bsum[blockIdx.x] = woff + sc;   // block total
}

__global__ __launch_bounds__(256) void scan2_kernel(const int* __restrict__ bsum,
                                                    int* __restrict__ boff,
                                                    int* __restrict__ rp)
{
    __shared__ int wsum[4];
    const int t = threadIdx.x, lane = t & 63, w = t >> 6;
    const int v = (t < SCAN_NB) ? bsum[t] : 0;
    int sc = v;
    #pragma unroll
    for (int o = 1; o < 64; o <<= 1) { int tmp = __shfl_up(sc, o, 64); if (lane >= o) sc += tmp; }
    if (lane == 63) wsum[w] = sc;
    __syncthreads();
    int woff = 0;
    #pragma unroll
    for (int i = 0; i < 3; ++i) if (i < w) woff += wsum[i];
    boff[t] = woff + sc - v;                 // exclusive block offset
    if (t == 0) rp[RN] = E_;                 // total degree == E
}

__global__ __launch_bounds__(256) void scan3_kernel(int* __restrict__ rp,
                                                    const int* __restrict__ boff)
{
    const int off = boff[blockIdx.x];
    if (off == 0) return;
    const int i0 = blockIdx.x * 1024 + threadIdx.x * 4;
    if (i0 + 3 < RN) {
        int4* p = (int4*)(rp + i0);
        int4 q = *p;
        q.x += off; q.y += off; q.z += off; q.w += off;
        *p = q;
    } else {
        for (int i = 0; i < 4; ++i)
            if (i0 + i < RN) rp[i0 + i] += off;
    }
}

__global__ void scatter_kernel(const int* __restrict__ src, const int* __restrict__ dst,
                               const int* __restrict__ rel, const int* __restrict__ rp,
                               int* __restrict__ fill, const int* __restrict__ deg_i,
                               const float* __restrict__ dinv,
                               int* __restrict__ csr_dst, float* __restrict__ csr_w,
                               float* __restrict__ csr_edinv)
{
    int e = blockIdx.x * 256 + threadIdx.x;
    if (e >= E_) return;
    int s = src[e], r = rel[e], d = dst[e];
    int key = s * R_ + r;
    int pos = rp[key] + atomicAdd(&fill[key], 1);
    csr_dst[pos] = d;
    csr_w[pos] = 1.0f / (float)deg_i[key];
    csr_edinv[pos] = dinv[key] * dinv[d * R_ + r];
}

// ---------------------------------------------------------------------------
// tv: node-major CSR — ONE edge loop per node (all 5 rels), unroll x4.
// Boundaries hoisted to SGPR via readfirstlane; per-edge rel recovered with
// 4 uniform compares; per-rel sums via predicated adds.
// ---------------------------------------------------------------------------
__global__ __launch_bounds__(256) void tv_kernel(
    const ushort_t* __restrict__ xh, const int* __restrict__ rp,
    const int* __restrict__ csr_dst, const float* __restrict__ csr_edinv,
    const int* __restrict__ act, int k, float* __restrict__ accbuf)
{
    if (act[k] == 0) return;
    const int lane = threadIdx.x & 63;
    const int wv = threadIdx.x >> 6;
    const int wid = blockIdx.x * 4 + wv;
    const int nw = gridDim.x * 4;
    float na[5] = {0, 0, 0, 0, 0};
    float ea[5] = {0, 0, 0, 0, 0};
    for (int n = wid; n < N_TOT; n += nw) {
        const int b0 = __builtin_amdgcn_readfirstlane(rp[n * R_ + 0]);
        const int b1 = __builtin_amdgcn_readfirstlane(rp[n * R_ + 1]);
        const int b2 = __builtin_amdgcn_readfirstlane(rp[n * R_ + 2]);
        const int b3 = __builtin_amdgcn_readfirstlane(rp[n * R_ + 3]);
        const int b4 = __builtin_amdgcn_readfirstlane(rp[n * R_ + 4]);
        const int b5 = __builtin_amdgcn_readfirstlane(rp[n * R_ + 5]);
        const uint_t vs = ((const uint_t*)(xh + (size_t)n * 128))[lane];
        const float sx = bflo(vs), sy = bfhi(vs);
        const float pp = fmaf(sx, sx, sy * sy);
        if (b1 > b0) na[0] += pp;
        if (b2 > b1) na[1] += pp;
        if (b3 > b2) na[2] += pp;
        if (b4 > b3) na[3] += pp;
        if (b5 > b4) na[4] += pp;
        int e = b0;
        for (; e + 4 <= b5; e += 4) {
            const int dn0 = csr_dst[e + 0];
            const int dn1 = csr_dst[e + 1];
            const int dn2 = csr_dst[e + 2];
            const int dn3 = csr_dst[e + 3];
            const float w0 = csr_edinv[e + 0];
            const float w1 = csr_edinv[e + 1];
            const float w2 = csr_edinv[e + 2];
            const float w3 = csr_edinv[e + 3];
            const uint_t v0 = ((const uint_t*)(xh + (size_t)dn0 * 128))[lane];
            const uint_t v1 = ((const uint_t*)(xh + (size_t)dn1 * 128))[lane];
            const uint_t v2 = ((const uint_t*)(xh + (size_t)dn2 * 128))[lane];
            const uint_t v3 = ((const uint_t*)(xh + (size_t)dn3 * 128))[lane];
            const float d0 = w0 * fmaf(sx, bflo(v0), sy * bfhi(v0));
            const float d1 = w1 * fmaf(sx, bflo(v1), sy * bfhi(v1));
            const float d2 = w2 * fmaf(sx, bflo(v2), sy * bfhi(v2));
            const float d3 = w3 * fmaf(sx, bflo(v3), sy * bfhi(v3));
            const int r0 = (e + 0 >= b1) + (e + 0 >= b2) + (e + 0 >= b3) + (e + 0 >= b4);
            const int r1 = (e + 1 >= b1) + (e + 1 >= b2) + (e + 1 >= b3) + (e + 1 >= b4);
            const int r2 = (e + 2 >= b1) + (e + 2 >= b2) + (e + 2 >= b3) + (e + 2 >= b4);
            const int r3 = (e + 3 >= b1) + (e + 3 >= b2) + (e + 3 >= b3) + (e + 3 >= b4);
            #pragma unroll
            for (int rr = 0; rr < 5; ++rr) {
                ea[rr] += (r0 == rr ? d0 : 0.0f) + (r1 == rr ? d1 : 0.0f) +
                          (r2 == rr ? d2 : 0.0f) + (r3 == rr ? d3 : 0.0f);
            }
        }
        for (; e < b5; ++e) {
            const int dn0 = csr_dst[e];
            const float w0 = csr_edinv[e];
            const uint_t v0 = ((const uint_t*)(xh + (size_t)dn0 * 128))[lane];
            const float d0 = w0 * fmaf(sx, bflo(v0), sy * bfhi(v0));
            const int r0 = (e >= b1) + (e >= b2) + (e >= b3) + (e >= b4);
            #pragma unroll
            for (int rr = 0; rr < 5; ++rr)
                ea[rr] += (r0 == rr ? d0 : 0.0f);
        }
    }
    __shared__ float sacc[4][10];
    #pragma unroll
    for (int r = 0; r < 5; ++r) {
        float a = na[r], b = ea[r];
        for (int o = 32; o > 0; o >>= 1) {
            a += __shfl_down(a, o, 64);
            b += __shfl_down(b, o, 64);
        }
        if (lane == 0) { sacc[wv][r] = a; sacc[wv][5 + r] = b; }
    }
    __syncthreads();
    if (threadIdx.x < 10) {
        float t = sacc[0][threadIdx.x] + sacc[1][threadIdx.x] +
                  sacc[2][threadIdx.x] + sacc[3][threadIdx.x];
        atomicAdd(&accbuf[k * 16 + threadIdx.x], t);
    }
}

// ---------------------------------------------------------------------------
// scalar: fp32 lane-parallel mirror descent (lanes 0..7 of one wave)
// ---------------------------------------------------------------------------
__global__ void scalar_kernel(const float* __restrict__ accbuf, float* __restrict__ ug,
                              float* __restrict__ c_l1, int* __restrict__ act, int k)
{
    if (blockIdx.x != 0 || threadIdx.x >= 8) return;
    const int r = threadIdx.x;
    const int a = act[k];
    float w = (r < 5) ? (accbuf[k * 16 + r] - accbuf[k * 16 + 5 + r]) * (1.0f / 30000.0f)
                      : 0.0f;
    float l1 = fabsf(w);
    for (int o = 4; o > 0; o >>= 1) l1 += __shfl_xor(l1, o, 8);
    if (k == 0 && r == 0) c_l1[0] = l1;
    if (!a) { if (r == 0) act[k + 1] = 0; return; }
    float u = (r < 5) ? ug[r] : 0.0f;
    const float fi = l1 + 3.0f;
    bool mact = true;
    for (int t = 1; t <= 20; ++t) {
        float T = sqrtf(3.2188758248682006f / ((float)t * fi * fi));
        float ta = u * expf(-T * (3.0f * u + w));
        float ssum = ta;
        for (int o = 4; o > 0; o >>= 1) ssum += __shfl_xor(ssum, o, 8);
        float un = ta / ssum;
        float d0 = u - un;
        float dq = d0 * d0;
        for (int o = 4; o > 0; o >>= 1) dq += __shfl_xor(dq, o, 8);
        if (mact) u = un;
        mact = mact && (sqrtf(dq) >= 1e-3f);
    }
    if (r < 5) ug[r] = u;
    if (r == 0) act[k + 1] = (l1 / c_l1[0] >= 0.3f) ? 1 : 0;
}

// ---------------------------------------------------------------------------
// msg + update: node-major — single edge loop, single accumulator pair
// (per-edge weight = u[rel]*csr_w), unroll x4, fp32 x in place, bf16 shadow.
// ---------------------------------------------------------------------------
__global__ __launch_bounds__(256) void msg_upd_kernel(
    float* __restrict__ x, const ushort_t* __restrict__ xh_in,
    ushort_t* __restrict__ xh_out,
    const int* __restrict__ rp, const int* __restrict__ csr_dst,
    const float* __restrict__ csr_w, const float* __restrict__ ug,
    const int* __restrict__ act, int k)
{
    if (act[k + 1] == 0) return;
    const int lane = threadIdx.x & 63;
    const int wid = blockIdx.x * 4 + (threadIdx.x >> 6);
    const int nw = gridDim.x * 4;
    const float u0 = ug[0], u1 = ug[1], u2 = ug[2], u3 = ug[3], u4 = ug[4];
    for (int n = wid; n < N_TOT; n += nw) {
        const int b1 = __builtin_amdgcn_readfirstlane(rp[n * R_ + 1]);
        const int b2 = __builtin_amdgcn_readfirstlane(rp[n * R_ + 2]);
        const int b3 = __builtin_amdgcn_readfirstlane(rp[n * R_ + 3]);
        const int b4 = __builtin_amdgcn_readfirstlane(rp[n * R_ + 4]);
        const int b0 = __builtin_amdgcn_readfirstlane(rp[n * R_ + 0]);
        const int b5 = __builtin_amdgcn_readfirstlane(rp[n * R_ + 5]);
        float ax0 = 0.0f, ay0 = 0.0f, ax1 = 0.0f, ay1 = 0.0f;
        int e = b0;
        for (; e + 4 <= b5; e += 4) {
            const int r0 = (e + 0 >= b1) + (e + 0 >= b2) + (e + 0 >= b3) + (e + 0 >= b4);
            const int r1 = (e + 1 >= b1) + (e + 1 >= b2) + (e + 1 >= b3) + (e + 1 >= b4);
            const int r2 = (e + 2 >= b1) + (e + 2 >= b2) + (e + 2 >= b3) + (e + 2 >= b4);
            const int r3 = (e + 3 >= b1) + (e + 3 >= b2) + (e + 3 >= b3) + (e + 3 >= b4);
            const float uu0 = (r0 == 0) ? u0 : (r0 == 1) ? u1 : (r0 == 2) ? u2 : (r0 == 3) ? u3 : u4;
            const float uu1 = (r1 == 0) ? u0 : (r1 == 1) ? u1 : (r1 == 2) ? u2 : (r1 == 3) ? u3 : u4;
            const float uu2 = (r2 == 0) ? u0 : (r2 == 1) ? u1 : (r2 == 2) ? u2 : (r2 == 3) ? u3 : u4;
            const float uu3 = (r3 == 0) ? u0 : (r3 == 1) ? u1 : (r3 == 2) ? u2 : (r3 == 3) ? u3 : u4;
            const int dn0 = csr_dst[e + 0];
            const int dn1 = csr_dst[e + 1];
            const int dn2 = csr_dst[e + 2];
            const int dn3 = csr_dst[e + 3];
            const float w0 = uu0 * csr_w[e + 0];
            const float w1 = uu1 * csr_w[e + 1];
            const float w2 = uu2 * csr_w[e + 2];
            const float w3 = uu3 * csr_w[e + 3];
            const uint_t v0 = ((const uint_t*)(xh_in + (size_t)dn0 * 128))[lane];
            const uint_t v1 = ((const uint_t*)(xh_in + (size_t)dn1 * 128))[lane];
            const uint_t v2 = ((const uint_t*)(xh_in + (size_t)dn2 * 128))[lane];
            const uint_t v3 = ((const uint_t*)(xh_in + (size_t)dn3 * 128))[lane];
            ax0 = fmaf(w0, bflo(v0), ax0); ay0 = fmaf(w0, bfhi(v0), ay0);
            ax1 = fmaf(w1, bflo(v1), ax1); ay1 = fmaf(w1, bfhi(v1), ay1);
            ax0 = fmaf(w2, bflo(v2), ax0); ay0 = fmaf(w2, bfhi(v2), ay0);
            ax1 = fmaf(w3, bflo(v3), ax1); ay1 = fmaf(w3, bfhi(v3), ay1);
        }
        for (; e < b5; ++e) {
            const int r0 = (e >= b1) + (e >= b2) + (e >= b3) + (e >= b4);
            const float uu0 = (r0 == 0) ? u0 : (r0 == 1) ? u1 : (r0 == 2) ? u2 : (r0 == 3) ? u3 : u4;
            const int dn0 = csr_dst[e];
            const float w0 = uu0 * csr_w[e];
            const uint_t v0 = ((const uint_t*)(xh_in + (size_t)dn0 * 128))[lane];
            ax0 = fmaf(w0, bflo(v0), ax0);
            ay0 = fmaf(w0, bfhi(v0), ay0);
        }
        const float ci = 1.0f / 21.0f, cb = 20.0f / 21.0f;
        float2* xp = (float2*)(x + (size_t)n * 128);
        const float2 xs = xp[lane];
        const float nx_ = fmaf(cb, ax0 + ax1, xs.x * ci);
        const float ny_ = fmaf(cb, ay0 + ay1, xs.y * ci);
        xp[lane] = make_float2(nx_, ny_);
        ((uint_t*)(xh_out + (size_t)n * 128))[lane] =
            ((uint_t)f2bf(ny_) << 16) | (uint_t)f2bf(nx_);
    }
}

// ---------------------------------------------------------------------------
// epilogue: logits = x@Wout + bout ; write logits, x, u (unchanged)
// ---------------------------------------------------------------------------
__global__ __launch_bounds__(256) void final_kernel(const float* __restrict__ x,
                                                    const float* __restrict__ Wout,
                                                    const float* __restrict__ bout,
                                                    const float* __restrict__ ug,
                                                    float* __restrict__ out)
{
    const int nl = threadIdx.x >> 7;
    const int n = blockIdx.x * 2 + nl;
    const int j = threadIdx.x & 127;
    const int lane = threadIdx.x & 63;
    const int wv = threadIdx.x >> 6;
    float xv = x[(size_t)n * 128 + j];
    out[(size_t)NC_ + (size_t)n * 128 + j] = xv;
    float p[8];
    #pragma unroll
    for (int c = 0; c < 8; ++c) p[c] = xv * Wout[j * 8 + c];
    #pragma unroll
    for (int c = 0; c < 8; ++c)
        for (int o = 32; o > 0; o >>= 1) p[c] += __shfl_down(p[c], o, 64);
    __shared__ float sp[4][8];
    if (lane == 0) {
        #pragma unroll
        for (int c = 0; c < 8; ++c) sp[wv][c] = p[c];
    }
    __syncthreads();
    if (j < 8) {
        int c = j;
        out[(size_t)n * 8 + c] = bout[c] + sp[2 * nl][c] + sp[2 * nl + 1][c];
    }
    if (blockIdx.x == 0 && threadIdx.x < 5)
        out[(size_t)NC_ + (size_t)NX_ + threadIdx.x] = ug[threadIdx.x];
}

// ---------------------------------------------------------------------------
extern "C" void kernel_launch(void* const* d_in, const int* in_sizes, int n_in,
                              void* d_out, int out_size, void* d_ws, size_t ws_size,
                              hipStream_t stream)
{
    const float* feat0 = (const float*)d_in[0];
    const float* feat1 = (const float*)d_in[1];
    const float* W0   = (const float*)d_in[2];
    const float* b0   = (const float*)d_in[3];
    const float* W1   = (const float*)d_in[4];
    const float* b1   = (const float*)d_in[5];
    const float* Wm1  = (const float*)d_in[6];
    const float* bm1  = (const float*)d_in[7];
    const float* Wm2  = (const float*)d_in[8];
    const float* bm2  = (const float*)d_in[9];
    const float* Wout = (const float*)d_in[10];
    const float* bout = (const float*)d_in[11];
    const int* src = (const int*)d_in[12];
    const int* dst = (const int*)d_in[13];
    const int* rel = (const int*)d_in[14];
    float* out = (float*)d_out;

    char* p = (char*)d_ws;
    auto alloc = [&](size_t bytes) { char* q = p; p += (bytes + 255) & ~(size_t)255; return q; };
    float*    xbuf      = (float*)   alloc((size_t)NX_ * 4);
    ushort_t* xh0       = (ushort_t*)alloc((size_t)NX_ * 2);
    ushort_t* xh1       = (ushort_t*)alloc((size_t)NX_ * 2);
    ushort_t* fb0       = (ushort_t*)alloc((size_t)N0_ * 256 * 2);
    ushort_t* fb1       = (ushort_t*)alloc((size_t)(N_TOT - N0_) * 128 * 2);
    ushort_t* wt0       = (ushort_t*)alloc((size_t)128 * 256 * 2);
    ushort_t* wt1       = (ushort_t*)alloc((size_t)128 * 128 * 2);
    ushort_t* wtm1      = (ushort_t*)alloc((size_t)128 * 128 * 2);
    ushort_t* wtm2      = (ushort_t*)alloc((size_t)128 * 128 * 2);
    int*      deg_i     = (int*)     alloc((size_t)RN * 4);
    float*    dinv      = (float*)   alloc((size_t)RN * 4);
    int*      rp        = (int*)     alloc(((size_t)RN + 1) * 4);
    int*      fill      = (int*)     alloc((size_t)RN * 4);
    int*      bsum      = (int*)     alloc((size_t)SCAN_NB * 4);
    int*      boff      = (int*)     alloc(256 * 4);
    int*      csr_dst   = (int*)     alloc((size_t)E_ * 4);
    float*    csr_w     = (float*)   alloc((size_t)E_ * 4);
    float*    csr_edinv = (float*)   alloc((size_t)E_ * 4);
    float*    accbuf    = (float*)   alloc(128 * 4);
    float*    ug        = (float*)   alloc(64);
    float*    c_l1      = (float*)   alloc(64);
    int*      act       = (int*)     alloc(64);

    hipMemsetAsync(deg_i, 0, (size_t)RN * 4, stream);
    hipMemsetAsync(fill, 0, (size_t)RN * 4, stream);
    hipMemsetAsync(accbuf, 0, 128 * 4, stream);
    init_kernel<<<1, 64, 0, stream>>>(ug, act);

    // bf16 pre-conversion
    cvtfeat_kernel<<<(N0_ * 256 / 4 + 255) / 256, 256, 0, stream>>>(feat0, fb0, N0_ * 256);
    cvtfeat_kernel<<<((N_TOT - N0_) * 128 / 4 + 255) / 256, 256, 0, stream>>>(
        feat1, fb1, (N_TOT - N0_) * 128);
    cvtw_kernel<<<(128 * 256 + 255) / 256, 256, 0, stream>>>(W0, wt0, 256);
    cvtw_kernel<<<(128 * 128 + 255) / 256, 256, 0, stream>>>(W1, wt1, 128);
    cvtw_kernel<<<(128 * 128 + 255) / 256, 256, 0, stream>>>(Wm1, wtm1, 128);
    cvtw_kernel<<<(128 * 128 + 255) / 256, 256, 0, stream>>>(Wm2, wtm2, 128);

    mlp_mfma_kernel<<<(N_TOT + 31) / 32, 256, 0, stream>>>(
        fb0, fb1, wt0, wt1, wtm1, wtm2, b0, b1, bm1, bm2, xbuf, xh0);

    deg_kernel<<<(E_ + 255) / 256, 256, 0, stream>>>(src, rel, deg_i);
    dinv_kernel<<<(RN + 255) / 256, 256, 0, stream>>>(deg_i, dinv);
    scan1_kernel<<<SCAN_NB, 256, 0, stream>>>(deg_i, rp, bsum);
    scan2_kernel<<<1, 256, 0, stream>>>(bsum, boff, rp);
    scan3_kernel<<<SCAN_NB, 256, 0, stream>>>(rp, boff);
    scatter_kernel<<<(E_ + 255) / 256, 256, 0, stream>>>(src, dst, rel, rp, fill,
                                                         deg_i, dinv,
                                                         csr_dst, csr_w, csr_edinv);

    ushort_t* ha = xh0;
    ushort_t* hb = xh1;
    for (int k = 0; k < 8; ++k) {
        tv_kernel<<<2048, 256, 0, stream>>>(ha, rp, csr_dst, csr_edinv, act, k, accbuf);
        scalar_kernel<<<1, 64, 0, stream>>>(accbuf, ug, c_l1, act, k);
        msg_upd_kernel<<<2048, 256, 0, stream>>>(xbuf, ha, hb, rp, csr_dst, csr_w,
                                                 ug, act, k);
        ushort_t* t = ha; ha = hb; hb = t;
    }

    final_kernel<<<N_TOT / 2, 256, 0, stream>>>(xbuf, Wout, bout, ug, out);
}

// Round 7
// 439.847 us; speedup vs baseline: 1.6224x; 1.0121x over previous
//
#include <hip/hip_runtime.h>
#include <cmath>

typedef unsigned short ushort_t;
typedef unsigned int uint_t;

#define N_TOT 30000
#define N0_   18000
#define R_    5
#define E_    600000
#define RN    (R_ * N_TOT)
#define NC_   (N_TOT * 8)        // logits elements
#define NX_   (N_TOT * 128)      // x elements
#define SCAN_NB ((RN + 1023) / 1024)   // 147 blocks of 1024 elements

typedef __attribute__((ext_vector_type(8))) short bf16x8;
typedef __attribute__((ext_vector_type(4))) float f32x4;

__device__ __forceinline__ ushort_t f2bf(float f) {
    uint_t u = __float_as_uint(f);
    uint_t r = (u + 0x7fffu + ((u >> 16) & 1u)) >> 16;   // RTNE
    return (ushort_t)r;
}
__device__ __forceinline__ float bflo(uint_t v) { return __uint_as_float(v << 16); }
__device__ __forceinline__ float bfhi(uint_t v) { return __uint_as_float(v & 0xffff0000u); }

// ---------------------------------------------------------------------------
// init: u = 1/R, act[0] = 1
// ---------------------------------------------------------------------------
__global__ void init_kernel(float* ug, int* act) {
    if (threadIdx.x < 5) ug[threadIdx.x] = 0.2f;
    if (threadIdx.x == 0) act[0] = 1;
}

// ---------------------------------------------------------------------------
// bf16 pre-conversion: feats row-major, weights transposed [col][k]
// ---------------------------------------------------------------------------
__global__ __launch_bounds__(256) void cvtfeat_kernel(const float* __restrict__ in,
                                                      ushort_t* __restrict__ out,
                                                      int nelem)
{
    int i = (blockIdx.x * 256 + threadIdx.x) * 4;
    if (i >= nelem) return;
    const float4 v = *(const float4*)(in + i);
    ushort_t o0 = f2bf(v.x), o1 = f2bf(v.y), o2 = f2bf(v.z), o3 = f2bf(v.w);
    uint_t p0 = (uint_t)o0 | ((uint_t)o1 << 16);
    uint_t p1 = (uint_t)o2 | ((uint_t)o3 << 16);
    uint2* op = (uint2*)(out + i);
    *op = make_uint2(p0, p1);
}

__global__ __launch_bounds__(256) void cvtw_kernel(const float* __restrict__ W,
                                                   ushort_t* __restrict__ wt, int K)
{
    int idx = blockIdx.x * 256 + threadIdx.x;   // idx = j*K + k
    if (idx >= 128 * K) return;
    int j = idx / K, k = idx - j * K;
    wt[idx] = f2bf(W[k * 128 + j]);
}

// ---------------------------------------------------------------------------
// MFMA MLP: 32 nodes per 256-thread block (4 waves) — unchanged from R4.
// ---------------------------------------------------------------------------
__global__ __launch_bounds__(256) void mlp_mfma_kernel(
    const ushort_t* __restrict__ fb0, const ushort_t* __restrict__ fb1,
    const ushort_t* __restrict__ wt0, const ushort_t* __restrict__ wt1,
    const ushort_t* __restrict__ wtm1, const ushort_t* __restrict__ wtm2,
    const float* __restrict__ b0, const float* __restrict__ b1,
    const float* __restrict__ bm1, const float* __restrict__ bm2,
    float* __restrict__ xout, ushort_t* __restrict__ xh)
{
    const int t = threadIdx.x;
    const int lane = t & 63;
    const int wv = t >> 6;            // 0..3 -> col block wv*32
    const int lr = lane & 15;         // A-row / B-col within tile
    const int lg = lane >> 4;         // k-group, D row-group
    const int row0 = blockIdx.x * 32;

    __shared__ ushort_t hls[32][136];   // bf16 h   (pad: 272B row stride)
    __shared__ float    tls[32][132];   // fp32 t1/t2 (pad: 528B row stride)
    __shared__ ushort_t zls[32][136];   // bf16 z

    // ---------------- GEMM1: h = feat @ W + b -------------------------------
    #pragma unroll
    for (int mt = 0; mt < 2; ++mt) {
        const int rb = row0 + mt * 16;
        const bool is0 = (rb < N0_);
        const int r = min(rb + lr, N_TOT - 1);
        const ushort_t* __restrict__ fa =
            is0 ? fb0 + (size_t)r * 256 : fb1 + (size_t)(r - N0_) * 128;
        const ushort_t* __restrict__ wt = is0 ? wt0 : wt1;
        const int K = is0 ? 256 : 128;
        const int c0 = wv * 32 + lr;

        f32x4 a0 = {0.f, 0.f, 0.f, 0.f};
        f32x4 a1 = {0.f, 0.f, 0.f, 0.f};
        for (int ks = 0; ks < K; ks += 32) {
            const bf16x8 af = *(const bf16x8*)(fa + ks + lg * 8);
            const bf16x8 wb0 = *(const bf16x8*)(wt + (size_t)c0 * K + ks + lg * 8);
            const bf16x8 wb1 = *(const bf16x8*)(wt + (size_t)(c0 + 16) * K + ks + lg * 8);
            a0 = __builtin_amdgcn_mfma_f32_16x16x32_bf16(af, wb0, a0, 0, 0, 0);
            a1 = __builtin_amdgcn_mfma_f32_16x16x32_bf16(af, wb1, a1, 0, 0, 0);
        }
        const float bb0 = is0 ? b0[c0] : b1[c0];
        const float bb1 = is0 ? b0[c0 + 16] : b1[c0 + 16];
        #pragma unroll
        for (int j = 0; j < 4; ++j) {
            hls[mt * 16 + lg * 4 + j][c0]      = f2bf(a0[j] + bb0);
            hls[mt * 16 + lg * 4 + j][c0 + 16] = f2bf(a1[j] + bb1);
        }
    }
    __syncthreads();

    // ---------------- GEMM2: t1 = h @ Wm1 + bm1 -----------------------------
    {
        const int c0 = wv * 32 + lr;
        f32x4 g00 = {0.f,0.f,0.f,0.f}, g01 = {0.f,0.f,0.f,0.f};
        f32x4 g10 = {0.f,0.f,0.f,0.f}, g11 = {0.f,0.f,0.f,0.f};
        for (int ks = 0; ks < 128; ks += 32) {
            const bf16x8 wb0 = *(const bf16x8*)(wtm1 + (size_t)c0 * 128 + ks + lg * 8);
            const bf16x8 wb1 = *(const bf16x8*)(wtm1 + (size_t)(c0 + 16) * 128 + ks + lg * 8);
            const bf16x8 af0 = *(const bf16x8*)(&hls[lr][ks + lg * 8]);
            const bf16x8 af1 = *(const bf16x8*)(&hls[16 + lr][ks + lg * 8]);
            g00 = __builtin_amdgcn_mfma_f32_16x16x32_bf16(af0, wb0, g00, 0, 0, 0);
            g01 = __builtin_amdgcn_mfma_f32_16x16x32_bf16(af0, wb1, g01, 0, 0, 0);
            g10 = __builtin_amdgcn_mfma_f32_16x16x32_bf16(af1, wb0, g10, 0, 0, 0);
            g11 = __builtin_amdgcn_mfma_f32_16x16x32_bf16(af1, wb1, g11, 0, 0, 0);
        }
        const float bb0 = bm1[c0], bb1 = bm1[c0 + 16];
        #pragma unroll
        for (int j = 0; j < 4; ++j) {
            tls[lg * 4 + j][c0]           = g00[j] + bb0;
            tls[lg * 4 + j][c0 + 16]      = g01[j] + bb1;
            tls[16 + lg * 4 + j][c0]      = g10[j] + bb0;
            tls[16 + lg * 4 + j][c0 + 16] = g11[j] + bb1;
        }
    }
    __syncthreads();

    // ---------------- LN + relu -> z (bf16) ---------------------------------
    {
        const int row = t >> 3, seg = t & 7;
        f32x4 v[4];
        float s = 0.f;
        #pragma unroll
        for (int i = 0; i < 4; ++i) {
            v[i] = *(const f32x4*)(&tls[row][seg * 16 + i * 4]);
            s += v[i][0] + v[i][1] + v[i][2] + v[i][3];
        }
        #pragma unroll
        for (int o = 1; o < 8; o <<= 1) s += __shfl_xor(s, o, 64);
        const float mean = s * (1.0f / 128.0f);
        float q = 0.f;
        #pragma unroll
        for (int i = 0; i < 4; ++i) {
            #pragma unroll
            for (int e = 0; e < 4; ++e) { float d = v[i][e] - mean; q = fmaf(d, d, q); }
        }
        #pragma unroll
        for (int o = 1; o < 8; o <<= 1) q += __shfl_xor(q, o, 64);
        const float inv = 1.0f / sqrtf(q * (1.0f / 128.0f) + 1e-5f);
        uint_t* zp = (uint_t*)&zls[row][0];
        #pragma unroll
        for (int i = 0; i < 4; ++i) {
            ushort_t z0 = f2bf(fmaxf((v[i][0] - mean) * inv, 0.0f));
            ushort_t z1 = f2bf(fmaxf((v[i][1] - mean) * inv, 0.0f));
            ushort_t z2 = f2bf(fmaxf((v[i][2] - mean) * inv, 0.0f));
            ushort_t z3 = f2bf(fmaxf((v[i][3] - mean) * inv, 0.0f));
            zp[(seg * 16 + i * 4) / 2]     = (uint_t)z0 | ((uint_t)z1 << 16);
            zp[(seg * 16 + i * 4) / 2 + 1] = (uint_t)z2 | ((uint_t)z3 << 16);
        }
    }
    __syncthreads();

    // ---------------- GEMM3: t2 = z @ Wm2 + bm2 -----------------------------
    {
        const int c0 = wv * 32 + lr;
        f32x4 g00 = {0.f,0.f,0.f,0.f}, g01 = {0.f,0.f,0.f,0.f};
        f32x4 g10 = {0.f,0.f,0.f,0.f}, g11 = {0.f,0.f,0.f,0.f};
        for (int ks = 0; ks < 128; ks += 32) {
            const bf16x8 wb0 = *(const bf16x8*)(wtm2 + (size_t)c0 * 128 + ks + lg * 8);
            const bf16x8 wb1 = *(const bf16x8*)(wtm2 + (size_t)(c0 + 16) * 128 + ks + lg * 8);
            const bf16x8 af0 = *(const bf16x8*)(&zls[lr][ks + lg * 8]);
            const bf16x8 af1 = *(const bf16x8*)(&zls[16 + lr][ks + lg * 8]);
            g00 = __builtin_amdgcn_mfma_f32_16x16x32_bf16(af0, wb0, g00, 0, 0, 0);
            g01 = __builtin_amdgcn_mfma_f32_16x16x32_bf16(af0, wb1, g01, 0, 0, 0);
            g10 = __builtin_amdgcn_mfma_f32_16x16x32_bf16(af1, wb0, g10, 0, 0, 0);
            g11 = __builtin_amdgcn_mfma_f32_16x16x32_bf16(af1, wb1, g11, 0, 0, 0);
        }
        __syncthreads();   // all zls reads done before tls is overwritten below
        const float bb0 = bm2[c0], bb1 = bm2[c0 + 16];
        #pragma unroll
        for (int j = 0; j < 4; ++j) {
            tls[lg * 4 + j][c0]           = g00[j] + bb0;
            tls[lg * 4 + j][c0 + 16]      = g01[j] + bb1;
            tls[16 + lg * 4 + j][c0]      = g10[j] + bb0;
            tls[16 + lg * 4 + j][c0 + 16] = g11[j] + bb1;
        }
    }
    __syncthreads();

    // ---------------- per-row standardization + store -----------------------
    {
        const int row = t >> 3, seg = t & 7;
        const int n = row0 + row;
        f32x4 v[4];
        float s = 0.f;
        #pragma unroll
        for (int i = 0; i < 4; ++i) {
            v[i] = *(const f32x4*)(&tls[row][seg * 16 + i * 4]);
            s += v[i][0] + v[i][1] + v[i][2] + v[i][3];
        }
        #pragma unroll
        for (int o = 1; o < 8; o <<= 1) s += __shfl_xor(s, o, 64);
        const float mu = s * (1.0f / 128.0f);
        float q = 0.f;
        #pragma unroll
        for (int i = 0; i < 4; ++i) {
            #pragma unroll
            for (int e = 0; e < 4; ++e) { float d = v[i][e] - mu; q = fmaf(d, d, q); }
        }
        #pragma unroll
        for (int o = 1; o < 8; o <<= 1) q += __shfl_xor(q, o, 64);
        const float sd = sqrtf(q * (1.0f / 127.0f));
        const float inv = 1.0f / sd;
        if (n < N_TOT) {
            uint_t* xhp = (uint_t*)xh + (size_t)n * 64 + seg * 8;
            float* xop = xout + (size_t)n * 128 + seg * 16;
            #pragma unroll
            for (int i = 0; i < 4; ++i) {
                float rr[4];
                #pragma unroll
                for (int e = 0; e < 4; ++e) {
                    float r = (v[i][e] - mu) * inv;
                    if (!(fabsf(r) <= 3.402823466e38f)) {
                        r = (r != r) ? 0.0f : ((r > 0.0f) ? 3.402823466e38f : -3.402823466e38f);
                    }
                    rr[e] = r;
                }
                *(float4*)(xop + i * 4) = make_float4(rr[0], rr[1], rr[2], rr[3]);
                xhp[i * 2]     = (uint_t)f2bf(rr[0]) | ((uint_t)f2bf(rr[1]) << 16);
                xhp[i * 2 + 1] = (uint_t)f2bf(rr[2]) | ((uint_t)f2bf(rr[3]) << 16);
            }
        }
    }
}

// ---------------------------------------------------------------------------
// preprocessing — node-major keys: key = src*5 + rel
// ---------------------------------------------------------------------------
__global__ void deg_kernel(const int* __restrict__ src, const int* __restrict__ rel,
                           int* __restrict__ deg_i)
{
    int e = blockIdx.x * 256 + threadIdx.x;
    if (e >= E_) return;
    atomicAdd(&deg_i[src[e] * R_ + rel[e]], 1);
}

__global__ void dinv_kernel(const int* __restrict__ deg_i, float* __restrict__ dinv)
{
    int i = blockIdx.x * 256 + threadIdx.x;
    if (i >= RN) return;
    int dg = deg_i[i];
    dinv[i] = (dg > 0) ? 1.0f / sqrtf((float)dg) : 0.0f;
}

// 3-pass parallel exclusive scan over RN elements (unchanged structure)
__global__ __launch_bounds__(256) void scan1_kernel(const int* __restrict__ cnt,
                                                    int* __restrict__ rp,
                                                    int* __restrict__ bsum)
{
    __shared__ int wsum[4];
    const int t = threadIdx.x, lane = t & 63, w = t >> 6;
    const int i0 = blockIdx.x * 1024 + t * 4;
    const int v0 = (i0 + 0 < RN) ? cnt[i0 + 0] : 0;
    const int v1 = (i0 + 1 < RN) ? cnt[i0 + 1] : 0;
    const int v2 = (i0 + 2 < RN) ? cnt[i0 + 2] : 0;
    const int v3 = (i0 + 3 < RN) ? cnt[i0 + 3] : 0;
    const int s = v0 + v1 + v2 + v3;
    int sc = s;
    #pragma unroll
    for (int o = 1; o < 64; o <<= 1) { int tmp = __shfl_up(sc, o, 64); if (lane >= o) sc += tmp; }
    if (lane == 63) wsum[w] = sc;
    __syncthreads();
    int woff = 0;
    #pragma unroll
    for (int i = 0; i < 3; ++i) if (i < w) woff += wsum[i];
    int run = woff + sc - s;                 // exclusive within block
    if (i0 + 0 < RN) rp[i0 + 0] = run; run += v0;
    if (i0 + 1 < RN) rp[i0 + 1] = run; run += v1;
    if (i0 + 2 < RN) rp[i0 + 2] = run; run += v2;
    if (i0 + 3 < RN) rp[i0 + 3] = run;
    if (t == 255) bsum[blockIdx.x] = woff + sc;   // block total
}

__global__ __launch_bounds__(256) void scan2_kernel(const int* __restrict__ bsum,
                                                    int* __restrict__ boff,
                                                    int* __restrict__ rp)
{
    __shared__ int wsum[4];
    const int t = threadIdx.x, lane = t & 63, w = t >> 6;
    const int v = (t < SCAN_NB) ? bsum[t] : 0;
    int sc = v;
    #pragma unroll
    for (int o = 1; o < 64; o <<= 1) { int tmp = __shfl_up(sc, o, 64); if (lane >= o) sc += tmp; }
    if (lane == 63) wsum[w] = sc;
    __syncthreads();
    int woff = 0;
    #pragma unroll
    for (int i = 0; i < 3; ++i) if (i < w) woff += wsum[i];
    boff[t] = woff + sc - v;                 // exclusive block offset
    if (t == 0) rp[RN] = E_;                 // total degree == E
}

__global__ __launch_bounds__(256) void scan3_kernel(int* __restrict__ rp,
                                                    const int* __restrict__ boff)
{
    const int off = boff[blockIdx.x];
    if (off == 0) return;
    const int i0 = blockIdx.x * 1024 + threadIdx.x * 4;
    if (i0 + 3 < RN) {
        int4* p = (int4*)(rp + i0);
        int4 q = *p;
        q.x += off; q.y += off; q.z += off; q.w += off;
        *p = q;
    } else {
        for (int i = 0; i < 4; ++i)
            if (i0 + i < RN) rp[i0 + i] += off;
    }
}

// scatter: build packed edge records {dst, edinv, w, 0} (one 16B load/edge)
__global__ void scatter_kernel(const int* __restrict__ src, const int* __restrict__ dst,
                               const int* __restrict__ rel, const int* __restrict__ rp,
                               int* __restrict__ fill, const int* __restrict__ deg_i,
                               const float* __restrict__ dinv,
                               int4* __restrict__ csr_pk)
{
    int e = blockIdx.x * 256 + threadIdx.x;
    if (e >= E_) return;
    int s = src[e], r = rel[e], d = dst[e];
    int key = s * R_ + r;
    int pos = rp[key] + atomicAdd(&fill[key], 1);
    float edinv = dinv[key] * dinv[d * R_ + r];
    float w = 1.0f / (float)deg_i[key];
    csr_pk[pos] = make_int4(d, __float_as_int(edinv), __float_as_int(w), 0);
}

// ---------------------------------------------------------------------------
// tv: node-major CSR, packed edges, unroll x8 (8 gathers in flight)
// ---------------------------------------------------------------------------
__global__ __launch_bounds__(256) void tv_kernel(
    const ushort_t* __restrict__ xh, const int* __restrict__ rp,
    const int4* __restrict__ csr_pk,
    const int* __restrict__ act, int k, float* __restrict__ accbuf)
{
    if (act[k] == 0) return;
    const int lane = threadIdx.x & 63;
    const int wv = threadIdx.x >> 6;
    const int wid = blockIdx.x * 4 + wv;
    const int nw = gridDim.x * 4;
    float na[5] = {0, 0, 0, 0, 0};
    float ea[5] = {0, 0, 0, 0, 0};
    for (int n = wid; n < N_TOT; n += nw) {
        const int b0 = __builtin_amdgcn_readfirstlane(rp[n * R_ + 0]);
        const int b1 = __builtin_amdgcn_readfirstlane(rp[n * R_ + 1]);
        const int b2 = __builtin_amdgcn_readfirstlane(rp[n * R_ + 2]);
        const int b3 = __builtin_amdgcn_readfirstlane(rp[n * R_ + 3]);
        const int b4 = __builtin_amdgcn_readfirstlane(rp[n * R_ + 4]);
        const int b5 = __builtin_amdgcn_readfirstlane(rp[n * R_ + 5]);
        const uint_t vs = ((const uint_t*)(xh + (size_t)n * 128))[lane];
        const float sx = bflo(vs), sy = bfhi(vs);
        const float pp = fmaf(sx, sx, sy * sy);
        if (b1 > b0) na[0] += pp;
        if (b2 > b1) na[1] += pp;
        if (b3 > b2) na[2] += pp;
        if (b4 > b3) na[3] += pp;
        if (b5 > b4) na[4] += pp;
        int e = b0;
        for (; e + 8 <= b5; e += 8) {
            int4 p0 = csr_pk[e + 0];
            int4 p1 = csr_pk[e + 1];
            int4 p2 = csr_pk[e + 2];
            int4 p3 = csr_pk[e + 3];
            int4 p4 = csr_pk[e + 4];
            int4 p5 = csr_pk[e + 5];
            int4 p6 = csr_pk[e + 6];
            int4 p7 = csr_pk[e + 7];
            const uint_t v0 = ((const uint_t*)(xh + (size_t)p0.x * 128))[lane];
            const uint_t v1 = ((const uint_t*)(xh + (size_t)p1.x * 128))[lane];
            const uint_t v2 = ((const uint_t*)(xh + (size_t)p2.x * 128))[lane];
            const uint_t v3 = ((const uint_t*)(xh + (size_t)p3.x * 128))[lane];
            const uint_t v4 = ((const uint_t*)(xh + (size_t)p4.x * 128))[lane];
            const uint_t v5 = ((const uint_t*)(xh + (size_t)p5.x * 128))[lane];
            const uint_t v6 = ((const uint_t*)(xh + (size_t)p6.x * 128))[lane];
            const uint_t v7 = ((const uint_t*)(xh + (size_t)p7.x * 128))[lane];
            const float d0 = __int_as_float(p0.y) * fmaf(sx, bflo(v0), sy * bfhi(v0));
            const float d1 = __int_as_float(p1.y) * fmaf(sx, bflo(v1), sy * bfhi(v1));
            const float d2 = __int_as_float(p2.y) * fmaf(sx, bflo(v2), sy * bfhi(v2));
            const float d3 = __int_as_float(p3.y) * fmaf(sx, bflo(v3), sy * bfhi(v3));
            const float d4 = __int_as_float(p4.y) * fmaf(sx, bflo(v4), sy * bfhi(v4));
            const float d5 = __int_as_float(p5.y) * fmaf(sx, bflo(v5), sy * bfhi(v5));
            const float d6 = __int_as_float(p6.y) * fmaf(sx, bflo(v6), sy * bfhi(v6));
            const float d7 = __int_as_float(p7.y) * fmaf(sx, bflo(v7), sy * bfhi(v7));
            const int r0 = (e + 0 >= b1) + (e + 0 >= b2) + (e + 0 >= b3) + (e + 0 >= b4);
            const int r1 = (e + 1 >= b1) + (e + 1 >= b2) + (e + 1 >= b3) + (e + 1 >= b4);
            const int r2 = (e + 2 >= b1) + (e + 2 >= b2) + (e + 2 >= b3) + (e + 2 >= b4);
            const int r3 = (e + 3 >= b1) + (e + 3 >= b2) + (e + 3 >= b3) + (e + 3 >= b4);
            const int r4 = (e + 4 >= b1) + (e + 4 >= b2) + (e + 4 >= b3) + (e + 4 >= b4);
            const int r5 = (e + 5 >= b1) + (e + 5 >= b2) + (e + 5 >= b3) + (e + 5 >= b4);
            const int r6 = (e + 6 >= b1) + (e + 6 >= b2) + (e + 6 >= b3) + (e + 6 >= b4);
            const int r7 = (e + 7 >= b1) + (e + 7 >= b2) + (e + 7 >= b3) + (e + 7 >= b4);
            #pragma unroll
            for (int rr = 0; rr < 5; ++rr) {
                ea[rr] += ((r0 == rr ? d0 : 0.0f) + (r1 == rr ? d1 : 0.0f)) +
                          ((r2 == rr ? d2 : 0.0f) + (r3 == rr ? d3 : 0.0f)) +
                          ((r4 == rr ? d4 : 0.0f) + (r5 == rr ? d5 : 0.0f)) +
                          ((r6 == rr ? d6 : 0.0f) + (r7 == rr ? d7 : 0.0f));
            }
        }
        for (; e + 4 <= b5; e += 4) {
            int4 p0 = csr_pk[e + 0];
            int4 p1 = csr_pk[e + 1];
            int4 p2 = csr_pk[e + 2];
            int4 p3 = csr_pk[e + 3];
            const uint_t v0 = ((const uint_t*)(xh + (size_t)p0.x * 128))[lane];
            const uint_t v1 = ((const uint_t*)(xh + (size_t)p1.x * 128))[lane];
            const uint_t v2 = ((const uint_t*)(xh + (size_t)p2.x * 128))[lane];
            const uint_t v3 = ((const uint_t*)(xh + (size_t)p3.x * 128))[lane];
            const float d0 = __int_as_float(p0.y) * fmaf(sx, bflo(v0), sy * bfhi(v0));
            const float d1 = __int_as_float(p1.y) * fmaf(sx, bflo(v1), sy * bfhi(v1));
            const float d2 = __int_as_float(p2.y) * fmaf(sx, bflo(v2), sy * bfhi(v2));
            const float d3 = __int_as_float(p3.y) * fmaf(sx, bflo(v3), sy * bfhi(v3));
            const int r0 = (e + 0 >= b1) + (e + 0 >= b2) + (e + 0 >= b3) + (e + 0 >= b4);
            const int r1 = (e + 1 >= b1) + (e + 1 >= b2) + (e + 1 >= b3) + (e + 1 >= b4);
            const int r2 = (e + 2 >= b1) + (e + 2 >= b2) + (e + 2 >= b3) + (e + 2 >= b4);
            const int r3 = (e + 3 >= b1) + (e + 3 >= b2) + (e + 3 >= b3) + (e + 3 >= b4);
            #pragma unroll
            for (int rr = 0; rr < 5; ++rr) {
                ea[rr] += (r0 == rr ? d0 : 0.0f) + (r1 == rr ? d1 : 0.0f) +
                          (r2 == rr ? d2 : 0.0f) + (r3 == rr ? d3 : 0.0f);
            }
        }
        for (; e < b5; ++e) {
            int4 p0 = csr_pk[e];
            const uint_t v0 = ((const uint_t*)(xh + (size_t)p0.x * 128))[lane];
            const float d0 = __int_as_float(p0.y) * fmaf(sx, bflo(v0), sy * bfhi(v0));
            const int r0 = (e >= b1) + (e >= b2) + (e >= b3) + (e >= b4);
            #pragma unroll
            for (int rr = 0; rr < 5; ++rr)
                ea[rr] += (r0 == rr ? d0 : 0.0f);
        }
    }
    __shared__ float sacc[4][10];
    #pragma unroll
    for (int r = 0; r < 5; ++r) {
        float a = na[r], b = ea[r];
        for (int o = 32; o > 0; o >>= 1) {
            a += __shfl_down(a, o, 64);
            b += __shfl_down(b, o, 64);
        }
        if (lane == 0) { sacc[wv][r] = a; sacc[wv][5 + r] = b; }
    }
    __syncthreads();
    if (threadIdx.x < 10) {
        float t = sacc[0][threadIdx.x] + sacc[1][threadIdx.x] +
                  sacc[2][threadIdx.x] + sacc[3][threadIdx.x];
        atomicAdd(&accbuf[k * 16 + threadIdx.x], t);
    }
}

// ---------------------------------------------------------------------------
// scalar: fp32 lane-parallel mirror descent (lanes 0..7 of one wave)
// ---------------------------------------------------------------------------
__global__ void scalar_kernel(const float* __restrict__ accbuf, float* __restrict__ ug,
                              float* __restrict__ c_l1, int* __restrict__ act, int k)
{
    if (blockIdx.x != 0 || threadIdx.x >= 8) return;
    const int r = threadIdx.x;
    const int a = act[k];
    float w = (r < 5) ? (accbuf[k * 16 + r] - accbuf[k * 16 + 5 + r]) * (1.0f / 30000.0f)
                      : 0.0f;
    float l1 = fabsf(w);
    for (int o = 4; o > 0; o >>= 1) l1 += __shfl_xor(l1, o, 8);
    if (k == 0 && r == 0) c_l1[0] = l1;
    if (!a) { if (r == 0) act[k + 1] = 0; return; }
    float u = (r < 5) ? ug[r] : 0.0f;
    const float fi = l1 + 3.0f;
    bool mact = true;
    for (int t = 1; t <= 20; ++t) {
        float T = sqrtf(3.2188758248682006f / ((float)t * fi * fi));
        float ta = u * expf(-T * (3.0f * u + w));
        float ssum = ta;
        for (int o = 4; o > 0; o >>= 1) ssum += __shfl_xor(ssum, o, 8);
        float un = ta / ssum;
        float d0 = u - un;
        float dq = d0 * d0;
        for (int o = 4; o > 0; o >>= 1) dq += __shfl_xor(dq, o, 8);
        if (mact) u = un;
        mact = mact && (sqrtf(dq) >= 1e-3f);
    }
    if (r < 5) ug[r] = u;
    if (r == 0) act[k + 1] = (l1 / c_l1[0] >= 0.3f) ? 1 : 0;
}

// ---------------------------------------------------------------------------
// msg + update: node-major, packed edges, unroll x8
// ---------------------------------------------------------------------------
__global__ __launch_bounds__(256) void msg_upd_kernel(
    float* __restrict__ x, const ushort_t* __restrict__ xh_in,
    ushort_t* __restrict__ xh_out,
    const int* __restrict__ rp, const int4* __restrict__ csr_pk,
    const float* __restrict__ ug,
    const int* __restrict__ act, int k)
{
    if (act[k + 1] == 0) return;
    const int lane = threadIdx.x & 63;
    const int wid = blockIdx.x * 4 + (threadIdx.x >> 6);
    const int nw = gridDim.x * 4;
    const float u0 = ug[0], u1 = ug[1], u2 = ug[2], u3 = ug[3], u4 = ug[4];
    for (int n = wid; n < N_TOT; n += nw) {
        const int b0 = __builtin_amdgcn_readfirstlane(rp[n * R_ + 0]);
        const int b1 = __builtin_amdgcn_readfirstlane(rp[n * R_ + 1]);
        const int b2 = __builtin_amdgcn_readfirstlane(rp[n * R_ + 2]);
        const int b3 = __builtin_amdgcn_readfirstlane(rp[n * R_ + 3]);
        const int b4 = __builtin_amdgcn_readfirstlane(rp[n * R_ + 4]);
        const int b5 = __builtin_amdgcn_readfirstlane(rp[n * R_ + 5]);
        float ax0 = 0.0f, ay0 = 0.0f, ax1 = 0.0f, ay1 = 0.0f;
        int e = b0;
        for (; e + 8 <= b5; e += 8) {
            int4 p0 = csr_pk[e + 0];
            int4 p1 = csr_pk[e + 1];
            int4 p2 = csr_pk[e + 2];
            int4 p3 = csr_pk[e + 3];
            int4 p4 = csr_pk[e + 4];
            int4 p5 = csr_pk[e + 5];
            int4 p6 = csr_pk[e + 6];
            int4 p7 = csr_pk[e + 7];
            const uint_t v0 = ((const uint_t*)(xh_in + (size_t)p0.x * 128))[lane];
            const uint_t v1 = ((const uint_t*)(xh_in + (size_t)p1.x * 128))[lane];
            const uint_t v2 = ((const uint_t*)(xh_in + (size_t)p2.x * 128))[lane];
            const uint_t v3 = ((const uint_t*)(xh_in + (size_t)p3.x * 128))[lane];
            const uint_t v4 = ((const uint_t*)(xh_in + (size_t)p4.x * 128))[lane];
            const uint_t v5 = ((const uint_t*)(xh_in + (size_t)p5.x * 128))[lane];
            const uint_t v6 = ((const uint_t*)(xh_in + (size_t)p6.x * 128))[lane];
            const uint_t v7 = ((const uint_t*)(xh_in + (size_t)p7.x * 128))[lane];
            const int r0 = (e + 0 >= b1) + (e + 0 >= b2) + (e + 0 >= b3) + (e + 0 >= b4);
            const int r1 = (e + 1 >= b1) + (e + 1 >= b2) + (e + 1 >= b3) + (e + 1 >= b4);
            const int r2 = (e + 2 >= b1) + (e + 2 >= b2) + (e + 2 >= b3) + (e + 2 >= b4);
            const int r3 = (e + 3 >= b1) + (e + 3 >= b2) + (e + 3 >= b3) + (e + 3 >= b4);
            const int r4 = (e + 4 >= b1) + (e + 4 >= b2) + (e + 4 >= b3) + (e + 4 >= b4);
            const int r5 = (e + 5 >= b1) + (e + 5 >= b2) + (e + 5 >= b3) + (e + 5 >= b4);
            const int r6 = (e + 6 >= b1) + (e + 6 >= b2) + (e + 6 >= b3) + (e + 6 >= b4);
            const int r7 = (e + 7 >= b1) + (e + 7 >= b2) + (e + 7 >= b3) + (e + 7 >= b4);
            const float w0 = ((r0 == 0) ? u0 : (r0 == 1) ? u1 : (r0 == 2) ? u2 : (r0 == 3) ? u3 : u4) * __int_as_float(p0.z);
            const float w1 = ((r1 == 0) ? u0 : (r1 == 1) ? u1 : (r1 == 2) ? u2 : (r1 == 3) ? u3 : u4) * __int_as_float(p1.z);
            const float w2 = ((r2 == 0) ? u0 : (r2 == 1) ? u1 : (r2 == 2) ? u2 : (r2 == 3) ? u3 : u4) * __int_as_float(p2.z);
            const float w3 = ((r3 == 0) ? u0 : (r3 == 1) ? u1 : (r3 == 2) ? u2 : (r3 == 3) ? u3 : u4) * __int_as_float(p3.z);
            const float w4 = ((r4 == 0) ? u0 : (r4 == 1) ? u1 : (r4 == 2) ? u2 : (r4 == 3) ? u3 : u4) * __int_as_float(p4.z);
            const float w5 = ((r5 == 0) ? u0 : (r5 == 1) ? u1 : (r5 == 2) ? u2 : (r5 == 3) ? u3 : u4) * __int_as_float(p5.z);
            const float w6 = ((r6 == 0) ? u0 : (r6 == 1) ? u1 : (r6 == 2) ? u2 : (r6 == 3) ? u3 : u4) * __int_as_float(p6.z);
            const float w7 = ((r7 == 0) ? u0 : (r7 == 1) ? u1 : (r7 == 2) ? u2 : (r7 == 3) ? u3 : u4) * __int_as_float(p7.z);
            ax0 = fmaf(w0, bflo(v0), ax0); ay0 = fmaf(w0, bfhi(v0), ay0);
            ax1 = fmaf(w1, bflo(v1), ax1); ay1 = fmaf(w1, bfhi(v1), ay1);
            ax0 = fmaf(w2, bflo(v2), ax0); ay0 = fmaf(w2, bfhi(v2), ay0);
            ax1 = fmaf(w3, bflo(v3), ax1); ay1 = fmaf(w3, bfhi(v3), ay1);
            ax0 = fmaf(w4, bflo(v4), ax0); ay0 = fmaf(w4, bfhi(v4), ay0);
            ax1 = fmaf(w5, bflo(v5), ax1); ay1 = fmaf(w5, bfhi(v5), ay1);
            ax0 = fmaf(w6, bflo(v6), ax0); ay0 = fmaf(w6, bfhi(v6), ay0);
            ax1 = fmaf(w7, bflo(v7), ax1); ay1 = fmaf(w7, bfhi(v7), ay1);
        }
        for (; e + 4 <= b5; e += 4) {
            int4 p0 = csr_pk[e + 0];
            int4 p1 = csr_pk[e + 1];
            int4 p2 = csr_pk[e + 2];
            int4 p3 = csr_pk[e + 3];
            const uint_t v0 = ((const uint_t*)(xh_in + (size_t)p0.x * 128))[lane];
            const uint_t v1 = ((const uint_t*)(xh_in + (size_t)p1.x * 128))[lane];
            const uint_t v2 = ((const uint_t*)(xh_in + (size_t)p2.x * 128))[lane];
            const uint_t v3 = ((const uint_t*)(xh_in + (size_t)p3.x * 128))[lane];
            const int r0 = (e + 0 >= b1) + (e + 0 >= b2) + (e + 0 >= b3) + (e + 0 >= b4);
            const int r1 = (e + 1 >= b1) + (e + 1 >= b2) + (e + 1 >= b3) + (e + 1 >= b4);
            const int r2 = (e + 2 >= b1) + (e + 2 >= b2) + (e + 2 >= b3) + (e + 2 >= b4);
            const int r3 = (e + 3 >= b1) + (e + 3 >= b2) + (e + 3 >= b3) + (e + 3 >= b4);
            const float w0 = ((r0 == 0) ? u0 : (r0 == 1) ? u1 : (r0 == 2) ? u2 : (r0 == 3) ? u3 : u4) * __int_as_float(p0.z);
            const float w1 = ((r1 == 0) ? u0 : (r1 == 1) ? u1 : (r1 == 2) ? u2 : (r1 == 3) ? u3 : u4) * __int_as_float(p1.z);
            const float w2 = ((r2 == 0) ? u0 : (r2 == 1) ? u1 : (r2 == 2) ? u2 : (r2 == 3) ? u3 : u4) * __int_as_float(p2.z);
            const float w3 = ((r3 == 0) ? u0 : (r3 == 1) ? u1 : (r3 == 2) ? u2 : (r3 == 3) ? u3 : u4) * __int_as_float(p3.z);
            ax0 = fmaf(w0, bflo(v0), ax0); ay0 = fmaf(w0, bfhi(v0), ay0);
            ax1 = fmaf(w1, bflo(v1), ax1); ay1 = fmaf(w1, bfhi(v1), ay1);
            ax0 = fmaf(w2, bflo(v2), ax0); ay0 = fmaf(w2, bfhi(v2), ay0);
            ax1 = fmaf(w3, bflo(v3), ax1); ay1 = fmaf(w3, bfhi(v3), ay1);
        }
        for (; e < b5; ++e) {
            int4 p0 = csr_pk[e];
            const int r0 = (e >= b1) + (e >= b2) + (e >= b3) + (e >= b4);
            const float w0 = ((r0 == 0) ? u0 : (r0 == 1) ? u1 : (r0 == 2) ? u2 : (r0 == 3) ? u3 : u4) * __int_as_float(p0.z);
            const uint_t v0 = ((const uint_t*)(xh_in + (size_t)p0.x * 128))[lane];
            ax0 = fmaf(w0, bflo(v0), ax0);
            ay0 = fmaf(w0, bfhi(v0), ay0);
        }
        const float ci = 1.0f / 21.0f, cb = 20.0f / 21.0f;
        float2* xp = (float2*)(x + (size_t)n * 128);
        const float2 xs = xp[lane];
        const float nx_ = fmaf(cb, ax0 + ax1, xs.x * ci);
        const float ny_ = fmaf(cb, ay0 + ay1, xs.y * ci);
        xp[lane] = make_float2(nx_, ny_);
        ((uint_t*)(xh_out + (size_t)n * 128))[lane] =
            ((uint_t)f2bf(ny_) << 16) | (uint_t)f2bf(nx_);
    }
}

// ---------------------------------------------------------------------------
// epilogue: logits = x@Wout + bout ; write logits, x, u (unchanged)
// ---------------------------------------------------------------------------
__global__ __launch_bounds__(256) void final_kernel(const float* __restrict__ x,
                                                    const float* __restrict__ Wout,
                                                    const float* __restrict__ bout,
                                                    const float* __restrict__ ug,
                                                    float* __restrict__ out)
{
    const int nl = threadIdx.x >> 7;
    const int n = blockIdx.x * 2 + nl;
    const int j = threadIdx.x & 127;
    const int lane = threadIdx.x & 63;
    const int wv = threadIdx.x >> 6;
    float xv = x[(size_t)n * 128 + j];
    out[(size_t)NC_ + (size_t)n * 128 + j] = xv;
    float p[8];
    #pragma unroll
    for (int c = 0; c < 8; ++c) p[c] = xv * Wout[j * 8 + c];
    #pragma unroll
    for (int c = 0; c < 8; ++c)
        for (int o = 32; o > 0; o >>= 1) p[c] += __shfl_down(p[c], o, 64);
    __shared__ float sp[4][8];
    if (lane == 0) {
        #pragma unroll
        for (int c = 0; c < 8; ++c) sp[wv][c] = p[c];
    }
    __syncthreads();
    if (j < 8) {
        int c = j;
        out[(size_t)n * 8 + c] = bout[c] + sp[2 * nl][c] + sp[2 * nl + 1][c];
    }
    if (blockIdx.x == 0 && threadIdx.x < 5)
        out[(size_t)NC_ + (size_t)NX_ + threadIdx.x] = ug[threadIdx.x];
}

// ---------------------------------------------------------------------------
extern "C" void kernel_launch(void* const* d_in, const int* in_sizes, int n_in,
                              void* d_out, int out_size, void* d_ws, size_t ws_size,
                              hipStream_t stream)
{
    const float* feat0 = (const float*)d_in[0];
    const float* feat1 = (const float*)d_in[1];
    const float* W0   = (const float*)d_in[2];
    const float* b0   = (const float*)d_in[3];
    const float* W1   = (const float*)d_in[4];
    const float* b1   = (const float*)d_in[5];
    const float* Wm1  = (const float*)d_in[6];
    const float* bm1  = (const float*)d_in[7];
    const float* Wm2  = (const float*)d_in[8];
    const float* bm2  = (const float*)d_in[9];
    const float* Wout = (const float*)d_in[10];
    const float* bout = (const float*)d_in[11];
    const int* src = (const int*)d_in[12];
    const int* dst = (const int*)d_in[13];
    const int* rel = (const int*)d_in[14];
    float* out = (float*)d_out;

    char* p = (char*)d_ws;
    auto alloc = [&](size_t bytes) { char* q = p; p += (bytes + 255) & ~(size_t)255; return q; };
    float*    xbuf      = (float*)   alloc((size_t)NX_ * 4);
    ushort_t* xh0       = (ushort_t*)alloc((size_t)NX_ * 2);
    ushort_t* xh1       = (ushort_t*)alloc((size_t)NX_ * 2);
    ushort_t* fb0       = (ushort_t*)alloc((size_t)N0_ * 256 * 2);
    ushort_t* fb1       = (ushort_t*)alloc((size_t)(N_TOT - N0_) * 128 * 2);
    ushort_t* wt0       = (ushort_t*)alloc((size_t)128 * 256 * 2);
    ushort_t* wt1       = (ushort_t*)alloc((size_t)128 * 128 * 2);
    ushort_t* wtm1      = (ushort_t*)alloc((size_t)128 * 128 * 2);
    ushort_t* wtm2      = (ushort_t*)alloc((size_t)128 * 128 * 2);
    int*      deg_i     = (int*)     alloc((size_t)RN * 4);
    float*    dinv      = (float*)   alloc((size_t)RN * 4);
    int*      rp        = (int*)     alloc(((size_t)RN + 1) * 4);
    int*      fill      = (int*)     alloc((size_t)RN * 4);
    int*      bsum      = (int*)     alloc((size_t)SCAN_NB * 4);
    int*      boff      = (int*)     alloc(256 * 4);
    int4*     csr_pk    = (int4*)    alloc((size_t)E_ * 16);
    float*    accbuf    = (float*)   alloc(128 * 4);
    float*    ug        = (float*)   alloc(64);
    float*    c_l1      = (float*)   alloc(64);
    int*      act       = (int*)     alloc(64);

    hipMemsetAsync(deg_i, 0, (size_t)RN * 4, stream);
    hipMemsetAsync(fill, 0, (size_t)RN * 4, stream);
    hipMemsetAsync(accbuf, 0, 128 * 4, stream);
    init_kernel<<<1, 64, 0, stream>>>(ug, act);

    // bf16 pre-conversion
    cvtfeat_kernel<<<(N0_ * 256 / 4 + 255) / 256, 256, 0, stream>>>(feat0, fb0, N0_ * 256);
    cvtfeat_kernel<<<((N_TOT - N0_) * 128 / 4 + 255) / 256, 256, 0, stream>>>(
        feat1, fb1, (N_TOT - N0_) * 128);
    cvtw_kernel<<<(128 * 256 + 255) / 256, 256, 0, stream>>>(W0, wt0, 256);
    cvtw_kernel<<<(128 * 128 + 255) / 256, 256, 0, stream>>>(W1, wt1, 128);
    cvtw_kernel<<<(128 * 128 + 255) / 256, 256, 0, stream>>>(Wm1, wtm1, 128);
    cvtw_kernel<<<(128 * 128 + 255) / 256, 256, 0, stream>>>(Wm2, wtm2, 128);

    mlp_mfma_kernel<<<(N_TOT + 31) / 32, 256, 0, stream>>>(
        fb0, fb1, wt0, wt1, wtm1, wtm2, b0, b1, bm1, bm2, xbuf, xh0);

    deg_kernel<<<(E_ + 255) / 256, 256, 0, stream>>>(src, rel, deg_i);
    dinv_kernel<<<(RN + 255) / 256, 256, 0, stream>>>(deg_i, dinv);
    scan1_kernel<<<SCAN_NB, 256, 0, stream>>>(deg_i, rp, bsum);
    scan2_kernel<<<1, 256, 0, stream>>>(bsum, boff, rp);
    scan3_kernel<<<SCAN_NB, 256, 0, stream>>>(rp, boff);
    scatter_kernel<<<(E_ + 255) / 256, 256, 0, stream>>>(src, dst, rel, rp, fill,
                                                         deg_i, dinv, csr_pk);

    ushort_t* ha = xh0;
    ushort_t* hb = xh1;
    for (int k = 0; k < 8; ++k) {
        tv_kernel<<<2048, 256, 0, stream>>>(ha, rp, csr_pk, act, k, accbuf);
        scalar_kernel<<<1, 64, 0, stream>>>(accbuf, ug, c_l1, act, k);
        msg_upd_kernel<<<2048, 256, 0, stream>>>(xbuf, ha, hb, rp, csr_pk,
                                                 ug, act, k);
        ushort_t* t = ha; ha = hb; hb = t;
    }

    final_kernel<<<N_TOT / 2, 256, 0, stream>>>(xbuf, Wout, bout, ug, out);
}

// Round 8
// 434.020 us; speedup vs baseline: 1.6442x; 1.0134x over previous
//
#include <hip/hip_runtime.h>
#include <hip/hip_fp16.h>
#include <cmath>

typedef unsigned short ushort_t;
typedef unsigned int uint_t;

#define N_TOT 30000
#define N0_   18000
#define R_    5
#define E_    600000
#define RN    (R_ * N_TOT)
#define NC_   (N_TOT * 8)        // logits elements
#define NX_   (N_TOT * 128)      // x elements
#define NL_   (N_TOT * 64)      // node*lane pairs
#define SCAN_NB ((RN + 1023) / 1024)   // 147 blocks of 1024 elements

typedef __attribute__((ext_vector_type(8))) short bf16x8;
typedef __attribute__((ext_vector_type(4))) float f32x4;

__device__ __forceinline__ ushort_t f2bf(float f) {
    uint_t u = __float_as_uint(f);
    uint_t r = (u + 0x7fffu + ((u >> 16) & 1u)) >> 16;   // RTNE
    return (ushort_t)r;
}
__device__ __forceinline__ float bflo(uint_t v) { return __uint_as_float(v << 16); }
__device__ __forceinline__ float bfhi(uint_t v) { return __uint_as_float(v & 0xffff0000u); }

// ---------------------------------------------------------------------------
// init: u = 1/R, act[0] = 1
// ---------------------------------------------------------------------------
__global__ void init_kernel(float* ug, int* act) {
    if (threadIdx.x < 5) ug[threadIdx.x] = 0.2f;
    if (threadIdx.x == 0) act[0] = 1;
}

// ---------------------------------------------------------------------------
// bf16 pre-conversion: feats row-major, weights transposed [col][k]
// ---------------------------------------------------------------------------
__global__ __launch_bounds__(256) void cvtfeat_kernel(const float* __restrict__ in,
                                                      ushort_t* __restrict__ out,
                                                      int nelem)
{
    int i = (blockIdx.x * 256 + threadIdx.x) * 4;
    if (i >= nelem) return;
    const float4 v = *(const float4*)(in + i);
    ushort_t o0 = f2bf(v.x), o1 = f2bf(v.y), o2 = f2bf(v.z), o3 = f2bf(v.w);
    uint_t p0 = (uint_t)o0 | ((uint_t)o1 << 16);
    uint_t p1 = (uint_t)o2 | ((uint_t)o3 << 16);
    uint2* op = (uint2*)(out + i);
    *op = make_uint2(p0, p1);
}

__global__ __launch_bounds__(256) void cvtw_kernel(const float* __restrict__ W,
                                                   ushort_t* __restrict__ wt, int K)
{
    int idx = blockIdx.x * 256 + threadIdx.x;   // idx = j*K + k
    if (idx >= 128 * K) return;
    int j = idx / K, k = idx - j * K;
    wt[idx] = f2bf(W[k * 128 + j]);
}

// ---------------------------------------------------------------------------
// MFMA MLP: 32 nodes per 256-thread block (4 waves) — unchanged from R4.
// ---------------------------------------------------------------------------
__global__ __launch_bounds__(256) void mlp_mfma_kernel(
    const ushort_t* __restrict__ fb0, const ushort_t* __restrict__ fb1,
    const ushort_t* __restrict__ wt0, const ushort_t* __restrict__ wt1,
    const ushort_t* __restrict__ wtm1, const ushort_t* __restrict__ wtm2,
    const float* __restrict__ b0, const float* __restrict__ b1,
    const float* __restrict__ bm1, const float* __restrict__ bm2,
    float* __restrict__ xout, ushort_t* __restrict__ xh)
{
    const int t = threadIdx.x;
    const int lane = t & 63;
    const int wv = t >> 6;            // 0..3 -> col block wv*32
    const int lr = lane & 15;         // A-row / B-col within tile
    const int lg = lane >> 4;         // k-group, D row-group
    const int row0 = blockIdx.x * 32;

    __shared__ ushort_t hls[32][136];   // bf16 h   (pad: 272B row stride)
    __shared__ float    tls[32][132];   // fp32 t1/t2 (pad: 528B row stride)
    __shared__ ushort_t zls[32][136];   // bf16 z

    // ---------------- GEMM1: h = feat @ W + b -------------------------------
    #pragma unroll
    for (int mt = 0; mt < 2; ++mt) {
        const int rb = row0 + mt * 16;
        const bool is0 = (rb < N0_);
        const int r = min(rb + lr, N_TOT - 1);
        const ushort_t* __restrict__ fa =
            is0 ? fb0 + (size_t)r * 256 : fb1 + (size_t)(r - N0_) * 128;
        const ushort_t* __restrict__ wt = is0 ? wt0 : wt1;
        const int K = is0 ? 256 : 128;
        const int c0 = wv * 32 + lr;

        f32x4 a0 = {0.f, 0.f, 0.f, 0.f};
        f32x4 a1 = {0.f, 0.f, 0.f, 0.f};
        for (int ks = 0; ks < K; ks += 32) {
            const bf16x8 af = *(const bf16x8*)(fa + ks + lg * 8);
            const bf16x8 wb0 = *(const bf16x8*)(wt + (size_t)c0 * K + ks + lg * 8);
            const bf16x8 wb1 = *(const bf16x8*)(wt + (size_t)(c0 + 16) * K + ks + lg * 8);
            a0 = __builtin_amdgcn_mfma_f32_16x16x32_bf16(af, wb0, a0, 0, 0, 0);
            a1 = __builtin_amdgcn_mfma_f32_16x16x32_bf16(af, wb1, a1, 0, 0, 0);
        }
        const float bb0 = is0 ? b0[c0] : b1[c0];
        const float bb1 = is0 ? b0[c0 + 16] : b1[c0 + 16];
        #pragma unroll
        for (int j = 0; j < 4; ++j) {
            hls[mt * 16 + lg * 4 + j][c0]      = f2bf(a0[j] + bb0);
            hls[mt * 16 + lg * 4 + j][c0 + 16] = f2bf(a1[j] + bb1);
        }
    }
    __syncthreads();

    // ---------------- GEMM2: t1 = h @ Wm1 + bm1 -----------------------------
    {
        const int c0 = wv * 32 + lr;
        f32x4 g00 = {0.f,0.f,0.f,0.f}, g01 = {0.f,0.f,0.f,0.f};
        f32x4 g10 = {0.f,0.f,0.f,0.f}, g11 = {0.f,0.f,0.f,0.f};
        for (int ks = 0; ks < 128; ks += 32) {
            const bf16x8 wb0 = *(const bf16x8*)(wtm1 + (size_t)c0 * 128 + ks + lg * 8);
            const bf16x8 wb1 = *(const bf16x8*)(wtm1 + (size_t)(c0 + 16) * 128 + ks + lg * 8);
            const bf16x8 af0 = *(const bf16x8*)(&hls[lr][ks + lg * 8]);
            const bf16x8 af1 = *(const bf16x8*)(&hls[16 + lr][ks + lg * 8]);
            g00 = __builtin_amdgcn_mfma_f32_16x16x32_bf16(af0, wb0, g00, 0, 0, 0);
            g01 = __builtin_amdgcn_mfma_f32_16x16x32_bf16(af0, wb1, g01, 0, 0, 0);
            g10 = __builtin_amdgcn_mfma_f32_16x16x32_bf16(af1, wb0, g10, 0, 0, 0);
            g11 = __builtin_amdgcn_mfma_f32_16x16x32_bf16(af1, wb1, g11, 0, 0, 0);
        }
        const float bb0 = bm1[c0], bb1 = bm1[c0 + 16];
        #pragma unroll
        for (int j = 0; j < 4; ++j) {
            tls[lg * 4 + j][c0]           = g00[j] + bb0;
            tls[lg * 4 + j][c0 + 16]      = g01[j] + bb1;
            tls[16 + lg * 4 + j][c0]      = g10[j] + bb0;
            tls[16 + lg * 4 + j][c0 + 16] = g11[j] + bb1;
        }
    }
    __syncthreads();

    // ---------------- LN + relu -> z (bf16) ---------------------------------
    {
        const int row = t >> 3, seg = t & 7;
        f32x4 v[4];
        float s = 0.f;
        #pragma unroll
        for (int i = 0; i < 4; ++i) {
            v[i] = *(const f32x4*)(&tls[row][seg * 16 + i * 4]);
            s += v[i][0] + v[i][1] + v[i][2] + v[i][3];
        }
        #pragma unroll
        for (int o = 1; o < 8; o <<= 1) s += __shfl_xor(s, o, 64);
        const float mean = s * (1.0f / 128.0f);
        float q = 0.f;
        #pragma unroll
        for (int i = 0; i < 4; ++i) {
            #pragma unroll
            for (int e = 0; e < 4; ++e) { float d = v[i][e] - mean; q = fmaf(d, d, q); }
        }
        #pragma unroll
        for (int o = 1; o < 8; o <<= 1) q += __shfl_xor(q, o, 64);
        const float inv = 1.0f / sqrtf(q * (1.0f / 128.0f) + 1e-5f);
        uint_t* zp = (uint_t*)&zls[row][0];
        #pragma unroll
        for (int i = 0; i < 4; ++i) {
            ushort_t z0 = f2bf(fmaxf((v[i][0] - mean) * inv, 0.0f));
            ushort_t z1 = f2bf(fmaxf((v[i][1] - mean) * inv, 0.0f));
            ushort_t z2 = f2bf(fmaxf((v[i][2] - mean) * inv, 0.0f));
            ushort_t z3 = f2bf(fmaxf((v[i][3] - mean) * inv, 0.0f));
            zp[(seg * 16 + i * 4) / 2]     = (uint_t)z0 | ((uint_t)z1 << 16);
            zp[(seg * 16 + i * 4) / 2 + 1] = (uint_t)z2 | ((uint_t)z3 << 16);
        }
    }
    __syncthreads();

    // ---------------- GEMM3: t2 = z @ Wm2 + bm2 -----------------------------
    {
        const int c0 = wv * 32 + lr;
        f32x4 g00 = {0.f,0.f,0.f,0.f}, g01 = {0.f,0.f,0.f,0.f};
        f32x4 g10 = {0.f,0.f,0.f,0.f}, g11 = {0.f,0.f,0.f,0.f};
        for (int ks = 0; ks < 128; ks += 32) {
            const bf16x8 wb0 = *(const bf16x8*)(wtm2 + (size_t)c0 * 128 + ks + lg * 8);
            const bf16x8 wb1 = *(const bf16x8*)(wtm2 + (size_t)(c0 + 16) * 128 + ks + lg * 8);
            const bf16x8 af0 = *(const bf16x8*)(&zls[lr][ks + lg * 8]);
            const bf16x8 af1 = *(const bf16x8*)(&zls[16 + lr][ks + lg * 8]);
            g00 = __builtin_amdgcn_mfma_f32_16x16x32_bf16(af0, wb0, g00, 0, 0, 0);
            g01 = __builtin_amdgcn_mfma_f32_16x16x32_bf16(af0, wb1, g01, 0, 0, 0);
            g10 = __builtin_amdgcn_mfma_f32_16x16x32_bf16(af1, wb0, g10, 0, 0, 0);
            g11 = __builtin_amdgcn_mfma_f32_16x16x32_bf16(af1, wb1, g11, 0, 0, 0);
        }
        __syncthreads();   // all zls reads done before tls is overwritten below
        const float bb0 = bm2[c0], bb1 = bm2[c0 + 16];
        #pragma unroll
        for (int j = 0; j < 4; ++j) {
            tls[lg * 4 + j][c0]           = g00[j] + bb0;
            tls[lg * 4 + j][c0 + 16]      = g01[j] + bb1;
            tls[16 + lg * 4 + j][c0]      = g10[j] + bb0;
            tls[16 + lg * 4 + j][c0 + 16] = g11[j] + bb1;
        }
    }
    __syncthreads();

    // ---------------- per-row standardization + store -----------------------
    {
        const int row = t >> 3, seg = t & 7;
        const int n = row0 + row;
        f32x4 v[4];
        float s = 0.f;
        #pragma unroll
        for (int i = 0; i < 4; ++i) {
            v[i] = *(const f32x4*)(&tls[row][seg * 16 + i * 4]);
            s += v[i][0] + v[i][1] + v[i][2] + v[i][3];
        }
        #pragma unroll
        for (int o = 1; o < 8; o <<= 1) s += __shfl_xor(s, o, 64);
        const float mu = s * (1.0f / 128.0f);
        float q = 0.f;
        #pragma unroll
        for (int i = 0; i < 4; ++i) {
            #pragma unroll
            for (int e = 0; e < 4; ++e) { float d = v[i][e] - mu; q = fmaf(d, d, q); }
        }
        #pragma unroll
        for (int o = 1; o < 8; o <<= 1) q += __shfl_xor(q, o, 64);
        const float sd = sqrtf(q * (1.0f / 127.0f));
        const float inv = 1.0f / sd;
        if (n < N_TOT) {
            uint_t* xhp = (uint_t*)xh + (size_t)n * 64 + seg * 8;
            float* xop = xout + (size_t)n * 128 + seg * 16;
            #pragma unroll
            for (int i = 0; i < 4; ++i) {
                float rr[4];
                #pragma unroll
                for (int e = 0; e < 4; ++e) {
                    float r = (v[i][e] - mu) * inv;
                    if (!(fabsf(r) <= 3.402823466e38f)) {
                        r = (r != r) ? 0.0f : ((r > 0.0f) ? 3.402823466e38f : -3.402823466e38f);
                    }
                    rr[e] = r;
                }
                *(float4*)(xop + i * 4) = make_float4(rr[0], rr[1], rr[2], rr[3]);
                xhp[i * 2]     = (uint_t)f2bf(rr[0]) | ((uint_t)f2bf(rr[1]) << 16);
                xhp[i * 2 + 1] = (uint_t)f2bf(rr[2]) | ((uint_t)f2bf(rr[3]) << 16);
            }
        }
    }
}

// ---------------------------------------------------------------------------
// preprocessing — node-major keys: key = src*5 + rel
// ---------------------------------------------------------------------------
__global__ void deg_kernel(const int* __restrict__ src, const int* __restrict__ rel,
                           int* __restrict__ deg_i)
{
    int e = blockIdx.x * 256 + threadIdx.x;
    if (e >= E_) return;
    atomicAdd(&deg_i[src[e] * R_ + rel[e]], 1);
}

__global__ void dinv_kernel(const int* __restrict__ deg_i, float* __restrict__ dinv)
{
    int i = blockIdx.x * 256 + threadIdx.x;
    if (i >= RN) return;
    int dg = deg_i[i];
    dinv[i] = (dg > 0) ? 1.0f / sqrtf((float)dg) : 0.0f;
}

// 3-pass parallel exclusive scan over RN elements
__global__ __launch_bounds__(256) void scan1_kernel(const int* __restrict__ cnt,
                                                    int* __restrict__ rp,
                                                    int* __restrict__ bsum)
{
    __shared__ int wsum[4];
    const int t = threadIdx.x, lane = t & 63, w = t >> 6;
    const int i0 = blockIdx.x * 1024 + t * 4;
    const int v0 = (i0 + 0 < RN) ? cnt[i0 + 0] : 0;
    const int v1 = (i0 + 1 < RN) ? cnt[i0 + 1] : 0;
    const int v2 = (i0 + 2 < RN) ? cnt[i0 + 2] : 0;
    const int v3 = (i0 + 3 < RN) ? cnt[i0 + 3] : 0;
    const int s = v0 + v1 + v2 + v3;
    int sc = s;
    #pragma unroll
    for (int o = 1; o < 64; o <<= 1) { int tmp = __shfl_up(sc, o, 64); if (lane >= o) sc += tmp; }
    if (lane == 63) wsum[w] = sc;
    __syncthreads();
    int woff = 0;
    #pragma unroll
    for (int i = 0; i < 3; ++i) if (i < w) woff += wsum[i];
    int run = woff + sc - s;                 // exclusive within block
    if (i0 + 0 < RN) rp[i0 + 0] = run; run += v0;
    if (i0 + 1 < RN) rp[i0 + 1] = run; run += v1;
    if (i0 + 2 < RN) rp[i0 + 2] = run; run += v2;
    if (i0 + 3 < RN) rp[i0 + 3] = run;
    if (t == 255) bsum[blockIdx.x] = woff + sc;   // block total
}

__global__ __launch_bounds__(256) void scan2_kernel(const int* __restrict__ bsum,
                                                    int* __restrict__ boff,
                                                    int* __restrict__ rp)
{
    __shared__ int wsum[4];
    const int t = threadIdx.x, lane = t & 63, w = t >> 6;
    const int v = (t < SCAN_NB) ? bsum[t] : 0;
    int sc = v;
    #pragma unroll
    for (int o = 1; o < 64; o <<= 1) { int tmp = __shfl_up(sc, o, 64); if (lane >= o) sc += tmp; }
    if (lane == 63) wsum[w] = sc;
    __syncthreads();
    int woff = 0;
    #pragma unroll
    for (int i = 0; i < 3; ++i) if (i < w) woff += wsum[i];
    boff[t] = woff + sc - v;                 // exclusive block offset
    if (t == 0) rp[RN] = E_;                 // total degree == E
}

__global__ __launch_bounds__(256) void scan3_kernel(int* __restrict__ rp,
                                                    const int* __restrict__ boff)
{
    const int off = boff[blockIdx.x];
    if (off == 0) return;
    const int i0 = blockIdx.x * 1024 + threadIdx.x * 4;
    if (i0 + 3 < RN) {
        int4* p = (int4*)(rp + i0);
        int4 q = *p;
        q.x += off; q.y += off; q.z += off; q.w += off;
        *p = q;
    } else {
        for (int i = 0; i < 4; ++i)
            if (i0 + i < RN) rp[i0 + i] += off;
    }
}

// scatter: build packed edge records {dst, edinv, w, 0}
__global__ void scatter_kernel(const int* __restrict__ src, const int* __restrict__ dst,
                               const int* __restrict__ rel, const int* __restrict__ rp,
                               int* __restrict__ fill, const int* __restrict__ deg_i,
                               const float* __restrict__ dinv,
                               int4* __restrict__ csr_pk)
{
    int e = blockIdx.x * 256 + threadIdx.x;
    if (e >= E_) return;
    int s = src[e], r = rel[e], d = dst[e];
    int key = s * R_ + r;
    int pos = rp[key] + atomicAdd(&fill[key], 1);
    float edinv = dinv[key] * dinv[d * R_ + r];
    float w = 1.0f / (float)deg_i[key];
    csr_pk[pos] = make_int4(d, __float_as_int(edinv), __float_as_int(w), 0);
}

// ---------------------------------------------------------------------------
// FUSED gather: ONE edge pass per iteration computing BOTH the tv partials
// (node + edge terms) AND the u-independent per-relation messages
// m_r[n] = sum_{e in rel r} w_e * x[dst], written to mbuf as packed fp16
// pairs.  The apply kernel combines m with u_{k+1} after the scalar step —
// no second gather pass.
// ---------------------------------------------------------------------------
__global__ __launch_bounds__(256) void gather_kernel(
    const ushort_t* __restrict__ xh, const int* __restrict__ rp,
    const int4* __restrict__ csr_pk,
    const int* __restrict__ act, int k, float* __restrict__ accbuf,
    uint_t* __restrict__ mbuf)
{
    if (act[k] == 0) return;
    const int lane = threadIdx.x & 63;
    const int wv = threadIdx.x >> 6;
    const int wid = blockIdx.x * 4 + wv;
    const int nw = gridDim.x * 4;
    float na[5] = {0, 0, 0, 0, 0};
    float ea[5] = {0, 0, 0, 0, 0};
    for (int n = wid; n < N_TOT; n += nw) {
        const int b0 = __builtin_amdgcn_readfirstlane(rp[n * R_ + 0]);
        const int b1 = __builtin_amdgcn_readfirstlane(rp[n * R_ + 1]);
        const int b2 = __builtin_amdgcn_readfirstlane(rp[n * R_ + 2]);
        const int b3 = __builtin_amdgcn_readfirstlane(rp[n * R_ + 3]);
        const int b4 = __builtin_amdgcn_readfirstlane(rp[n * R_ + 4]);
        const int b5 = __builtin_amdgcn_readfirstlane(rp[n * R_ + 5]);
        const uint_t vs = ((const uint_t*)(xh + (size_t)n * 128))[lane];
        const float sx = bflo(vs), sy = bfhi(vs);
        const float pp = fmaf(sx, sx, sy * sy);
        if (b1 > b0) na[0] += pp;
        if (b2 > b1) na[1] += pp;
        if (b3 > b2) na[2] += pp;
        if (b4 > b3) na[3] += pp;
        if (b5 > b4) na[4] += pp;
        float mx[5] = {0, 0, 0, 0, 0};
        float my[5] = {0, 0, 0, 0, 0};
        int e = b0;
        for (; e + 4 <= b5; e += 4) {
            int4 p0 = csr_pk[e + 0];
            int4 p1 = csr_pk[e + 1];
            int4 p2 = csr_pk[e + 2];
            int4 p3 = csr_pk[e + 3];
            const uint_t v0 = ((const uint_t*)(xh + (size_t)p0.x * 128))[lane];
            const uint_t v1 = ((const uint_t*)(xh + (size_t)p1.x * 128))[lane];
            const uint_t v2 = ((const uint_t*)(xh + (size_t)p2.x * 128))[lane];
            const uint_t v3 = ((const uint_t*)(xh + (size_t)p3.x * 128))[lane];
            const float x0 = bflo(v0), y0 = bfhi(v0);
            const float x1 = bflo(v1), y1 = bfhi(v1);
            const float x2 = bflo(v2), y2 = bfhi(v2);
            const float x3 = bflo(v3), y3 = bfhi(v3);
            const float d0 = __int_as_float(p0.y) * fmaf(sx, x0, sy * y0);
            const float d1 = __int_as_float(p1.y) * fmaf(sx, x1, sy * y1);
            const float d2 = __int_as_float(p2.y) * fmaf(sx, x2, sy * y2);
            const float d3 = __int_as_float(p3.y) * fmaf(sx, x3, sy * y3);
            const int r0 = (e + 0 >= b1) + (e + 0 >= b2) + (e + 0 >= b3) + (e + 0 >= b4);
            const int r1 = (e + 1 >= b1) + (e + 1 >= b2) + (e + 1 >= b3) + (e + 1 >= b4);
            const int r2 = (e + 2 >= b1) + (e + 2 >= b2) + (e + 2 >= b3) + (e + 2 >= b4);
            const int r3 = (e + 3 >= b1) + (e + 3 >= b2) + (e + 3 >= b3) + (e + 3 >= b4);
            #pragma unroll
            for (int rr = 0; rr < 5; ++rr) {
                ea[rr] += (r0 == rr ? d0 : 0.0f) + (r1 == rr ? d1 : 0.0f) +
                          (r2 == rr ? d2 : 0.0f) + (r3 == rr ? d3 : 0.0f);
                const float ws0 = (r0 == rr) ? __int_as_float(p0.z) : 0.0f;
                const float ws1 = (r1 == rr) ? __int_as_float(p1.z) : 0.0f;
                const float ws2 = (r2 == rr) ? __int_as_float(p2.z) : 0.0f;
                const float ws3 = (r3 == rr) ? __int_as_float(p3.z) : 0.0f;
                mx[rr] = fmaf(ws0, x0, fmaf(ws1, x1, fmaf(ws2, x2, fmaf(ws3, x3, mx[rr]))));
                my[rr] = fmaf(ws0, y0, fmaf(ws1, y1, fmaf(ws2, y2, fmaf(ws3, y3, my[rr]))));
            }
        }
        for (; e < b5; ++e) {
            int4 p0 = csr_pk[e];
            const uint_t v0 = ((const uint_t*)(xh + (size_t)p0.x * 128))[lane];
            const float x0 = bflo(v0), y0 = bfhi(v0);
            const float d0 = __int_as_float(p0.y) * fmaf(sx, x0, sy * y0);
            const int r0 = (e >= b1) + (e >= b2) + (e >= b3) + (e >= b4);
            #pragma unroll
            for (int rr = 0; rr < 5; ++rr) {
                ea[rr] += (r0 == rr ? d0 : 0.0f);
                const float ws0 = (r0 == rr) ? __int_as_float(p0.z) : 0.0f;
                mx[rr] = fmaf(ws0, x0, mx[rr]);
                my[rr] = fmaf(ws0, y0, my[rr]);
            }
        }
        #pragma unroll
        for (int rr = 0; rr < 5; ++rr) {
            __half2 hm = __floats2half2_rn(mx[rr], my[rr]);
            mbuf[(size_t)rr * NL_ + (size_t)n * 64 + lane] =
                *reinterpret_cast<const uint_t*>(&hm);
        }
    }
    __shared__ float sacc[4][10];
    #pragma unroll
    for (int r = 0; r < 5; ++r) {
        float a = na[r], b = ea[r];
        for (int o = 32; o > 0; o >>= 1) {
            a += __shfl_down(a, o, 64);
            b += __shfl_down(b, o, 64);
        }
        if (lane == 0) { sacc[wv][r] = a; sacc[wv][5 + r] = b; }
    }
    __syncthreads();
    if (threadIdx.x < 10) {
        float t = sacc[0][threadIdx.x] + sacc[1][threadIdx.x] +
                  sacc[2][threadIdx.x] + sacc[3][threadIdx.x];
        atomicAdd(&accbuf[k * 16 + threadIdx.x], t);
    }
}

// ---------------------------------------------------------------------------
// scalar: fp32 lane-parallel mirror descent (lanes 0..7 of one wave)
// ---------------------------------------------------------------------------
__global__ void scalar_kernel(const float* __restrict__ accbuf, float* __restrict__ ug,
                              float* __restrict__ c_l1, int* __restrict__ act, int k)
{
    if (blockIdx.x != 0 || threadIdx.x >= 8) return;
    const int r = threadIdx.x;
    const int a = act[k];
    float w = (r < 5) ? (accbuf[k * 16 + r] - accbuf[k * 16 + 5 + r]) * (1.0f / 30000.0f)
                      : 0.0f;
    float l1 = fabsf(w);
    for (int o = 4; o > 0; o >>= 1) l1 += __shfl_xor(l1, o, 8);
    if (k == 0 && r == 0) c_l1[0] = l1;
    if (!a) { if (r == 0) act[k + 1] = 0; return; }
    float u = (r < 5) ? ug[r] : 0.0f;
    const float fi = l1 + 3.0f;
    bool mact = true;
    for (int t = 1; t <= 20; ++t) {
        float T = sqrtf(3.2188758248682006f / ((float)t * fi * fi));
        float ta = u * expf(-T * (3.0f * u + w));
        float ssum = ta;
        for (int o = 4; o > 0; o >>= 1) ssum += __shfl_xor(ssum, o, 8);
        float un = ta / ssum;
        float d0 = u - un;
        float dq = d0 * d0;
        for (int o = 4; o > 0; o >>= 1) dq += __shfl_xor(dq, o, 8);
        if (mact) u = un;
        mact = mact && (sqrtf(dq) >= 1e-3f);
    }
    if (r < 5) ug[r] = u;
    if (r == 0) act[k + 1] = (l1 / c_l1[0] >= 0.3f) ? 1 : 0;
}

// ---------------------------------------------------------------------------
// apply: x = x/(1+L1) + L1/(1+L1) * sum_r u_r m_r — pure streaming.
// ---------------------------------------------------------------------------
__global__ __launch_bounds__(256) void apply_kernel(
    float* __restrict__ x, ushort_t* __restrict__ xh_out,
    const uint_t* __restrict__ mbuf, const float* __restrict__ ug,
    const int* __restrict__ act, int k)
{
    if (act[k + 1] == 0) return;
    const int tid = blockIdx.x * 256 + threadIdx.x;
    if (tid >= NL_) return;
    const float u0 = ug[0], u1 = ug[1], u2 = ug[2], u3 = ug[3], u4 = ug[4];

    uint_t w0 = mbuf[(size_t)0 * NL_ + tid];
    uint_t w1 = mbuf[(size_t)1 * NL_ + tid];
    uint_t w2 = mbuf[(size_t)2 * NL_ + tid];
    uint_t w3 = mbuf[(size_t)3 * NL_ + tid];
    uint_t w4 = mbuf[(size_t)4 * NL_ + tid];
    const float2 m0 = __half22float2(*reinterpret_cast<const __half2*>(&w0));
    const float2 m1 = __half22float2(*reinterpret_cast<const __half2*>(&w1));
    const float2 m2 = __half22float2(*reinterpret_cast<const __half2*>(&w2));
    const float2 m3 = __half22float2(*reinterpret_cast<const __half2*>(&w3));
    const float2 m4 = __half22float2(*reinterpret_cast<const __half2*>(&w4));

    const float sm_x = u0 * m0.x + u1 * m1.x + u2 * m2.x + u3 * m3.x + u4 * m4.x;
    const float sm_y = u0 * m0.y + u1 * m1.y + u2 * m2.y + u3 * m3.y + u4 * m4.y;

    const float ci = 1.0f / 21.0f, cb = 20.0f / 21.0f;
    float2* xp = (float2*)x;
    const float2 xs = xp[tid];
    const float nx_ = fmaf(cb, sm_x, xs.x * ci);
    const float ny_ = fmaf(cb, sm_y, xs.y * ci);
    xp[tid] = make_float2(nx_, ny_);
    ((uint_t*)xh_out)[tid] = ((uint_t)f2bf(ny_) << 16) | (uint_t)f2bf(nx_);
}

// ---------------------------------------------------------------------------
// epilogue: logits = x@Wout + bout ; write logits, x, u (unchanged)
// ---------------------------------------------------------------------------
__global__ __launch_bounds__(256) void final_kernel(const float* __restrict__ x,
                                                    const float* __restrict__ Wout,
                                                    const float* __restrict__ bout,
                                                    const float* __restrict__ ug,
                                                    float* __restrict__ out)
{
    const int nl = threadIdx.x >> 7;
    const int n = blockIdx.x * 2 + nl;
    const int j = threadIdx.x & 127;
    const int lane = threadIdx.x & 63;
    const int wv = threadIdx.x >> 6;
    float xv = x[(size_t)n * 128 + j];
    out[(size_t)NC_ + (size_t)n * 128 + j] = xv;
    float p[8];
    #pragma unroll
    for (int c = 0; c < 8; ++c) p[c] = xv * Wout[j * 8 + c];
    #pragma unroll
    for (int c = 0; c < 8; ++c)
        for (int o = 32; o > 0; o >>= 1) p[c] += __shfl_down(p[c], o, 64);
    __shared__ float sp[4][8];
    if (lane == 0) {
        #pragma unroll
        for (int c = 0; c < 8; ++c) sp[wv][c] = p[c];
    }
    __syncthreads();
    if (j < 8) {
        int c = j;
        out[(size_t)n * 8 + c] = bout[c] + sp[2 * nl][c] + sp[2 * nl + 1][c];
    }
    if (blockIdx.x == 0 && threadIdx.x < 5)
        out[(size_t)NC_ + (size_t)NX_ + threadIdx.x] = ug[threadIdx.x];
}

// ---------------------------------------------------------------------------
extern "C" void kernel_launch(void* const* d_in, const int* in_sizes, int n_in,
                              void* d_out, int out_size, void* d_ws, size_t ws_size,
                              hipStream_t stream)
{
    const float* feat0 = (const float*)d_in[0];
    const float* feat1 = (const float*)d_in[1];
    const float* W0   = (const float*)d_in[2];
    const float* b0   = (const float*)d_in[3];
    const float* W1   = (const float*)d_in[4];
    const float* b1   = (const float*)d_in[5];
    const float* Wm1  = (const float*)d_in[6];
    const float* bm1  = (const float*)d_in[7];
    const float* Wm2  = (const float*)d_in[8];
    const float* bm2  = (const float*)d_in[9];
    const float* Wout = (const float*)d_in[10];
    const float* bout = (const float*)d_in[11];
    const int* src = (const int*)d_in[12];
    const int* dst = (const int*)d_in[13];
    const int* rel = (const int*)d_in[14];
    float* out = (float*)d_out;

    char* p = (char*)d_ws;
    auto alloc = [&](size_t bytes) { char* q = p; p += (bytes + 255) & ~(size_t)255; return q; };
    float*    xbuf      = (float*)   alloc((size_t)NX_ * 4);
    ushort_t* xh0       = (ushort_t*)alloc((size_t)NX_ * 2);
    ushort_t* xh1       = (ushort_t*)alloc((size_t)NX_ * 2);
    uint_t*   mbuf      = (uint_t*)  alloc((size_t)R_ * NL_ * 4);   // 38.4 MB fp16 msgs
    ushort_t* fb0       = (ushort_t*)alloc((size_t)N0_ * 256 * 2);
    ushort_t* fb1       = (ushort_t*)alloc((size_t)(N_TOT - N0_) * 128 * 2);
    ushort_t* wt0       = (ushort_t*)alloc((size_t)128 * 256 * 2);
    ushort_t* wt1       = (ushort_t*)alloc((size_t)128 * 128 * 2);
    ushort_t* wtm1      = (ushort_t*)alloc((size_t)128 * 128 * 2);
    ushort_t* wtm2      = (ushort_t*)alloc((size_t)128 * 128 * 2);
    int*      deg_i     = (int*)     alloc((size_t)RN * 4);
    float*    dinv      = (float*)   alloc((size_t)RN * 4);
    int*      rp        = (int*)     alloc(((size_t)RN + 1) * 4);
    int*      fill      = (int*)     alloc((size_t)RN * 4);
    int*      bsum      = (int*)     alloc((size_t)SCAN_NB * 4);
    int*      boff      = (int*)     alloc(256 * 4);
    int4*     csr_pk    = (int4*)    alloc((size_t)E_ * 16);
    float*    accbuf    = (float*)   alloc(128 * 4);
    float*    ug        = (float*)   alloc(64);
    float*    c_l1      = (float*)   alloc(64);
    int*      act       = (int*)     alloc(64);

    hipMemsetAsync(deg_i, 0, (size_t)RN * 4, stream);
    hipMemsetAsync(fill, 0, (size_t)RN * 4, stream);
    hipMemsetAsync(accbuf, 0, 128 * 4, stream);
    init_kernel<<<1, 64, 0, stream>>>(ug, act);

    // bf16 pre-conversion
    cvtfeat_kernel<<<(N0_ * 256 / 4 + 255) / 256, 256, 0, stream>>>(feat0, fb0, N0_ * 256);
    cvtfeat_kernel<<<((N_TOT - N0_) * 128 / 4 + 255) / 256, 256, 0, stream>>>(
        feat1, fb1, (N_TOT - N0_) * 128);
    cvtw_kernel<<<(128 * 256 + 255) / 256, 256, 0, stream>>>(W0, wt0, 256);
    cvtw_kernel<<<(128 * 128 + 255) / 256, 256, 0, stream>>>(W1, wt1, 128);
    cvtw_kernel<<<(128 * 128 + 255) / 256, 256, 0, stream>>>(Wm1, wtm1, 128);
    cvtw_kernel<<<(128 * 128 + 255) / 256, 256, 0, stream>>>(Wm2, wtm2, 128);

    mlp_mfma_kernel<<<(N_TOT + 31) / 32, 256, 0, stream>>>(
        fb0, fb1, wt0, wt1, wtm1, wtm2, b0, b1, bm1, bm2, xbuf, xh0);

    deg_kernel<<<(E_ + 255) / 256, 256, 0, stream>>>(src, rel, deg_i);
    dinv_kernel<<<(RN + 255) / 256, 256, 0, stream>>>(deg_i, dinv);
    scan1_kernel<<<SCAN_NB, 256, 0, stream>>>(deg_i, rp, bsum);
    scan2_kernel<<<1, 256, 0, stream>>>(bsum, boff, rp);
    scan3_kernel<<<SCAN_NB, 256, 0, stream>>>(rp, boff);
    scatter_kernel<<<(E_ + 255) / 256, 256, 0, stream>>>(src, dst, rel, rp, fill,
                                                         deg_i, dinv, csr_pk);

    ushort_t* ha = xh0;
    ushort_t* hb = xh1;
    for (int k = 0; k < 8; ++k) {
        gather_kernel<<<2048, 256, 0, stream>>>(ha, rp, csr_pk, act, k, accbuf, mbuf);
        scalar_kernel<<<1, 64, 0, stream>>>(accbuf, ug, c_l1, act, k);
        apply_kernel<<<(NL_ + 255) / 256, 256, 0, stream>>>(xbuf, hb, mbuf, ug, act, k);
        ushort_t* t = ha; ha = hb; hb = t;
    }

    final_kernel<<<N_TOT / 2, 256, 0, stream>>>(xbuf, Wout, bout, ug, out);
}